// Round 6
// baseline (4277.320 us; speedup 1.0000x reference)
//
#include <hip/hip_runtime.h>
#include <cstdint>

#define N_NODES 50000
#define FEAT    128
#define HID     64
#define NREL    3
#define NTREE   2
#define NEDGE   500000
#define NCLS    2

#define BKT   391
#define CAP   1600
#define CHUNK 8192

typedef __attribute__((ext_vector_type(8))) short bfrag;   // 8 bf16 (4 VGPR)
typedef __attribute__((ext_vector_type(4))) float ffrag;   // 4 f32 acc

__device__ __forceinline__ float wave_red(float v){
  #pragma unroll
  for(int off = 32; off > 0; off >>= 1) v += __shfl_xor(v, off, 64);
  return v;
}

__device__ __forceinline__ unsigned short f2b(float f){
  unsigned int u = __float_as_uint(f);
  unsigned int r = (u + 0x7FFFu + ((u >> 16) & 1u)) >> 16;
  return (unsigned short)r;
}
__device__ __forceinline__ float b2f_lo(unsigned int u){ return __uint_as_float(u << 16); }
__device__ __forceinline__ float b2f_hi(unsigned int u){ return __uint_as_float(u & 0xFFFF0000u); }
__device__ __forceinline__ float b2f(unsigned short s){ return __uint_as_float(((unsigned int)s) << 16); }
__device__ __forceinline__ unsigned int fkey(float f){
  unsigned int u = __float_as_uint(f);
  return (u & 0x80000000u) ? ~u : (u | 0x80000000u);
}
__device__ __forceinline__ float kdec(unsigned int k){
  return __uint_as_float((k & 0x80000000u) ? (k ^ 0x80000000u) : ~k);
}

struct EdgePtrs { const int* s[9]; const int* d[9]; };

// ================= CSR build pass A: LDS-staged bucket sort =================
__global__ __launch_bounds__(256)
void k_passA(EdgePtrs ep, int* __restrict__ cursor, int* __restrict__ bucketed){
  int set = blockIdx.y;
  const int* src = ep.s[set];
  const int* dst = ep.d[set];
  __shared__ int stage[CHUNK];
  __shared__ int hist[BKT], gbase[BKT], lbase[BKT], cur[BKT];
  int tid = threadIdx.x;
  for(int b = tid; b < BKT; b += 256) hist[b] = 0;
  __syncthreads();
  int e0 = blockIdx.x * CHUNK;
  int nE = NEDGE - e0; if(nE > CHUNK) nE = CHUNK;
  for(int i = tid; i < nE; i += 256) atomicAdd(&hist[dst[e0 + i] >> 7], 1);
  __syncthreads();
  for(int b = tid; b < BKT; b += 256){
    int c = hist[b];
    gbase[b] = c ? atomicAdd(&cursor[set * BKT + b], c) : 0;
  }
  // exclusive scan of hist -> lbase/cur (wave 0)
  if(tid < 64){
    int running = 0;
    for(int base = 0; base < BKT; base += 64){
      int idx = base + tid;
      int v = (idx < BKT) ? hist[idx] : 0;
      int orig = v;
      #pragma unroll
      for(int off = 1; off < 64; off <<= 1){
        int t = __shfl_up(v, off, 64);
        if(tid >= off) v += t;
      }
      if(idx < BKT){ lbase[idx] = running + v - orig; cur[idx] = running + v - orig; }
      running += __shfl(v, 63, 64);
    }
  }
  __syncthreads();
  for(int i = tid; i < nE; i += 256){
    int e = e0 + i;
    int d = dst[e];
    int r = atomicAdd(&cur[d >> 7], 1);
    stage[r] = (d << 16) | src[e];
  }
  __syncthreads();
  int* bk = bucketed + (size_t)set * BKT * CAP;
  for(int i = tid; i < nE; i += 256){
    int p = stage[i];
    int b = ((unsigned int)p) >> 23;
    int pos = gbase[b] + (i - lbase[b]);
    if(pos < CAP) bk[b * CAP + pos] = p;
  }
}

__global__ void k_scanB(const int* __restrict__ cursor, int* __restrict__ bktbase,
                        int* __restrict__ indptr9){
  int set = blockIdx.x;
  __shared__ int sm[512];
  int tid = threadIdx.x;
  int v = (tid < BKT) ? cursor[set * BKT + tid] : 0;
  sm[tid] = v; __syncthreads();
  for(int off = 1; off < 512; off <<= 1){
    int t = (tid >= off) ? sm[tid - off] : 0;
    __syncthreads();
    sm[tid] += t;
    __syncthreads();
  }
  if(tid < BKT) bktbase[set * BKT + tid] = sm[tid] - v;
  if(tid == 0) indptr9[(size_t)set * (N_NODES + 1) + N_NODES] = NEDGE;
}

__global__ __launch_bounds__(256)
void k_passB(const int* __restrict__ bucketed, const int* __restrict__ cursor,
             const int* __restrict__ bktbase, int* __restrict__ indptr9,
             int* __restrict__ csr9){
  int set = blockIdx.y, b = blockIdx.x;
  int cnt = cursor[set * BKT + b]; if(cnt > CAP) cnt = CAP;
  int ebase = bktbase[set * BKT + b];
  const int* bk = bucketed + (size_t)set * BKT * CAP + b * CAP;
  __shared__ int pk[CAP];
  __shared__ int stage[CAP];
  __shared__ int h[128], sc[128], cur[128];
  int tid = threadIdx.x;
  for(int i = tid; i < cnt; i += 256) pk[i] = bk[i];
  if(tid < 128) h[tid] = 0;
  __syncthreads();
  for(int i = tid; i < cnt; i += 256) atomicAdd(&h[(pk[i] >> 16) & 127], 1);
  __syncthreads();
  if(tid < 128) sc[tid] = h[tid];
  __syncthreads();
  for(int off = 1; off < 128; off <<= 1){
    int t = 0;
    if(tid < 128 && tid >= off) t = sc[tid - off];
    __syncthreads();
    if(tid < 128) sc[tid] += t;
    __syncthreads();
  }
  if(tid < 128){
    int excl = sc[tid] - h[tid];
    cur[tid] = excl;
    int node = b * 128 + tid;
    if(node < N_NODES) indptr9[(size_t)set * (N_NODES + 1) + node] = ebase + excl;
  }
  __syncthreads();
  for(int i = tid; i < cnt; i += 256){
    int p = pk[i];
    int r = atomicAdd(&cur[(p >> 16) & 127], 1);
    stage[r] = p & 0xFFFF;
  }
  __syncthreads();
  int* out = csr9 + (size_t)set * NEDGE + ebase;
  for(int i = tid; i < cnt; i += 256) out[i] = stage[i];
}

// ================= f32 -> bf16 bulk convert =================
__global__ void k_tobf16(const float* __restrict__ in, unsigned short* __restrict__ o, int n4){
  int i = blockIdx.x * 256 + threadIdx.x;
  if(i < n4){
    float4 v = ((const float4*)in)[i];
    ushort4 u; u.x = f2b(v.x); u.y = f2b(v.y); u.z = f2b(v.z); u.w = f2b(v.w);
    ((ushort4*)o)[i] = u;
  }
}

// ================= weight pack: f32 W[k][c] -> bf16 Wt[(k>>3)*64+c][k&7] =================
struct PackJobs { const float* src[20]; int wst[20]; int K[20]; int dst[20]; int n; };

__global__ void k_wpack(PackJobs J, unsigned short* __restrict__ out){
  int j = blockIdx.x;
  if(j >= J.n) return;
  const float* s = J.src[j];
  int wst = J.wst[j], K = J.K[j];
  unsigned short* o = out + J.dst[j];
  for(int i = threadIdx.x; i < K * 64; i += 256){
    int k = i >> 6, c = i & 63;
    o[((((k >> 3) * 64) + c) << 3) + (k & 7)] = f2b(s[(size_t)k * wst + c]);
  }
}

// ================= MFMA node GEMM =================
struct MG {
  const unsigned short* Wt[4];
  const float* bias[4];
  const void* add[4];
  const float* mul[4];
  void* out[4];
  int ast, mst, ost;
};

template<int K1, int K2, int NGRP, int RELU, int HAS_ADD, int ADDB, int HAS_MUL, int OUT_BF16>
__global__ __launch_bounds__(256)
void k_mgemm(const unsigned short* __restrict__ X1, int xs1,
             const unsigned short* __restrict__ X2, int xs2, MG P){
  constexpr int K = K1 + K2;
  constexpr int KS = K / 32;
  int tid = threadIdx.x;
  int lane = tid & 63;
  int w = tid >> 6;
  int row0 = blockIdx.x * 64 + w * 16;
  int l15 = lane & 15, kg = lane >> 4;
  int arow = row0 + l15; if(arow > N_NODES - 1) arow = N_NODES - 1;
  bfrag a[KS];
  #pragma unroll
  for(int ks = 0; ks < KS; ks++){
    int kk = ks * 32 + kg * 8;
    const unsigned short* p = (kk < K1) ? (X1 + (size_t)arow * xs1 + kk)
                                        : (X2 + (size_t)arow * xs2 + (kk - K1));
    a[ks] = *(const bfrag*)p;
  }
  int orow0 = row0 + kg * 4;
  #pragma unroll
  for(int g = 0; g < NGRP; g++){
    const unsigned short* Wg = P.Wt[g];
    #pragma unroll
    for(int ct = 0; ct < 4; ct++){
      int col = ct * 16 + l15;
      ffrag acc = {0.f, 0.f, 0.f, 0.f};
      #pragma unroll
      for(int ks = 0; ks < KS; ks++){
        bfrag bf = *(const bfrag*)(Wg + (((size_t)(ks * 4 + kg) * 64 + col) << 3));
        acc = __builtin_amdgcn_mfma_f32_16x16x32_bf16(a[ks], bf, acc, 0, 0, 0);
      }
      float bv = P.bias[g] ? P.bias[g][col] : 0.f;
      #pragma unroll
      for(int i = 0; i < 4; i++){
        int r = orow0 + i;
        if(r >= N_NODES) break;
        float v = acc[i] + bv;
        if(HAS_ADD){
          if(ADDB) v += b2f(((const unsigned short*)P.add[g])[(size_t)r * P.ast + col]);
          else     v += ((const float*)P.add[g])[(size_t)r * P.ast + col];
        }
        if(RELU) v = fmaxf(v, 0.f);
        if(HAS_MUL) v *= P.mul[g][(size_t)r * P.mst + col];
        if(OUT_BF16) ((unsigned short*)P.out[g])[(size_t)r * P.ost + col] = f2b(v);
        else         ((float*)P.out[g])[(size_t)r * P.ost + col] = v;
      }
    }
  }
}

// ================= mean aggregation (quarter-wave: 4 edges in flight) =================
template<int OUTB>
__global__ void k_aggq(const unsigned short* __restrict__ TB, int tst,
                       const int* __restrict__ indptr, const int* __restrict__ csr,
                       void* __restrict__ out){
  int br = blockIdx.y;
  const unsigned short* T = TB + (size_t)br * tst;
  const int* ip = indptr + (size_t)br * (N_NODES + 1);
  const int* cs = csr + (size_t)br * NEDGE;
  int lane = threadIdx.x & 63, wid = threadIdx.x >> 6;
  int node = blockIdx.x * 4 + wid;
  if(node >= N_NODES) return;
  int q = lane >> 4, c = lane & 15;
  int beg = ip[node], end = ip[node + 1];
  int cnt = end - beg;
  float sc = 1.0f / (float)(cnt >= 1 ? cnt : 1);
  float a0 = 0.f, a1 = 0.f, a2 = 0.f, a3 = 0.f;
  for(int j = beg + q; j < end; j += 4){
    int s = cs[j];
    uint2 u = *(const uint2*)(T + (size_t)s * 64 + c * 4);
    a0 += b2f_lo(u.x); a1 += b2f_hi(u.x);
    a2 += b2f_lo(u.y); a3 += b2f_hi(u.y);
  }
  a0 += __shfl_xor(a0, 16, 64); a1 += __shfl_xor(a1, 16, 64);
  a2 += __shfl_xor(a2, 16, 64); a3 += __shfl_xor(a3, 16, 64);
  a0 += __shfl_xor(a0, 32, 64); a1 += __shfl_xor(a1, 32, 64);
  a2 += __shfl_xor(a2, 32, 64); a3 += __shfl_xor(a3, 32, 64);
  if(q == 0){
    if(OUTB){
      ushort4 o; o.x = f2b(a0 * sc); o.y = f2b(a1 * sc); o.z = f2b(a2 * sc); o.w = f2b(a3 * sc);
      *(ushort4*)((unsigned short*)out + (size_t)br * tst + (size_t)node * 64 + c * 4) = o;
    } else {
      *(float4*)((float*)out + (size_t)node * 64 + c * 4) = float4{a0 * sc, a1 * sc, a2 * sc, a3 * sc};
    }
  }
}

// ================= gating + lo =================
__global__ void k_gates_lo(const unsigned short* __restrict__ t0b, const unsigned short* __restrict__ t1b,
                           const float* __restrict__ y, const float* __restrict__ gate_W,
                           const float* __restrict__ gate_b, unsigned short* __restrict__ lo){
  int lane = threadIdx.x & 63, wid = threadIdx.x >> 6;
  int node = blockIdx.x * 4 + wid;
  if(node >= N_NODES) return;
  size_t idx = (size_t)node * 64 + lane;
  float t0v = b2f(t0b[idx]), t1v = b2f(t1b[idx]), yv = y[idx];
  float g0 = wave_red(t0v * gate_W[lane]) + gate_b[0];
  float g1 = wave_red(t1v * gate_W[64 + lane]) + gate_b[1];
  float m = fmaxf(g0, g1);
  float e0 = expf(g0 - m), e1 = expf(g1 - m);
  float a0 = e0 / (e0 + e1);
  lo[idx] = f2b(yv + a0 * t0v + (1.f - a0) * t1v);
}

// ================= constant vectors + minmax-key init =================
__global__ void k_cvec2(const float* __restrict__ ee, const float* __restrict__ ne,
                        const float* __restrict__ eaW1, const float* __restrict__ eab1,
                        const float* __restrict__ fmW, const float* __restrict__ fmb,
                        float* __restrict__ cE, float* __restrict__ cF,
                        unsigned int* __restrict__ keys){
  int j = threadIdx.x;
  if(blockIdx.x == 0){
    if(j == 0){ keys[0] = 0xFFFFFFFFu; keys[1] = 0u; }
    float s = eab1[j];
    for(int k = 0; k < 64; k++) s += ee[k] * eaW1[(128 + k) * 128 + j];
    cE[j] = s;
  } else {
    float s = fmb[j];
    for(int k = 0; k < 64; k++) s += ne[k] * fmW[(192 + k) * 128 + j];
    cF[j] = s;
  }
}

// ================= per-edge MLP (half-wave, fused sumem + minmax) =================
__global__ void k_em2(const unsigned short* __restrict__ AB,
                      const int* __restrict__ indptr, const int* __restrict__ csr_src,
                      const float* __restrict__ cvec, const float* __restrict__ W2,
                      const float* __restrict__ b2, float* __restrict__ em,
                      float* __restrict__ sumem, unsigned int* __restrict__ keys){
  int lane = threadIdx.x & 63, wid = threadIdx.x >> 6;
  int node = blockIdx.x * 4 + wid;
  if(node >= N_NODES) return;
  int h = lane >> 5, c = lane & 31;
  uint2 bu = *(const uint2*)(AB + (size_t)node * 256 + 128 + c * 4);
  float4 cv = *(const float4*)&cvec[c * 4];
  float4 wv = *(const float4*)&W2[c * 4];
  float c0 = b2f_lo(bu.x) + cv.x, c1 = b2f_hi(bu.x) + cv.y;
  float c2 = b2f_lo(bu.y) + cv.z, c3 = b2f_hi(bu.y) + cv.w;
  float b2v = b2[0];
  int beg = indptr[node], end = indptr[node + 1];
  float ssum = 0.f, mn = 3.4e38f, mx = -3.4e38f;
  for(int j = beg + h; j < end; j += 2){
    int s = csr_src[j];
    uint2 au = *(const uint2*)(AB + (size_t)s * 256 + c * 4);
    float v = fmaxf(b2f_lo(au.x) + c0, 0.f) * wv.x + fmaxf(b2f_hi(au.x) + c1, 0.f) * wv.y
            + fmaxf(b2f_lo(au.y) + c2, 0.f) * wv.z + fmaxf(b2f_hi(au.y) + c3, 0.f) * wv.w;
    #pragma unroll
    for(int off = 1; off < 32; off <<= 1) v += __shfl_xor(v, off, 64);
    if(c == 0){
      float r = v + b2v;
      em[j] = r;
      ssum += r;
      mn = fminf(mn, r); mx = fmaxf(mx, r);
    }
  }
  float so  = __shfl_xor(ssum, 32, 64);
  float mno = __shfl_xor(mn, 32, 64);
  float mxo = __shfl_xor(mx, 32, 64);
  if(lane == 0){
    sumem[node] = ssum + so;
    if(end > beg){
      atomicMin(&keys[0], fkey(fminf(mn, mno)));
      atomicMax(&keys[1], fkey(fmaxf(mx, mxo)));
    }
  }
}

// ================= scal + deg^-1/2 (O(N)) =================
__global__ void k_dinv(const int* __restrict__ indptr, const float* __restrict__ sumem,
                       const unsigned int* __restrict__ keys, float* __restrict__ scal,
                       float* __restrict__ dinv){
  int i = blockIdx.x * 256 + threadIdx.x;
  float mn = kdec(keys[0]), mx = kdec(keys[1]);
  float inv = 1.0f / fmaxf(mx - mn, 1e-30f);
  if(i == 0){ scal[0] = mn; scal[1] = inv; }
  if(i >= N_NODES) return;
  float cnt = (float)(indptr[i + 1] - indptr[i]);
  dinv[i] = rsqrtf(1.f + (sumem[i] - cnt * mn) * inv);
}

// ================= GCN layer (quarter-wave gather) =================
template<int RELU, int OUTB>
__global__ void k_gcn(const unsigned short* __restrict__ xW, const int* __restrict__ indptr,
                      const int* __restrict__ csr_src, const float* __restrict__ em,
                      const float* __restrict__ scal, const float* __restrict__ dinv,
                      const float* __restrict__ bias, void* __restrict__ out, int ostride){
  int lane = threadIdx.x & 63, wid = threadIdx.x >> 6;
  int node = blockIdx.x * 4 + wid;
  if(node >= N_NODES) return;
  int q = lane >> 4, c = lane & 15;
  float mn = scal[0], inv = scal[1];
  float di = dinv[node];
  float a0 = 0.f, a1 = 0.f, a2 = 0.f, a3 = 0.f;
  int beg = indptr[node], end = indptr[node + 1];
  for(int j = beg + q; j < end; j += 4){
    int s = csr_src[j];
    float wv = (em[j] - mn) * inv * dinv[s];
    uint2 u = *(const uint2*)(xW + (size_t)s * 64 + c * 4);
    a0 += wv * b2f_lo(u.x); a1 += wv * b2f_hi(u.x);
    a2 += wv * b2f_lo(u.y); a3 += wv * b2f_hi(u.y);
  }
  a0 += __shfl_xor(a0, 16, 64); a1 += __shfl_xor(a1, 16, 64);
  a2 += __shfl_xor(a2, 16, 64); a3 += __shfl_xor(a3, 16, 64);
  a0 += __shfl_xor(a0, 32, 64); a1 += __shfl_xor(a1, 32, 64);
  a2 += __shfl_xor(a2, 32, 64); a3 += __shfl_xor(a3, 32, 64);
  if(q == 0){
    uint2 su = *(const uint2*)(xW + (size_t)node * 64 + c * 4);
    float4 bv = *(const float4*)&bias[c * 4];
    float dd = di * di;
    float r0 = a0 * di + b2f_lo(su.x) * dd + bv.x;
    float r1 = a1 * di + b2f_hi(su.x) * dd + bv.y;
    float r2 = a2 * di + b2f_lo(su.y) * dd + bv.z;
    float r3 = a3 * di + b2f_hi(su.y) * dd + bv.w;
    if(RELU){ r0 = fmaxf(r0, 0.f); r1 = fmaxf(r1, 0.f); r2 = fmaxf(r2, 0.f); r3 = fmaxf(r3, 0.f); }
    if(OUTB){
      ushort4 o; o.x = f2b(r0); o.y = f2b(r1); o.z = f2b(r2); o.w = f2b(r3);
      *(ushort4*)((unsigned short*)out + (size_t)node * ostride + c * 4) = o;
    } else {
      *(float4*)((float*)out + (size_t)node * ostride + c * 4) = float4{r0, r1, r2, r3};
    }
  }
}

// ================= logits + log_softmax =================
__global__ void k_logits(const float* __restrict__ xt, const float* __restrict__ lin_W,
                         const float* __restrict__ lin_b, float* __restrict__ out){
  int lane = threadIdx.x & 63, wid = threadIdx.x >> 6;
  int node = blockIdx.x * 4 + wid;
  if(node >= N_NODES) return;
  float a0 = 0.f, a1 = 0.f;
  #pragma unroll
  for(int q = 0; q < 3; q++){
    int k = q * 64 + lane;
    float v = xt[(size_t)node * 192 + k];
    a0 += v * lin_W[k * 2 + 0];
    a1 += v * lin_W[k * 2 + 1];
  }
  a0 = wave_red(a0);
  a1 = wave_red(a1);
  if(lane == 0){
    float l0 = fminf(fmaxf(a0 + lin_b[0], -1e10f), 1e10f);
    float l1 = fminf(fmaxf(a1 + lin_b[1], -1e10f), 1e10f);
    float m = fmaxf(l0, l1);
    float d = expf(l0 - m) + expf(l1 - m);
    float ls = m + logf(d);
    out[(size_t)node * 2 + 0] = l0 - ls;
    out[(size_t)node * 2 + 1] = l1 - ls;
  }
}

// =====================================================================
extern "C" void kernel_launch(void* const* d_in, const int* in_sizes, int n_in,
                              void* d_out, int out_size, void* d_ws, size_t ws_size,
                              hipStream_t stream){
  (void)in_sizes; (void)n_in; (void)out_size;
  const int N = N_NODES, E = NEDGE;

  const float* x        = (const float*)d_in[0];
  const int*  edge_main = (const int*)d_in[1];
  const int*  edge_tree = (const int*)d_in[2];
  const float* sage_Wl0 = (const float*)d_in[3];
  const float* sage_Wr0 = (const float*)d_in[4];
  const float* sage_b0  = (const float*)d_in[5];
  const float* sage_Wl1 = (const float*)d_in[6];
  const float* sage_Wr1 = (const float*)d_in[7];
  const float* sage_b1  = (const float*)d_in[8];
  const float* tree_Wl  = (const float*)d_in[9];
  const float* tree_Wr  = (const float*)d_in[10];
  const float* tree_b   = (const float*)d_in[11];
  const float* gate_W   = (const float*)d_in[12];
  const float* gate_b   = (const float*)d_in[13];
  const float* node_emb = (const float*)d_in[14];
  const float* edge_emb = (const float*)d_in[15];
  const float* fm_W     = (const float*)d_in[16];
  const float* fm_b     = (const float*)d_in[17];
  const float* ea_W1    = (const float*)d_in[18];
  const float* ea_b1    = (const float*)d_in[19];
  const float* ea_W2    = (const float*)d_in[20];
  const float* ea_b2    = (const float*)d_in[21];
  const float* gcn_W0   = (const float*)d_in[22];
  const float* gcn_b0   = (const float*)d_in[23];
  const float* gcn_W1   = (const float*)d_in[24];
  const float* gcn_b1   = (const float*)d_in[25];
  const float* lin_W    = (const float*)d_in[26];
  const float* lin_b    = (const float*)d_in[27];

  float* out_lsm   = (float*)d_out;
  float* out_xtemp = (float*)d_out + (size_t)N * NCLS;

  // ---- workspace (~93.3 MB, phase-overlaid) ----
  char* ws = (char*)d_ws;
  unsigned short* TB3  = (unsigned short*)(ws + 0);          // bf16 [3][N][64] (steps 1-2)
  unsigned short* TBs  = (unsigned short*)(ws + 0);          // bf16 [N,64] (steps 3-4)
  float*          Y    = (float*)(ws + 0);                   // f32 [N,64] (steps 5-6)
  unsigned short* xW0b = (unsigned short*)(ws + 0);          // gcn phase
  unsigned short* z0b  = (unsigned short*)(ws + 6400000);
  unsigned short* xW1b = (unsigned short*)(ws + 12800000);
  unsigned short* AG3  = (unsigned short*)(ws + 19200000);   // bf16 [3][N][64] (step 2)
  float*          AG   = (float*)(ws + 19200000);            // f32 [N,64] (steps 4-5)
  unsigned short* LOb  = (unsigned short*)(ws + 25600000);   // bf16 [N,64] (steps 6-11)
  unsigned short* AB   = (unsigned short*)(ws + 0);          // bf16 [N,256] (steps 8-9)
  unsigned short* y0b  = (unsigned short*)(ws + 38400000);   // bf16 [N,64]
  unsigned short* T0b  = (unsigned short*)(ws + 44800000);
  unsigned short* T1b  = (unsigned short*)(ws + 51200000);
  unsigned short* MXb  = (unsigned short*)(ws + 38400000);   // bf16 [N,128] (steps 11-13)
  unsigned short* xb   = (unsigned short*)(ws + 57600000);   // bf16 [N,128] persistent
  int*   bucketed = (int*)(ws + 0);                          // [9][BKT][CAP] CSR phase only
  unsigned short* Wpk = (unsigned short*)(ws + 70400000);    // packed weights (~0.6MB)
  int*   csr9     = (int*)(ws + 71000064);                   // 18MB
  int*   indptr9  = (int*)(ws + 89000064);                   // 1.8MB
  float* em       = (float*)(ws + 90800128);                 // 2MB
  float* sumem    = (float*)(ws + 92800128);                 // 200KB
  float* dinv     = (float*)(ws + 93000128);                 // 200KB
  int*   cursor   = (int*)(ws + 93200128);
  int*   bktbase  = (int*)(ws + 93214208);
  float* cvecE    = (float*)(ws + 93228288);
  float* cvecF    = (float*)(ws + 93228800);
  float* scal     = (float*)(ws + 93229312);
  unsigned int* keys = (unsigned int*)(ws + 93229328);
  if(ws_size < 93229440) return;

  const int GN4 = (N + 3) / 4;
  const int GN  = (N + 255) / 256;
  const int GGM = (N + 63) / 64;
  const int NCH = (E + CHUNK - 1) / CHUNK;

  // ---- weight pack jobs ----
  PackJobs PJ[2]; PJ[0].n = 0; PJ[1].n = 0;
  int npj = 0, dstElem = 0;
  const unsigned short* WlpA[NREL]; const unsigned short* WlpB[NREL]; const unsigned short* WlpC[NREL];
  const unsigned short* Wr0j[NREL]; const unsigned short* WrT0[NREL]; const unsigned short* WrT1[NREL];
  const unsigned short* Wl1j[NREL]; const unsigned short* Wr1j[NREL];
  const unsigned short* Fm0j[NREL]; const unsigned short* Fm1j[NREL];
  const unsigned short* G0j[NREL];  const unsigned short* G1j[NREL];
  const unsigned short *EaA0, *EaA1, *EaB0, *EaB1;
  auto addjob = [&](const float* src, int wst, int K) -> const unsigned short* {
    int slot = npj < 20 ? 0 : 1;
    int k = npj - slot * 20;
    PJ[slot].src[k] = src; PJ[slot].wst[k] = wst; PJ[slot].K[k] = K; PJ[slot].dst[k] = dstElem;
    PJ[slot].n = k + 1;
    const unsigned short* ret = Wpk + dstElem;
    dstElem += K * 64; npj++;
    return ret;
  };
  for(int r = 0; r < NREL; r++){
    WlpA[r] = addjob(sage_Wl0 + (size_t)r * 8192, 64, 128);
    WlpB[r] = addjob(tree_Wl + (size_t)(r * NTREE + 0) * 8192, 64, 128);
    WlpC[r] = addjob(tree_Wl + (size_t)(r * NTREE + 1) * 8192, 64, 128);
    Wr0j[r] = addjob(sage_Wr0 + (size_t)r * 8192, 64, 128);
    WrT0[r] = addjob(tree_Wr + (size_t)(r * NTREE + 0) * 8192, 64, 128);
    WrT1[r] = addjob(tree_Wr + (size_t)(r * NTREE + 1) * 8192, 64, 128);
    Wl1j[r] = addjob(sage_Wl1 + (size_t)r * 4096, 64, 64);
    Wr1j[r] = addjob(sage_Wr1 + (size_t)r * 4096, 64, 64);
    Fm0j[r] = addjob(fm_W + (size_t)r * 32768, 128, 192);
    Fm1j[r] = addjob(fm_W + (size_t)r * 32768 + 64, 128, 192);
    G0j[r]  = addjob(gcn_W0 + (size_t)r * 8192, 64, 128);
    G1j[r]  = addjob(gcn_W1 + (size_t)r * 4096, 64, 64);
  }
  EaA0 = addjob(ea_W1, 128, 64);
  EaA1 = addjob(ea_W1 + 64, 128, 64);
  EaB0 = addjob(ea_W1 + 64 * 128, 128, 64);
  EaB1 = addjob(ea_W1 + 64 * 128 + 64, 128, 64);

  // ---- CSR build for all 9 edge sets ----
  EdgePtrs ep;
  for(int r = 0; r < NREL; r++){
    ep.s[r * 3 + 0] = edge_main + (size_t)r * 2 * E;
    ep.d[r * 3 + 0] = ep.s[r * 3 + 0] + E;
    for(int t = 0; t < NTREE; t++){
      ep.s[r * 3 + 1 + t] = edge_tree + ((size_t)(r * NTREE + t) * 2) * E;
      ep.d[r * 3 + 1 + t] = ep.s[r * 3 + 1 + t] + E;
    }
  }
  hipMemsetAsync(cursor, 0, 9 * BKT * 4, stream);
  k_passA<<<dim3(NCH, 9), 256, 0, stream>>>(ep, cursor, bucketed);
  k_scanB<<<9, 512, 0, stream>>>(cursor, bktbase, indptr9);
  k_passB<<<dim3(BKT, 9), 256, 0, stream>>>(bucketed, cursor, bktbase, indptr9, csr9);

  // ---- one-time conversions ----
  k_wpack<<<PJ[0].n, 256, 0, stream>>>(PJ[0], Wpk);
  k_wpack<<<PJ[1].n, 256, 0, stream>>>(PJ[1], Wpk);
  k_tobf16<<<(N * 128 / 4 + 255) / 256, 256, 0, stream>>>(x, xb, N * 128 / 4);

  for(int r = 0; r < NREL; r++){
    const int* ipM = indptr9 + (size_t)(r * 3) * (N + 1);
    const int* csM = csr9 + (size_t)(r * 3) * E;

    // 1. Wl-pack: TB3[br] = bf16( x @ Wl[br] ), three separate [N,64] tables
    { MG p{}; p.ost = 64;
      p.Wt[0] = WlpA[r]; p.Wt[1] = WlpB[r]; p.Wt[2] = WlpC[r];
      p.out[0] = TB3; p.out[1] = TB3 + (size_t)N * 64; p.out[2] = TB3 + (size_t)2 * N * 64;
      k_mgemm<128, 0, 3, 0, 0, 0, 0, 1><<<GGM, 256, 0, stream>>>(xb, 128, nullptr, 0, p); }

    // 2a. batched aggs for 3 branches -> AG3 (bf16)
    k_aggq<1><<<dim3(GN4, 3), 256, 0, stream>>>(TB3, N * 64, ipM, csM, AG3);
    // 2b. one NGRP=3 mgemm: y0/T0/T1 = relu(x@Wr + AG3 + b)
    { MG p{}; p.ast = 64; p.ost = 64;
      p.Wt[0] = Wr0j[r]; p.bias[0] = sage_b0 + r * 64; p.add[0] = AG3;                         p.out[0] = y0b;
      p.Wt[1] = WrT0[r]; p.bias[1] = tree_b + (size_t)(r * NTREE + 0) * 64; p.add[1] = AG3 + (size_t)N * 64;   p.out[1] = T0b;
      p.Wt[2] = WrT1[r]; p.bias[2] = tree_b + (size_t)(r * NTREE + 1) * 64; p.add[2] = AG3 + (size_t)2 * N * 64; p.out[2] = T1b;
      k_mgemm<128, 0, 3, 1, 1, 1, 0, 1><<<GGM, 256, 0, stream>>>(xb, 128, nullptr, 0, p); }

    // 3. TBs = bf16(y0 @ Wl1)
    { MG p{}; p.ost = 64; p.Wt[0] = Wl1j[r]; p.out[0] = TBs;
      k_mgemm<64, 0, 1, 0, 0, 0, 0, 1><<<GGM, 256, 0, stream>>>(y0b, 64, nullptr, 0, p); }
    // 4. AG = agg(TBs, main), f32
    k_aggq<0><<<dim3(GN4, 1), 256, 0, stream>>>(TBs, N * 64, ipM, csM, AG);
    // 5. Y = y0 @ Wr1 + AG + b1 (f32)
    { MG p{}; p.ast = 64; p.ost = 64;
      p.Wt[0] = Wr1j[r]; p.bias[0] = sage_b1 + r * 64; p.add[0] = AG; p.out[0] = Y;
      k_mgemm<64, 0, 1, 0, 1, 0, 0, 0><<<GGM, 256, 0, stream>>>(y0b, 64, nullptr, 0, p); }

    // 6. gating: lo = y + a0*t0 + a1*t1 -> bf16
    k_gates_lo<<<GN4, 256, 0, stream>>>(T0b, T1b, Y, gate_W + (size_t)r * 128, gate_b + r * 2, LOb);

    // 7. constant vectors (+ minmax key init)
    k_cvec2<<<2, 128, 0, stream>>>(edge_emb + r * 64, node_emb + r * 64, ea_W1, ea_b1,
                                   fm_W + (size_t)r * 32768, fm_b + r * 128, cvecE, cvecF, keys);

    // 8. ea-pack: AB = bf16( lo @ [A0|A1|B0|B1] )
    { MG p{}; p.ost = 256;
      p.Wt[0] = EaA0; p.Wt[1] = EaA1; p.Wt[2] = EaB0; p.Wt[3] = EaB1;
      p.out[0] = AB; p.out[1] = AB + 64; p.out[2] = AB + 128; p.out[3] = AB + 192;
      k_mgemm<64, 0, 4, 0, 0, 0, 0, 1><<<GGM, 256, 0, stream>>>(LOb, 64, nullptr, 0, p); }

    // 9. em (fused sumem + minmax atomics)
    k_em2<<<GN4, 256, 0, stream>>>(AB, ipM, csM, cvecE, ea_W2, ea_b2, em, sumem, keys);

    // 10. scal + dinv (O(N))
    k_dinv<<<GN, 256, 0, stream>>>(ipM, sumem, keys, scal, dinv);

    // 11. feature mask: MXb = bf16( x * ([lo|x]@fmW + cvecF) )
    { MG p{}; p.mst = 128; p.ost = 128;
      p.Wt[0] = Fm0j[r]; p.Wt[1] = Fm1j[r];
      p.bias[0] = cvecF; p.bias[1] = cvecF + 64;
      p.mul[0] = x; p.mul[1] = x + 64;
      p.out[0] = MXb; p.out[1] = MXb + 64;
      k_mgemm<64, 128, 2, 0, 0, 0, 1, 1><<<GGM, 256, 0, stream>>>(LOb, 64, xb, 128, p); }

    // 13-16. GCN stack
    { MG p{}; p.ost = 64; p.Wt[0] = G0j[r]; p.out[0] = xW0b;
      k_mgemm<128, 0, 1, 0, 0, 0, 0, 1><<<GGM, 256, 0, stream>>>(MXb, 128, nullptr, 0, p); }
    k_gcn<1, 1><<<GN4, 256, 0, stream>>>(xW0b, ipM, csM, em, scal, dinv, gcn_b0 + r * 64, z0b, 64);
    { MG p{}; p.ost = 64; p.Wt[0] = G1j[r]; p.out[0] = xW1b;
      k_mgemm<64, 0, 1, 0, 0, 0, 0, 1><<<GGM, 256, 0, stream>>>(z0b, 64, nullptr, 0, p); }
    k_gcn<0, 0><<<GN4, 256, 0, stream>>>(xW1b, ipM, csM, em, scal, dinv, gcn_b1 + r * 64,
                                         out_xtemp + r * 64, 192);
  }

  k_logits<<<GN4, 256, 0, stream>>>(out_xtemp, lin_W, lin_b, out_lsm);
}

// Round 7
// 987.464 us; speedup vs baseline: 4.3316x; 4.3316x over previous
//
#include <hip/hip_runtime.h>
#include <cstdint>

#define N_NODES 50000
#define FEAT    128
#define HID     64
#define NREL    3
#define NTREE   2
#define NEDGE   500000
#define NCLS    2

#define BKT   391
#define CAP   1600
#define CHUNK 8192

typedef __attribute__((ext_vector_type(8))) short bfrag;   // 8 bf16 (4 VGPR)
typedef __attribute__((ext_vector_type(4))) float ffrag;   // 4 f32 acc

__device__ __forceinline__ float wave_red(float v){
  #pragma unroll
  for(int off = 32; off > 0; off >>= 1) v += __shfl_xor(v, off, 64);
  return v;
}

__device__ __forceinline__ unsigned short f2b(float f){
  unsigned int u = __float_as_uint(f);
  unsigned int r = (u + 0x7FFFu + ((u >> 16) & 1u)) >> 16;
  return (unsigned short)r;
}
__device__ __forceinline__ float b2f_lo(unsigned int u){ return __uint_as_float(u << 16); }
__device__ __forceinline__ float b2f_hi(unsigned int u){ return __uint_as_float(u & 0xFFFF0000u); }
__device__ __forceinline__ float b2f(unsigned short s){ return __uint_as_float(((unsigned int)s) << 16); }

struct EdgePtrs { const int* s[9]; const int* d[9]; };

// ================= CSR build pass A: LDS-staged bucket sort =================
__global__ __launch_bounds__(256)
void k_passA(EdgePtrs ep, int* __restrict__ cursor, int* __restrict__ bucketed){
  int set = blockIdx.y;
  const int* src = ep.s[set];
  const int* dst = ep.d[set];
  __shared__ int stage[CHUNK];
  __shared__ int hist[BKT], gbase[BKT], lbase[BKT], cur[BKT];
  int tid = threadIdx.x;
  for(int b = tid; b < BKT; b += 256) hist[b] = 0;
  __syncthreads();
  int e0 = blockIdx.x * CHUNK;
  int nE = NEDGE - e0; if(nE > CHUNK) nE = CHUNK;
  for(int i = tid; i < nE; i += 256) atomicAdd(&hist[dst[e0 + i] >> 7], 1);
  __syncthreads();
  for(int b = tid; b < BKT; b += 256){
    int c = hist[b];
    gbase[b] = c ? atomicAdd(&cursor[set * BKT + b], c) : 0;
  }
  // exclusive scan of hist -> lbase/cur (wave 0)
  if(tid < 64){
    int running = 0;
    for(int base = 0; base < BKT; base += 64){
      int idx = base + tid;
      int v = (idx < BKT) ? hist[idx] : 0;
      int orig = v;
      #pragma unroll
      for(int off = 1; off < 64; off <<= 1){
        int t = __shfl_up(v, off, 64);
        if(tid >= off) v += t;
      }
      if(idx < BKT){ lbase[idx] = running + v - orig; cur[idx] = running + v - orig; }
      running += __shfl(v, 63, 64);
    }
  }
  __syncthreads();
  for(int i = tid; i < nE; i += 256){
    int e = e0 + i;
    int d = dst[e];
    int r = atomicAdd(&cur[d >> 7], 1);
    stage[r] = (d << 16) | src[e];
  }
  __syncthreads();
  int* bk = bucketed + (size_t)set * BKT * CAP;
  for(int i = tid; i < nE; i += 256){
    int p = stage[i];
    int b = ((unsigned int)p) >> 23;
    int pos = gbase[b] + (i - lbase[b]);
    if(pos < CAP) bk[b * CAP + pos] = p;
  }
}

__global__ void k_scanB(const int* __restrict__ cursor, int* __restrict__ bktbase,
                        int* __restrict__ indptr9){
  int set = blockIdx.x;
  __shared__ int sm[512];
  int tid = threadIdx.x;
  int v = (tid < BKT) ? cursor[set * BKT + tid] : 0;
  sm[tid] = v; __syncthreads();
  for(int off = 1; off < 512; off <<= 1){
    int t = (tid >= off) ? sm[tid - off] : 0;
    __syncthreads();
    sm[tid] += t;
    __syncthreads();
  }
  if(tid < BKT) bktbase[set * BKT + tid] = sm[tid] - v;
  if(tid == 0) indptr9[(size_t)set * (N_NODES + 1) + N_NODES] = NEDGE;
}

__global__ __launch_bounds__(256)
void k_passB(const int* __restrict__ bucketed, const int* __restrict__ cursor,
             const int* __restrict__ bktbase, int* __restrict__ indptr9,
             int* __restrict__ csr9){
  int set = blockIdx.y, b = blockIdx.x;
  int cnt = cursor[set * BKT + b]; if(cnt > CAP) cnt = CAP;
  int ebase = bktbase[set * BKT + b];
  const int* bk = bucketed + (size_t)set * BKT * CAP + b * CAP;
  __shared__ int pk[CAP];
  __shared__ int stage[CAP];
  __shared__ int h[128], sc[128], cur[128];
  int tid = threadIdx.x;
  for(int i = tid; i < cnt; i += 256) pk[i] = bk[i];
  if(tid < 128) h[tid] = 0;
  __syncthreads();
  for(int i = tid; i < cnt; i += 256) atomicAdd(&h[(pk[i] >> 16) & 127], 1);
  __syncthreads();
  if(tid < 128) sc[tid] = h[tid];
  __syncthreads();
  for(int off = 1; off < 128; off <<= 1){
    int t = 0;
    if(tid < 128 && tid >= off) t = sc[tid - off];
    __syncthreads();
    if(tid < 128) sc[tid] += t;
    __syncthreads();
  }
  if(tid < 128){
    int excl = sc[tid] - h[tid];
    cur[tid] = excl;
    int node = b * 128 + tid;
    if(node < N_NODES) indptr9[(size_t)set * (N_NODES + 1) + node] = ebase + excl;
  }
  __syncthreads();
  for(int i = tid; i < cnt; i += 256){
    int p = pk[i];
    int r = atomicAdd(&cur[(p >> 16) & 127], 1);
    stage[r] = p & 0xFFFF;
  }
  __syncthreads();
  int* out = csr9 + (size_t)set * NEDGE + ebase;
  for(int i = tid; i < cnt; i += 256) out[i] = stage[i];
}

// ================= f32 -> bf16 bulk convert =================
__global__ void k_tobf16(const float* __restrict__ in, unsigned short* __restrict__ o, int n4){
  int i = blockIdx.x * 256 + threadIdx.x;
  if(i < n4){
    float4 v = ((const float4*)in)[i];
    ushort4 u; u.x = f2b(v.x); u.y = f2b(v.y); u.z = f2b(v.z); u.w = f2b(v.w);
    ((ushort4*)o)[i] = u;
  }
}

// ================= weight pack: f32 W[k][c] -> bf16 Wt[(k>>3)*64+c][k&7] =================
struct PackJobs { const float* src[20]; int wst[20]; int K[20]; int dst[20]; int n; };

__global__ void k_wpack(PackJobs J, unsigned short* __restrict__ out){
  int j = blockIdx.x;
  if(j >= J.n) return;
  const float* s = J.src[j];
  int wst = J.wst[j], K = J.K[j];
  unsigned short* o = out + J.dst[j];
  for(int i = threadIdx.x; i < K * 64; i += 256){
    int k = i >> 6, c = i & 63;
    o[((((k >> 3) * 64) + c) << 3) + (k & 7)] = f2b(s[(size_t)k * wst + c]);
  }
}

// ================= MFMA node GEMM =================
struct MG {
  const unsigned short* Wt[4];
  const float* bias[4];
  const void* add[4];
  const float* mul[4];
  void* out[4];
  int ast, mst, ost;
};

template<int K1, int K2, int NGRP, int RELU, int HAS_ADD, int ADDB, int HAS_MUL, int OUT_BF16>
__global__ __launch_bounds__(256)
void k_mgemm(const unsigned short* __restrict__ X1, int xs1,
             const unsigned short* __restrict__ X2, int xs2, MG P){
  constexpr int K = K1 + K2;
  constexpr int KS = K / 32;
  int tid = threadIdx.x;
  int lane = tid & 63;
  int w = tid >> 6;
  int row0 = blockIdx.x * 64 + w * 16;
  int l15 = lane & 15, kg = lane >> 4;
  int arow = row0 + l15; if(arow > N_NODES - 1) arow = N_NODES - 1;
  bfrag a[KS];
  #pragma unroll
  for(int ks = 0; ks < KS; ks++){
    int kk = ks * 32 + kg * 8;
    const unsigned short* p = (kk < K1) ? (X1 + (size_t)arow * xs1 + kk)
                                        : (X2 + (size_t)arow * xs2 + (kk - K1));
    a[ks] = *(const bfrag*)p;
  }
  int orow0 = row0 + kg * 4;
  #pragma unroll
  for(int g = 0; g < NGRP; g++){
    const unsigned short* Wg = P.Wt[g];
    #pragma unroll
    for(int ct = 0; ct < 4; ct++){
      int col = ct * 16 + l15;
      ffrag acc = {0.f, 0.f, 0.f, 0.f};
      #pragma unroll
      for(int ks = 0; ks < KS; ks++){
        bfrag bf = *(const bfrag*)(Wg + (((size_t)(ks * 4 + kg) * 64 + col) << 3));
        acc = __builtin_amdgcn_mfma_f32_16x16x32_bf16(a[ks], bf, acc, 0, 0, 0);
      }
      float bv = P.bias[g] ? P.bias[g][col] : 0.f;
      #pragma unroll
      for(int i = 0; i < 4; i++){
        int r = orow0 + i;
        if(r >= N_NODES) break;
        float v = acc[i] + bv;
        if(HAS_ADD){
          if(ADDB) v += b2f(((const unsigned short*)P.add[g])[(size_t)r * P.ast + col]);
          else     v += ((const float*)P.add[g])[(size_t)r * P.ast + col];
        }
        if(RELU) v = fmaxf(v, 0.f);
        if(HAS_MUL) v *= P.mul[g][(size_t)r * P.mst + col];
        if(OUT_BF16) ((unsigned short*)P.out[g])[(size_t)r * P.ost + col] = f2b(v);
        else         ((float*)P.out[g])[(size_t)r * P.ost + col] = v;
      }
    }
  }
}

// ================= mean aggregation (quarter-wave: 4 edges in flight) =================
template<int OUTB>
__global__ void k_aggq(const unsigned short* __restrict__ TB, int tst,
                       const int* __restrict__ indptr, const int* __restrict__ csr,
                       void* __restrict__ out){
  int br = blockIdx.y;
  const unsigned short* T = TB + (size_t)br * tst;
  const int* ip = indptr + (size_t)br * (N_NODES + 1);
  const int* cs = csr + (size_t)br * NEDGE;
  int lane = threadIdx.x & 63, wid = threadIdx.x >> 6;
  int node = blockIdx.x * 4 + wid;
  if(node >= N_NODES) return;
  int q = lane >> 4, c = lane & 15;
  int beg = ip[node], end = ip[node + 1];
  int cnt = end - beg;
  float sc = 1.0f / (float)(cnt >= 1 ? cnt : 1);
  float a0 = 0.f, a1 = 0.f, a2 = 0.f, a3 = 0.f;
  for(int j = beg + q; j < end; j += 4){
    int s = cs[j];
    uint2 u = *(const uint2*)(T + (size_t)s * 64 + c * 4);
    a0 += b2f_lo(u.x); a1 += b2f_hi(u.x);
    a2 += b2f_lo(u.y); a3 += b2f_hi(u.y);
  }
  a0 += __shfl_xor(a0, 16, 64); a1 += __shfl_xor(a1, 16, 64);
  a2 += __shfl_xor(a2, 16, 64); a3 += __shfl_xor(a3, 16, 64);
  a0 += __shfl_xor(a0, 32, 64); a1 += __shfl_xor(a1, 32, 64);
  a2 += __shfl_xor(a2, 32, 64); a3 += __shfl_xor(a3, 32, 64);
  if(q == 0){
    if(OUTB){
      ushort4 o; o.x = f2b(a0 * sc); o.y = f2b(a1 * sc); o.z = f2b(a2 * sc); o.w = f2b(a3 * sc);
      *(ushort4*)((unsigned short*)out + (size_t)br * tst + (size_t)node * 64 + c * 4) = o;
    } else {
      *(float4*)((float*)out + (size_t)node * 64 + c * 4) = float4{a0 * sc, a1 * sc, a2 * sc, a3 * sc};
    }
  }
}

// ================= gating + lo =================
__global__ void k_gates_lo(const unsigned short* __restrict__ t0b, const unsigned short* __restrict__ t1b,
                           const float* __restrict__ y, const float* __restrict__ gate_W,
                           const float* __restrict__ gate_b, unsigned short* __restrict__ lo){
  int lane = threadIdx.x & 63, wid = threadIdx.x >> 6;
  int node = blockIdx.x * 4 + wid;
  if(node >= N_NODES) return;
  size_t idx = (size_t)node * 64 + lane;
  float t0v = b2f(t0b[idx]), t1v = b2f(t1b[idx]), yv = y[idx];
  float g0 = wave_red(t0v * gate_W[lane]) + gate_b[0];
  float g1 = wave_red(t1v * gate_W[64 + lane]) + gate_b[1];
  float m = fmaxf(g0, g1);
  float e0 = expf(g0 - m), e1 = expf(g1 - m);
  float a0 = e0 / (e0 + e1);
  lo[idx] = f2b(yv + a0 * t0v + (1.f - a0) * t1v);
}

// ================= constant vectors =================
__global__ void k_cvec2(const float* __restrict__ ee, const float* __restrict__ ne,
                        const float* __restrict__ eaW1, const float* __restrict__ eab1,
                        const float* __restrict__ fmW, const float* __restrict__ fmb,
                        float* __restrict__ cE, float* __restrict__ cF){
  int j = threadIdx.x;
  if(blockIdx.x == 0){
    float s = eab1[j];
    for(int k = 0; k < 64; k++) s += ee[k] * eaW1[(128 + k) * 128 + j];
    cE[j] = s;
  } else {
    float s = fmb[j];
    for(int k = 0; k < 64; k++) s += ne[k] * fmW[(192 + k) * 128 + j];
    cF[j] = s;
  }
}

// ================= per-edge MLP (half-wave, fused sumem; NO global atomics) =================
__global__ void k_em2(const unsigned short* __restrict__ AB,
                      const int* __restrict__ indptr, const int* __restrict__ csr_src,
                      const float* __restrict__ cvec, const float* __restrict__ W2,
                      const float* __restrict__ b2, float* __restrict__ em,
                      float* __restrict__ sumem){
  int lane = threadIdx.x & 63, wid = threadIdx.x >> 6;
  int node = blockIdx.x * 4 + wid;
  if(node >= N_NODES) return;
  int h = lane >> 5, c = lane & 31;
  uint2 bu = *(const uint2*)(AB + (size_t)node * 256 + 128 + c * 4);
  float4 cv = *(const float4*)&cvec[c * 4];
  float4 wv = *(const float4*)&W2[c * 4];
  float c0 = b2f_lo(bu.x) + cv.x, c1 = b2f_hi(bu.x) + cv.y;
  float c2 = b2f_lo(bu.y) + cv.z, c3 = b2f_hi(bu.y) + cv.w;
  float b2v = b2[0];
  int beg = indptr[node], end = indptr[node + 1];
  float ssum = 0.f;
  for(int j = beg + h; j < end; j += 2){
    int s = csr_src[j];
    uint2 au = *(const uint2*)(AB + (size_t)s * 256 + c * 4);
    float v = fmaxf(b2f_lo(au.x) + c0, 0.f) * wv.x + fmaxf(b2f_hi(au.x) + c1, 0.f) * wv.y
            + fmaxf(b2f_lo(au.y) + c2, 0.f) * wv.z + fmaxf(b2f_hi(au.y) + c3, 0.f) * wv.w;
    #pragma unroll
    for(int off = 1; off < 32; off <<= 1) v += __shfl_xor(v, off, 64);
    if(c == 0){
      float r = v + b2v;
      em[j] = r;
      ssum += r;
    }
  }
  float so = __shfl_xor(ssum, 32, 64);
  if(lane == 0) sumem[node] = ssum + so;
}

// ================= min/max over em =================
__global__ void k_minmax_part(const float* __restrict__ em, int n,
                              float* __restrict__ pmn, float* __restrict__ pmx){
  __shared__ float smn[256], smx[256];
  int tid = threadIdx.x;
  float mn = 3.4e38f, mx = -3.4e38f;
  for(int i = blockIdx.x * 256 + tid; i < n; i += gridDim.x * 256){
    float v = em[i];
    mn = fminf(mn, v); mx = fmaxf(mx, v);
  }
  smn[tid] = mn; smx[tid] = mx; __syncthreads();
  for(int s = 128; s > 0; s >>= 1){
    if(tid < s){ smn[tid] = fminf(smn[tid], smn[tid + s]); smx[tid] = fmaxf(smx[tid], smx[tid + s]); }
    __syncthreads();
  }
  if(tid == 0){ pmn[blockIdx.x] = smn[0]; pmx[blockIdx.x] = smx[0]; }
}

__global__ void k_minmax_final(const float* __restrict__ pmn, const float* __restrict__ pmx,
                               int nb, float* __restrict__ scal){
  __shared__ float smn[256], smx[256];
  int tid = threadIdx.x;
  float mn = 3.4e38f, mx = -3.4e38f;
  if(tid < nb){ mn = pmn[tid]; mx = pmx[tid]; }
  smn[tid] = mn; smx[tid] = mx; __syncthreads();
  for(int s = 128; s > 0; s >>= 1){
    if(tid < s){ smn[tid] = fminf(smn[tid], smn[tid + s]); smx[tid] = fmaxf(smx[tid], smx[tid + s]); }
    __syncthreads();
  }
  if(tid == 0){
    scal[0] = smn[0];
    scal[1] = 1.0f / fmaxf(smx[0] - smn[0], 1e-30f);
  }
}

// ================= scal + deg^-1/2 (O(N)) =================
__global__ void k_dinv(const int* __restrict__ indptr, const float* __restrict__ sumem,
                       const float* __restrict__ scal, float* __restrict__ dinv){
  int i = blockIdx.x * 256 + threadIdx.x;
  if(i >= N_NODES) return;
  float mn = scal[0], inv = scal[1];
  float cnt = (float)(indptr[i + 1] - indptr[i]);
  dinv[i] = rsqrtf(1.f + (sumem[i] - cnt * mn) * inv);
}

// ================= GCN layer (quarter-wave gather) =================
template<int RELU, int OUTB>
__global__ void k_gcn(const unsigned short* __restrict__ xW, const int* __restrict__ indptr,
                      const int* __restrict__ csr_src, const float* __restrict__ em,
                      const float* __restrict__ scal, const float* __restrict__ dinv,
                      const float* __restrict__ bias, void* __restrict__ out, int ostride){
  int lane = threadIdx.x & 63, wid = threadIdx.x >> 6;
  int node = blockIdx.x * 4 + wid;
  if(node >= N_NODES) return;
  int q = lane >> 4, c = lane & 15;
  float mn = scal[0], inv = scal[1];
  float di = dinv[node];
  float a0 = 0.f, a1 = 0.f, a2 = 0.f, a3 = 0.f;
  int beg = indptr[node], end = indptr[node + 1];
  for(int j = beg + q; j < end; j += 4){
    int s = csr_src[j];
    float wv = (em[j] - mn) * inv * dinv[s];
    uint2 u = *(const uint2*)(xW + (size_t)s * 64 + c * 4);
    a0 += wv * b2f_lo(u.x); a1 += wv * b2f_hi(u.x);
    a2 += wv * b2f_lo(u.y); a3 += wv * b2f_hi(u.y);
  }
  a0 += __shfl_xor(a0, 16, 64); a1 += __shfl_xor(a1, 16, 64);
  a2 += __shfl_xor(a2, 16, 64); a3 += __shfl_xor(a3, 16, 64);
  a0 += __shfl_xor(a0, 32, 64); a1 += __shfl_xor(a1, 32, 64);
  a2 += __shfl_xor(a2, 32, 64); a3 += __shfl_xor(a3, 32, 64);
  if(q == 0){
    uint2 su = *(const uint2*)(xW + (size_t)node * 64 + c * 4);
    float4 bv = *(const float4*)&bias[c * 4];
    float dd = di * di;
    float r0 = a0 * di + b2f_lo(su.x) * dd + bv.x;
    float r1 = a1 * di + b2f_hi(su.x) * dd + bv.y;
    float r2 = a2 * di + b2f_lo(su.y) * dd + bv.z;
    float r3 = a3 * di + b2f_hi(su.y) * dd + bv.w;
    if(RELU){ r0 = fmaxf(r0, 0.f); r1 = fmaxf(r1, 0.f); r2 = fmaxf(r2, 0.f); r3 = fmaxf(r3, 0.f); }
    if(OUTB){
      ushort4 o; o.x = f2b(r0); o.y = f2b(r1); o.z = f2b(r2); o.w = f2b(r3);
      *(ushort4*)((unsigned short*)out + (size_t)node * ostride + c * 4) = o;
    } else {
      *(float4*)((float*)out + (size_t)node * ostride + c * 4) = float4{r0, r1, r2, r3};
    }
  }
}

// ================= logits + log_softmax =================
__global__ void k_logits(const float* __restrict__ xt, const float* __restrict__ lin_W,
                         const float* __restrict__ lin_b, float* __restrict__ out){
  int lane = threadIdx.x & 63, wid = threadIdx.x >> 6;
  int node = blockIdx.x * 4 + wid;
  if(node >= N_NODES) return;
  float a0 = 0.f, a1 = 0.f;
  #pragma unroll
  for(int q = 0; q < 3; q++){
    int k = q * 64 + lane;
    float v = xt[(size_t)node * 192 + k];
    a0 += v * lin_W[k * 2 + 0];
    a1 += v * lin_W[k * 2 + 1];
  }
  a0 = wave_red(a0);
  a1 = wave_red(a1);
  if(lane == 0){
    float l0 = fminf(fmaxf(a0 + lin_b[0], -1e10f), 1e10f);
    float l1 = fminf(fmaxf(a1 + lin_b[1], -1e10f), 1e10f);
    float m = fmaxf(l0, l1);
    float d = expf(l0 - m) + expf(l1 - m);
    float ls = m + logf(d);
    out[(size_t)node * 2 + 0] = l0 - ls;
    out[(size_t)node * 2 + 1] = l1 - ls;
  }
}

// =====================================================================
extern "C" void kernel_launch(void* const* d_in, const int* in_sizes, int n_in,
                              void* d_out, int out_size, void* d_ws, size_t ws_size,
                              hipStream_t stream){
  (void)in_sizes; (void)n_in; (void)out_size;
  const int N = N_NODES, E = NEDGE;

  const float* x        = (const float*)d_in[0];
  const int*  edge_main = (const int*)d_in[1];
  const int*  edge_tree = (const int*)d_in[2];
  const float* sage_Wl0 = (const float*)d_in[3];
  const float* sage_Wr0 = (const float*)d_in[4];
  const float* sage_b0  = (const float*)d_in[5];
  const float* sage_Wl1 = (const float*)d_in[6];
  const float* sage_Wr1 = (const float*)d_in[7];
  const float* sage_b1  = (const float*)d_in[8];
  const float* tree_Wl  = (const float*)d_in[9];
  const float* tree_Wr  = (const float*)d_in[10];
  const float* tree_b   = (const float*)d_in[11];
  const float* gate_W   = (const float*)d_in[12];
  const float* gate_b   = (const float*)d_in[13];
  const float* node_emb = (const float*)d_in[14];
  const float* edge_emb = (const float*)d_in[15];
  const float* fm_W     = (const float*)d_in[16];
  const float* fm_b     = (const float*)d_in[17];
  const float* ea_W1    = (const float*)d_in[18];
  const float* ea_b1    = (const float*)d_in[19];
  const float* ea_W2    = (const float*)d_in[20];
  const float* ea_b2    = (const float*)d_in[21];
  const float* gcn_W0   = (const float*)d_in[22];
  const float* gcn_b0   = (const float*)d_in[23];
  const float* gcn_W1   = (const float*)d_in[24];
  const float* gcn_b1   = (const float*)d_in[25];
  const float* lin_W    = (const float*)d_in[26];
  const float* lin_b    = (const float*)d_in[27];

  float* out_lsm   = (float*)d_out;
  float* out_xtemp = (float*)d_out + (size_t)N * NCLS;

  // ---- workspace (~93.3 MB, phase-overlaid) ----
  char* ws = (char*)d_ws;
  unsigned short* TB3  = (unsigned short*)(ws + 0);          // bf16 [3][N][64] (steps 1-2)
  unsigned short* TBs  = (unsigned short*)(ws + 0);          // bf16 [N,64] (steps 3-4)
  float*          Y    = (float*)(ws + 0);                   // f32 [N,64] (steps 5-6)
  unsigned short* xW0b = (unsigned short*)(ws + 0);          // gcn phase
  unsigned short* z0b  = (unsigned short*)(ws + 6400000);
  unsigned short* xW1b = (unsigned short*)(ws + 12800000);
  unsigned short* AG3  = (unsigned short*)(ws + 19200000);   // bf16 [3][N][64] (step 2)
  float*          AG   = (float*)(ws + 19200000);            // f32 [N,64] (steps 4-5)
  unsigned short* LOb  = (unsigned short*)(ws + 25600000);   // bf16 [N,64] (steps 6-11)
  unsigned short* AB   = (unsigned short*)(ws + 0);          // bf16 [N,256] (steps 8-9)
  unsigned short* y0b  = (unsigned short*)(ws + 38400000);   // bf16 [N,64]
  unsigned short* T0b  = (unsigned short*)(ws + 44800000);
  unsigned short* T1b  = (unsigned short*)(ws + 51200000);
  unsigned short* MXb  = (unsigned short*)(ws + 38400000);   // bf16 [N,128] (steps 11-13)
  unsigned short* xb   = (unsigned short*)(ws + 57600000);   // bf16 [N,128] persistent
  int*   bucketed = (int*)(ws + 0);                          // [9][BKT][CAP] CSR phase only
  unsigned short* Wpk = (unsigned short*)(ws + 70400000);    // packed weights (~0.6MB)
  int*   csr9     = (int*)(ws + 71000064);                   // 18MB
  int*   indptr9  = (int*)(ws + 89000064);                   // 1.8MB
  float* em       = (float*)(ws + 90800128);                 // 2MB
  float* sumem    = (float*)(ws + 92800128);                 // 200KB
  float* dinv     = (float*)(ws + 93000128);                 // 200KB
  int*   cursor   = (int*)(ws + 93200128);
  int*   bktbase  = (int*)(ws + 93214208);
  float* cvecE    = (float*)(ws + 93228288);
  float* cvecF    = (float*)(ws + 93228800);
  float* scal     = (float*)(ws + 93229312);
  float* pmn      = (float*)(ws + 93229568);                 // 1KB
  float* pmx      = (float*)(ws + 93230592);                 // 1KB
  if(ws_size < 93231616) return;

  const int GN4 = (N + 3) / 4;
  const int GN  = (N + 255) / 256;
  const int GGM = (N + 63) / 64;
  const int NCH = (E + CHUNK - 1) / CHUNK;

  // ---- weight pack jobs ----
  PackJobs PJ[2]; PJ[0].n = 0; PJ[1].n = 0;
  int npj = 0, dstElem = 0;
  const unsigned short* WlpA[NREL]; const unsigned short* WlpB[NREL]; const unsigned short* WlpC[NREL];
  const unsigned short* Wr0j[NREL]; const unsigned short* WrT0[NREL]; const unsigned short* WrT1[NREL];
  const unsigned short* Wl1j[NREL]; const unsigned short* Wr1j[NREL];
  const unsigned short* Fm0j[NREL]; const unsigned short* Fm1j[NREL];
  const unsigned short* G0j[NREL];  const unsigned short* G1j[NREL];
  const unsigned short *EaA0, *EaA1, *EaB0, *EaB1;
  auto addjob = [&](const float* src, int wst, int K) -> const unsigned short* {
    int slot = npj < 20 ? 0 : 1;
    int k = npj - slot * 20;
    PJ[slot].src[k] = src; PJ[slot].wst[k] = wst; PJ[slot].K[k] = K; PJ[slot].dst[k] = dstElem;
    PJ[slot].n = k + 1;
    const unsigned short* ret = Wpk + dstElem;
    dstElem += K * 64; npj++;
    return ret;
  };
  for(int r = 0; r < NREL; r++){
    WlpA[r] = addjob(sage_Wl0 + (size_t)r * 8192, 64, 128);
    WlpB[r] = addjob(tree_Wl + (size_t)(r * NTREE + 0) * 8192, 64, 128);
    WlpC[r] = addjob(tree_Wl + (size_t)(r * NTREE + 1) * 8192, 64, 128);
    Wr0j[r] = addjob(sage_Wr0 + (size_t)r * 8192, 64, 128);
    WrT0[r] = addjob(tree_Wr + (size_t)(r * NTREE + 0) * 8192, 64, 128);
    WrT1[r] = addjob(tree_Wr + (size_t)(r * NTREE + 1) * 8192, 64, 128);
    Wl1j[r] = addjob(sage_Wl1 + (size_t)r * 4096, 64, 64);
    Wr1j[r] = addjob(sage_Wr1 + (size_t)r * 4096, 64, 64);
    Fm0j[r] = addjob(fm_W + (size_t)r * 32768, 128, 192);
    Fm1j[r] = addjob(fm_W + (size_t)r * 32768 + 64, 128, 192);
    G0j[r]  = addjob(gcn_W0 + (size_t)r * 8192, 64, 128);
    G1j[r]  = addjob(gcn_W1 + (size_t)r * 4096, 64, 64);
  }
  EaA0 = addjob(ea_W1, 128, 64);
  EaA1 = addjob(ea_W1 + 64, 128, 64);
  EaB0 = addjob(ea_W1 + 64 * 128, 128, 64);
  EaB1 = addjob(ea_W1 + 64 * 128 + 64, 128, 64);

  // ---- CSR build for all 9 edge sets ----
  EdgePtrs ep;
  for(int r = 0; r < NREL; r++){
    ep.s[r * 3 + 0] = edge_main + (size_t)r * 2 * E;
    ep.d[r * 3 + 0] = ep.s[r * 3 + 0] + E;
    for(int t = 0; t < NTREE; t++){
      ep.s[r * 3 + 1 + t] = edge_tree + ((size_t)(r * NTREE + t) * 2) * E;
      ep.d[r * 3 + 1 + t] = ep.s[r * 3 + 1 + t] + E;
    }
  }
  hipMemsetAsync(cursor, 0, 9 * BKT * 4, stream);
  k_passA<<<dim3(NCH, 9), 256, 0, stream>>>(ep, cursor, bucketed);
  k_scanB<<<9, 512, 0, stream>>>(cursor, bktbase, indptr9);
  k_passB<<<dim3(BKT, 9), 256, 0, stream>>>(bucketed, cursor, bktbase, indptr9, csr9);

  // ---- one-time conversions ----
  k_wpack<<<PJ[0].n, 256, 0, stream>>>(PJ[0], Wpk);
  k_wpack<<<PJ[1].n, 256, 0, stream>>>(PJ[1], Wpk);
  k_tobf16<<<(N * 128 / 4 + 255) / 256, 256, 0, stream>>>(x, xb, N * 128 / 4);

  for(int r = 0; r < NREL; r++){
    const int* ipM = indptr9 + (size_t)(r * 3) * (N + 1);
    const int* csM = csr9 + (size_t)(r * 3) * E;

    // 1. Wl-pack: TB3[br] = bf16( x @ Wl[br] ), three separate [N,64] tables
    { MG p{}; p.ost = 64;
      p.Wt[0] = WlpA[r]; p.Wt[1] = WlpB[r]; p.Wt[2] = WlpC[r];
      p.out[0] = TB3; p.out[1] = TB3 + (size_t)N * 64; p.out[2] = TB3 + (size_t)2 * N * 64;
      k_mgemm<128, 0, 3, 0, 0, 0, 0, 1><<<GGM, 256, 0, stream>>>(xb, 128, nullptr, 0, p); }

    // 2a. batched aggs for 3 branches -> AG3 (bf16)
    k_aggq<1><<<dim3(GN4, 3), 256, 0, stream>>>(TB3, N * 64, ipM, csM, AG3);
    // 2b. one NGRP=3 mgemm: y0/T0/T1 = relu(x@Wr + AG3 + b)
    { MG p{}; p.ast = 64; p.ost = 64;
      p.Wt[0] = Wr0j[r]; p.bias[0] = sage_b0 + r * 64; p.add[0] = AG3;                         p.out[0] = y0b;
      p.Wt[1] = WrT0[r]; p.bias[1] = tree_b + (size_t)(r * NTREE + 0) * 64; p.add[1] = AG3 + (size_t)N * 64;   p.out[1] = T0b;
      p.Wt[2] = WrT1[r]; p.bias[2] = tree_b + (size_t)(r * NTREE + 1) * 64; p.add[2] = AG3 + (size_t)2 * N * 64; p.out[2] = T1b;
      k_mgemm<128, 0, 3, 1, 1, 1, 0, 1><<<GGM, 256, 0, stream>>>(xb, 128, nullptr, 0, p); }

    // 3. TBs = bf16(y0 @ Wl1)
    { MG p{}; p.ost = 64; p.Wt[0] = Wl1j[r]; p.out[0] = TBs;
      k_mgemm<64, 0, 1, 0, 0, 0, 0, 1><<<GGM, 256, 0, stream>>>(y0b, 64, nullptr, 0, p); }
    // 4. AG = agg(TBs, main), f32
    k_aggq<0><<<dim3(GN4, 1), 256, 0, stream>>>(TBs, N * 64, ipM, csM, AG);
    // 5. Y = y0 @ Wr1 + AG + b1 (f32)
    { MG p{}; p.ast = 64; p.ost = 64;
      p.Wt[0] = Wr1j[r]; p.bias[0] = sage_b1 + r * 64; p.add[0] = AG; p.out[0] = Y;
      k_mgemm<64, 0, 1, 0, 1, 0, 0, 0><<<GGM, 256, 0, stream>>>(y0b, 64, nullptr, 0, p); }

    // 6. gating: lo = y + a0*t0 + a1*t1 -> bf16
    k_gates_lo<<<GN4, 256, 0, stream>>>(T0b, T1b, Y, gate_W + (size_t)r * 128, gate_b + r * 2, LOb);

    // 7. constant vectors
    k_cvec2<<<2, 128, 0, stream>>>(edge_emb + r * 64, node_emb + r * 64, ea_W1, ea_b1,
                                   fm_W + (size_t)r * 32768, fm_b + r * 128, cvecE, cvecF);

    // 8. ea-pack: AB = bf16( lo @ [A0|A1|B0|B1] )
    { MG p{}; p.ost = 256;
      p.Wt[0] = EaA0; p.Wt[1] = EaA1; p.Wt[2] = EaB0; p.Wt[3] = EaB1;
      p.out[0] = AB; p.out[1] = AB + 64; p.out[2] = AB + 128; p.out[3] = AB + 192;
      k_mgemm<64, 0, 4, 0, 0, 0, 0, 1><<<GGM, 256, 0, stream>>>(LOb, 64, nullptr, 0, p); }

    // 9. em (fused sumem)
    k_em2<<<GN4, 256, 0, stream>>>(AB, ipM, csM, cvecE, ea_W2, ea_b2, em, sumem);

    // 9b. min/max over em (two-pass, contention-free)
    k_minmax_part<<<256, 256, 0, stream>>>(em, E, pmn, pmx);
    k_minmax_final<<<1, 256, 0, stream>>>(pmn, pmx, 256, scal);

    // 10. dinv (O(N))
    k_dinv<<<GN, 256, 0, stream>>>(ipM, sumem, scal, dinv);

    // 11. feature mask: MXb = bf16( x * ([lo|x]@fmW + cvecF) )
    { MG p{}; p.mst = 128; p.ost = 128;
      p.Wt[0] = Fm0j[r]; p.Wt[1] = Fm1j[r];
      p.bias[0] = cvecF; p.bias[1] = cvecF + 64;
      p.mul[0] = x; p.mul[1] = x + 64;
      p.out[0] = MXb; p.out[1] = MXb + 64;
      k_mgemm<64, 128, 2, 0, 0, 0, 1, 1><<<GGM, 256, 0, stream>>>(LOb, 64, xb, 128, p); }

    // 13-16. GCN stack
    { MG p{}; p.ost = 64; p.Wt[0] = G0j[r]; p.out[0] = xW0b;
      k_mgemm<128, 0, 1, 0, 0, 0, 0, 1><<<GGM, 256, 0, stream>>>(MXb, 128, nullptr, 0, p); }
    k_gcn<1, 1><<<GN4, 256, 0, stream>>>(xW0b, ipM, csM, em, scal, dinv, gcn_b0 + r * 64, z0b, 64);
    { MG p{}; p.ost = 64; p.Wt[0] = G1j[r]; p.out[0] = xW1b;
      k_mgemm<64, 0, 1, 0, 0, 0, 0, 1><<<GGM, 256, 0, stream>>>(z0b, 64, nullptr, 0, p); }
    k_gcn<0, 0><<<GN4, 256, 0, stream>>>(xW1b, ipM, csM, em, scal, dinv, gcn_b1 + r * 64,
                                         out_xtemp + r * 64, 192);
  }

  k_logits<<<GN4, 256, 0, stream>>>(out_xtemp, lin_W, lin_b, out_lsm);
}

// Round 8
// 913.656 us; speedup vs baseline: 4.6815x; 1.0808x over previous
//
#include <hip/hip_runtime.h>
#include <cstdint>

#define N_NODES 50000
#define FEAT    128
#define HID     64
#define NREL    3
#define NTREE   2
#define NEDGE   500000
#define NCLS    2

#define BKT   391
#define CAP   1600
#define CHUNK 4096

typedef __attribute__((ext_vector_type(8))) short bfrag;   // 8 bf16 (4 VGPR)
typedef __attribute__((ext_vector_type(4))) float ffrag;   // 4 f32 acc

__device__ __forceinline__ float wave_red(float v){
  #pragma unroll
  for(int off = 32; off > 0; off >>= 1) v += __shfl_xor(v, off, 64);
  return v;
}

__device__ __forceinline__ unsigned short f2b(float f){
  unsigned int u = __float_as_uint(f);
  unsigned int r = (u + 0x7FFFu + ((u >> 16) & 1u)) >> 16;
  return (unsigned short)r;
}
__device__ __forceinline__ float b2f_lo(unsigned int u){ return __uint_as_float(u << 16); }
__device__ __forceinline__ float b2f_hi(unsigned int u){ return __uint_as_float(u & 0xFFFF0000u); }
__device__ __forceinline__ float b2f(unsigned short s){ return __uint_as_float(((unsigned int)s) << 16); }

struct EdgePtrs { const int* s[9]; const int* d[9]; };

// ================= CSR build pass A: LDS-staged bucket sort =================
__global__ __launch_bounds__(256)
void k_passA(EdgePtrs ep, int* __restrict__ cursor, int* __restrict__ bucketed){
  int set = blockIdx.y;
  const int* src = ep.s[set];
  const int* dst = ep.d[set];
  __shared__ int stage[CHUNK];
  __shared__ int hist[BKT], gbase[BKT], lbase[BKT], cur[BKT];
  int tid = threadIdx.x;
  for(int b = tid; b < BKT; b += 256) hist[b] = 0;
  __syncthreads();
  int e0 = blockIdx.x * CHUNK;
  int nE = NEDGE - e0; if(nE > CHUNK) nE = CHUNK;
  for(int i = tid; i < nE; i += 256) atomicAdd(&hist[dst[e0 + i] >> 7], 1);
  __syncthreads();
  for(int b = tid; b < BKT; b += 256){
    int c = hist[b];
    gbase[b] = c ? atomicAdd(&cursor[set * BKT + b], c) : 0;
  }
  // exclusive scan of hist -> lbase/cur (wave 0)
  if(tid < 64){
    int running = 0;
    for(int base = 0; base < BKT; base += 64){
      int idx = base + tid;
      int v = (idx < BKT) ? hist[idx] : 0;
      int orig = v;
      #pragma unroll
      for(int off = 1; off < 64; off <<= 1){
        int t = __shfl_up(v, off, 64);
        if(tid >= off) v += t;
      }
      if(idx < BKT){ lbase[idx] = running + v - orig; cur[idx] = running + v - orig; }
      running += __shfl(v, 63, 64);
    }
  }
  __syncthreads();
  for(int i = tid; i < nE; i += 256){
    int e = e0 + i;
    int d = dst[e];
    int r = atomicAdd(&cur[d >> 7], 1);
    stage[r] = (d << 16) | src[e];
  }
  __syncthreads();
  int* bk = bucketed + (size_t)set * BKT * CAP;
  for(int i = tid; i < nE; i += 256){
    int p = stage[i];
    int b = ((unsigned int)p) >> 23;
    int pos = gbase[b] + (i - lbase[b]);
    if(pos < CAP) bk[b * CAP + pos] = p;
  }
}

__global__ void k_scanB(const int* __restrict__ cursor, int* __restrict__ bktbase,
                        int* __restrict__ indptr9){
  int set = blockIdx.x;
  __shared__ int sm[512];
  int tid = threadIdx.x;
  int v = (tid < BKT) ? cursor[set * BKT + tid] : 0;
  sm[tid] = v; __syncthreads();
  for(int off = 1; off < 512; off <<= 1){
    int t = (tid >= off) ? sm[tid - off] : 0;
    __syncthreads();
    sm[tid] += t;
    __syncthreads();
  }
  if(tid < BKT) bktbase[set * BKT + tid] = sm[tid] - v;
  if(tid == 0) indptr9[(size_t)set * (N_NODES + 1) + N_NODES] = NEDGE;
}

__global__ __launch_bounds__(256)
void k_passB(const int* __restrict__ bucketed, const int* __restrict__ cursor,
             const int* __restrict__ bktbase, int* __restrict__ indptr9,
             int* __restrict__ csr9){
  int set = blockIdx.y, b = blockIdx.x;
  int cnt = cursor[set * BKT + b]; if(cnt > CAP) cnt = CAP;
  int ebase = bktbase[set * BKT + b];
  const int* bk = bucketed + (size_t)set * BKT * CAP + b * CAP;
  __shared__ int pk[CAP];
  __shared__ int stage[CAP];
  __shared__ int h[128], sc[128], cur[128];
  int tid = threadIdx.x;
  for(int i = tid; i < cnt; i += 256) pk[i] = bk[i];
  if(tid < 128) h[tid] = 0;
  __syncthreads();
  for(int i = tid; i < cnt; i += 256) atomicAdd(&h[(pk[i] >> 16) & 127], 1);
  __syncthreads();
  if(tid < 128) sc[tid] = h[tid];
  __syncthreads();
  for(int off = 1; off < 128; off <<= 1){
    int t = 0;
    if(tid < 128 && tid >= off) t = sc[tid - off];
    __syncthreads();
    if(tid < 128) sc[tid] += t;
    __syncthreads();
  }
  if(tid < 128){
    int excl = sc[tid] - h[tid];
    cur[tid] = excl;
    int node = b * 128 + tid;
    if(node < N_NODES) indptr9[(size_t)set * (N_NODES + 1) + node] = ebase + excl;
  }
  __syncthreads();
  for(int i = tid; i < cnt; i += 256){
    int p = pk[i];
    int r = atomicAdd(&cur[(p >> 16) & 127], 1);
    stage[r] = p & 0xFFFF;
  }
  __syncthreads();
  int* out = csr9 + (size_t)set * NEDGE + ebase;
  for(int i = tid; i < cnt; i += 256) out[i] = stage[i];
}

// ================= f32 -> bf16 bulk convert =================
__global__ void k_tobf16(const float* __restrict__ in, unsigned short* __restrict__ o, int n4){
  int i = blockIdx.x * 256 + threadIdx.x;
  if(i < n4){
    float4 v = ((const float4*)in)[i];
    ushort4 u; u.x = f2b(v.x); u.y = f2b(v.y); u.z = f2b(v.z); u.w = f2b(v.w);
    ((ushort4*)o)[i] = u;
  }
}

// ================= weight pack: f32 W[k][c] -> bf16 Wt[(k>>3)*64+c][k&7] =================
struct PackJobs { const float* src[20]; int wst[20]; int K[20]; int dst[20]; int n; };

__global__ void k_wpack(PackJobs J, unsigned short* __restrict__ out){
  int j = blockIdx.x;
  if(j >= J.n) return;
  const float* s = J.src[j];
  int wst = J.wst[j], K = J.K[j];
  unsigned short* o = out + J.dst[j];
  for(int i = threadIdx.x; i < K * 64; i += 256){
    int k = i >> 6, c = i & 63;
    o[((((k >> 3) * 64) + c) << 3) + (k & 7)] = f2b(s[(size_t)k * wst + c]);
  }
}

// ================= MFMA node GEMM =================
struct MG {
  const unsigned short* Wt[4];
  const float* bias[4];
  const void* add[4];
  const float* mul[4];
  void* out[4];
  int ast, mst, ost;
};

template<int K1, int K2, int NGRP, int RELU, int HAS_ADD, int ADDB, int HAS_MUL, int OUT_BF16>
__global__ __launch_bounds__(256)
void k_mgemm(const unsigned short* __restrict__ X1, int xs1,
             const unsigned short* __restrict__ X2, int xs2, MG P){
  constexpr int K = K1 + K2;
  constexpr int KS = K / 32;
  int tid = threadIdx.x;
  int lane = tid & 63;
  int w = tid >> 6;
  int row0 = blockIdx.x * 64 + w * 16;
  int l15 = lane & 15, kg = lane >> 4;
  int arow = row0 + l15; if(arow > N_NODES - 1) arow = N_NODES - 1;
  bfrag a[KS];
  #pragma unroll
  for(int ks = 0; ks < KS; ks++){
    int kk = ks * 32 + kg * 8;
    const unsigned short* p = (kk < K1) ? (X1 + (size_t)arow * xs1 + kk)
                                        : (X2 + (size_t)arow * xs2 + (kk - K1));
    a[ks] = *(const bfrag*)p;
  }
  int orow0 = row0 + kg * 4;
  #pragma unroll
  for(int g = 0; g < NGRP; g++){
    const unsigned short* Wg = P.Wt[g];
    #pragma unroll
    for(int ct = 0; ct < 4; ct++){
      int col = ct * 16 + l15;
      ffrag acc = {0.f, 0.f, 0.f, 0.f};
      #pragma unroll
      for(int ks = 0; ks < KS; ks++){
        bfrag bf = *(const bfrag*)(Wg + (((size_t)(ks * 4 + kg) * 64 + col) << 3));
        acc = __builtin_amdgcn_mfma_f32_16x16x32_bf16(a[ks], bf, acc, 0, 0, 0);
      }
      float bv = P.bias[g] ? P.bias[g][col] : 0.f;
      #pragma unroll
      for(int i = 0; i < 4; i++){
        int r = orow0 + i;
        if(r >= N_NODES) break;
        float v = acc[i] + bv;
        if(HAS_ADD){
          if(ADDB) v += b2f(((const unsigned short*)P.add[g])[(size_t)r * P.ast + col]);
          else     v += ((const float*)P.add[g])[(size_t)r * P.ast + col];
        }
        if(RELU) v = fmaxf(v, 0.f);
        if(HAS_MUL) v *= P.mul[g][(size_t)r * P.mst + col];
        if(OUT_BF16) ((unsigned short*)P.out[g])[(size_t)r * P.ost + col] = f2b(v);
        else         ((float*)P.out[g])[(size_t)r * P.ost + col] = v;
      }
    }
  }
}

// ================= fused AB + MX GEMM (shared A-operand LOb|xb) =================
struct ABMX {
  const unsigned short* Wea[4]; // K=64 packs
  const unsigned short* Wfm[2]; // K=192 packs
  const float* cF;
  const float* xf32;
  unsigned short* ab;   // [N][256]
  unsigned short* mx;   // [N][128]
};

__global__ __launch_bounds__(256)
void k_abmx(const unsigned short* __restrict__ LOb, const unsigned short* __restrict__ xb, ABMX P){
  int tid = threadIdx.x, lane = tid & 63, w = tid >> 6;
  int row0 = blockIdx.x * 64 + w * 16;
  int l15 = lane & 15, kg = lane >> 4;
  int arow = row0 + l15; if(arow > N_NODES - 1) arow = N_NODES - 1;
  bfrag a[6];
  a[0] = *(const bfrag*)(LOb + (size_t)arow * 64 + kg * 8);
  a[1] = *(const bfrag*)(LOb + (size_t)arow * 64 + 32 + kg * 8);
  #pragma unroll
  for(int ks = 0; ks < 4; ks++)
    a[2 + ks] = *(const bfrag*)(xb + (size_t)arow * 128 + ks * 32 + kg * 8);
  int orow0 = row0 + kg * 4;
  #pragma unroll
  for(int g = 0; g < 4; g++){
    const unsigned short* Wg = P.Wea[g];
    #pragma unroll
    for(int ct = 0; ct < 4; ct++){
      int col = ct * 16 + l15;
      ffrag acc = {0.f, 0.f, 0.f, 0.f};
      bfrag b0 = *(const bfrag*)(Wg + (((size_t)(0 * 4 + kg) * 64 + col) << 3));
      bfrag b1 = *(const bfrag*)(Wg + (((size_t)(1 * 4 + kg) * 64 + col) << 3));
      acc = __builtin_amdgcn_mfma_f32_16x16x32_bf16(a[0], b0, acc, 0, 0, 0);
      acc = __builtin_amdgcn_mfma_f32_16x16x32_bf16(a[1], b1, acc, 0, 0, 0);
      #pragma unroll
      for(int i = 0; i < 4; i++){
        int r = orow0 + i;
        if(r >= N_NODES) break;
        P.ab[(size_t)r * 256 + g * 64 + col] = f2b(acc[i]);
      }
    }
  }
  #pragma unroll
  for(int g = 0; g < 2; g++){
    const unsigned short* Wg = P.Wfm[g];
    #pragma unroll
    for(int ct = 0; ct < 4; ct++){
      int col = ct * 16 + l15;
      ffrag acc = {0.f, 0.f, 0.f, 0.f};
      #pragma unroll
      for(int ks = 0; ks < 6; ks++){
        bfrag bf = *(const bfrag*)(Wg + (((size_t)(ks * 4 + kg) * 64 + col) << 3));
        acc = __builtin_amdgcn_mfma_f32_16x16x32_bf16(a[ks], bf, acc, 0, 0, 0);
      }
      float bv = P.cF[g * 64 + col];
      #pragma unroll
      for(int i = 0; i < 4; i++){
        int r = orow0 + i;
        if(r >= N_NODES) break;
        float v = (acc[i] + bv) * P.xf32[(size_t)r * 128 + g * 64 + col];
        P.mx[(size_t)r * 128 + g * 64 + col] = f2b(v);
      }
    }
  }
}

// ================= mean aggregation (quarter-wave, 2x unrolled) =================
template<int OUTB>
__global__ void k_aggq(const unsigned short* __restrict__ TB, int tst,
                       const int* __restrict__ indptr, const int* __restrict__ csr,
                       void* __restrict__ out){
  int br = blockIdx.y;
  const unsigned short* T = TB + (size_t)br * tst;
  const int* ip = indptr + (size_t)br * (N_NODES + 1);
  const int* cs = csr + (size_t)br * NEDGE;
  int lane = threadIdx.x & 63, wid = threadIdx.x >> 6;
  int node = blockIdx.x * 4 + wid;
  if(node >= N_NODES) return;
  int q = lane >> 4, c = lane & 15;
  int beg = ip[node], end = ip[node + 1];
  int cnt = end - beg;
  float sc = 1.0f / (float)(cnt >= 1 ? cnt : 1);
  float a0 = 0.f, a1 = 0.f, a2 = 0.f, a3 = 0.f;
  int j = beg + q;
  for(; j + 4 < end; j += 8){
    int s0 = cs[j], s1 = cs[j + 4];
    uint2 u0 = *(const uint2*)(T + (size_t)s0 * 64 + c * 4);
    uint2 u1 = *(const uint2*)(T + (size_t)s1 * 64 + c * 4);
    a0 += b2f_lo(u0.x) + b2f_lo(u1.x); a1 += b2f_hi(u0.x) + b2f_hi(u1.x);
    a2 += b2f_lo(u0.y) + b2f_lo(u1.y); a3 += b2f_hi(u0.y) + b2f_hi(u1.y);
  }
  if(j < end){
    int s = cs[j];
    uint2 u = *(const uint2*)(T + (size_t)s * 64 + c * 4);
    a0 += b2f_lo(u.x); a1 += b2f_hi(u.x);
    a2 += b2f_lo(u.y); a3 += b2f_hi(u.y);
  }
  a0 += __shfl_xor(a0, 16, 64); a1 += __shfl_xor(a1, 16, 64);
  a2 += __shfl_xor(a2, 16, 64); a3 += __shfl_xor(a3, 16, 64);
  a0 += __shfl_xor(a0, 32, 64); a1 += __shfl_xor(a1, 32, 64);
  a2 += __shfl_xor(a2, 32, 64); a3 += __shfl_xor(a3, 32, 64);
  if(q == 0){
    if(OUTB){
      ushort4 o; o.x = f2b(a0 * sc); o.y = f2b(a1 * sc); o.z = f2b(a2 * sc); o.w = f2b(a3 * sc);
      *(ushort4*)((unsigned short*)out + (size_t)br * tst + (size_t)node * 64 + c * 4) = o;
    } else {
      *(float4*)((float*)out + (size_t)node * 64 + c * 4) = float4{a0 * sc, a1 * sc, a2 * sc, a3 * sc};
    }
  }
}

// ================= gating + lo (+ constant vectors in extra blocks) =================
__global__ void k_gates_cvec(const unsigned short* __restrict__ t0b, const unsigned short* __restrict__ t1b,
                             const float* __restrict__ y, const float* __restrict__ gate_W,
                             const float* __restrict__ gate_b, unsigned short* __restrict__ lo,
                             const float* __restrict__ ee, const float* __restrict__ ne,
                             const float* __restrict__ eaW1, const float* __restrict__ eab1,
                             const float* __restrict__ fmW, const float* __restrict__ fmb,
                             float* __restrict__ cE, float* __restrict__ cF, int gn4){
  if(blockIdx.x >= gn4){
    int which = blockIdx.x - gn4;
    int j = threadIdx.x;
    if(j < 128){
      if(which == 0){
        float s = eab1[j];
        for(int k = 0; k < 64; k++) s += ee[k] * eaW1[(128 + k) * 128 + j];
        cE[j] = s;
      } else {
        float s = fmb[j];
        for(int k = 0; k < 64; k++) s += ne[k] * fmW[(192 + k) * 128 + j];
        cF[j] = s;
      }
    }
    return;
  }
  int lane = threadIdx.x & 63, wid = threadIdx.x >> 6;
  int node = blockIdx.x * 4 + wid;
  if(node >= N_NODES) return;
  size_t idx = (size_t)node * 64 + lane;
  float t0v = b2f(t0b[idx]), t1v = b2f(t1b[idx]), yv = y[idx];
  float g0 = wave_red(t0v * gate_W[lane]) + gate_b[0];
  float g1 = wave_red(t1v * gate_W[64 + lane]) + gate_b[1];
  float m = fmaxf(g0, g1);
  float e0 = expf(g0 - m), e1 = expf(g1 - m);
  float a0 = e0 / (e0 + e1);
  lo[idx] = f2b(yv + a0 * t0v + (1.f - a0) * t1v);
}

// ================= per-edge MLP (half-wave, 2x unroll, fused sumem + block minmax) =================
__global__ void k_em2(const unsigned short* __restrict__ AB,
                      const int* __restrict__ indptr, const int* __restrict__ csr_src,
                      const float* __restrict__ cvec, const float* __restrict__ W2,
                      const float* __restrict__ b2, float* __restrict__ em,
                      float* __restrict__ sumem, float* __restrict__ pmn, float* __restrict__ pmx){
  int lane = threadIdx.x & 63, wid = threadIdx.x >> 6;
  int node = blockIdx.x * 4 + wid;
  bool act = (node < N_NODES);
  float mn = 3.4e38f, mx = -3.4e38f;
  if(act){
    int h = lane >> 5, c = lane & 31;
    uint2 bu = *(const uint2*)(AB + (size_t)node * 256 + 128 + c * 4);
    float4 cv = *(const float4*)&cvec[c * 4];
    float4 wv = *(const float4*)&W2[c * 4];
    float c0 = b2f_lo(bu.x) + cv.x, c1 = b2f_hi(bu.x) + cv.y;
    float c2 = b2f_lo(bu.y) + cv.z, c3 = b2f_hi(bu.y) + cv.w;
    float b2v = b2[0];
    int beg = indptr[node], end = indptr[node + 1];
    float ssum = 0.f;
    int j = beg + h;
    for(; j + 2 < end; j += 4){
      int s0 = csr_src[j], s1 = csr_src[j + 2];
      uint2 au0 = *(const uint2*)(AB + (size_t)s0 * 256 + c * 4);
      uint2 au1 = *(const uint2*)(AB + (size_t)s1 * 256 + c * 4);
      float v0 = fmaxf(b2f_lo(au0.x) + c0, 0.f) * wv.x + fmaxf(b2f_hi(au0.x) + c1, 0.f) * wv.y
               + fmaxf(b2f_lo(au0.y) + c2, 0.f) * wv.z + fmaxf(b2f_hi(au0.y) + c3, 0.f) * wv.w;
      float v1 = fmaxf(b2f_lo(au1.x) + c0, 0.f) * wv.x + fmaxf(b2f_hi(au1.x) + c1, 0.f) * wv.y
               + fmaxf(b2f_lo(au1.y) + c2, 0.f) * wv.z + fmaxf(b2f_hi(au1.y) + c3, 0.f) * wv.w;
      #pragma unroll
      for(int off = 1; off < 32; off <<= 1){
        v0 += __shfl_xor(v0, off, 64);
        v1 += __shfl_xor(v1, off, 64);
      }
      if(c == 0){
        float r0 = v0 + b2v, r1 = v1 + b2v;
        em[j] = r0; em[j + 2] = r1;
        ssum += r0 + r1;
        mn = fminf(mn, fminf(r0, r1)); mx = fmaxf(mx, fmaxf(r0, r1));
      }
    }
    if(j < end){
      int s = csr_src[j];
      uint2 au = *(const uint2*)(AB + (size_t)s * 256 + c * 4);
      float v = fmaxf(b2f_lo(au.x) + c0, 0.f) * wv.x + fmaxf(b2f_hi(au.x) + c1, 0.f) * wv.y
              + fmaxf(b2f_lo(au.y) + c2, 0.f) * wv.z + fmaxf(b2f_hi(au.y) + c3, 0.f) * wv.w;
      #pragma unroll
      for(int off = 1; off < 32; off <<= 1) v += __shfl_xor(v, off, 64);
      if(c == 0){
        float r = v + b2v;
        em[j] = r;
        ssum += r;
        mn = fminf(mn, r); mx = fmaxf(mx, r);
      }
    }
    float so = __shfl_xor(ssum, 32, 64);
    if(lane == 0) sumem[node] = ssum + so;
    mn = fminf(mn, __shfl_xor(mn, 32, 64));
    mx = fmaxf(mx, __shfl_xor(mx, 32, 64));
  }
  // block-level min/max partials (no global atomics)
  __shared__ float bmn[4], bmx[4];
  if(lane == 0){ bmn[wid] = mn; bmx[wid] = mx; }
  __syncthreads();
  if(threadIdx.x == 0){
    pmn[blockIdx.x] = fminf(fminf(bmn[0], bmn[1]), fminf(bmn[2], bmn[3]));
    pmx[blockIdx.x] = fmaxf(fmaxf(bmx[0], bmx[1]), fmaxf(bmx[2], bmx[3]));
  }
}

// ================= final min/max over block partials =================
__global__ void k_minmax_final(const float* __restrict__ pmn, const float* __restrict__ pmx,
                               int nb, float* __restrict__ scal){
  __shared__ float smn[256], smx[256];
  int tid = threadIdx.x;
  float mn = 3.4e38f, mx = -3.4e38f;
  for(int i = tid; i < nb; i += 256){
    mn = fminf(mn, pmn[i]); mx = fmaxf(mx, pmx[i]);
  }
  smn[tid] = mn; smx[tid] = mx; __syncthreads();
  for(int s = 128; s > 0; s >>= 1){
    if(tid < s){ smn[tid] = fminf(smn[tid], smn[tid + s]); smx[tid] = fmaxf(smx[tid], smx[tid + s]); }
    __syncthreads();
  }
  if(tid == 0){
    scal[0] = smn[0];
    scal[1] = 1.0f / fmaxf(smx[0] - smn[0], 1e-30f);
  }
}

// ================= scal + deg^-1/2 (O(N)) =================
__global__ void k_dinv(const int* __restrict__ indptr, const float* __restrict__ sumem,
                       const float* __restrict__ scal, float* __restrict__ dinv){
  int i = blockIdx.x * 256 + threadIdx.x;
  if(i >= N_NODES) return;
  float mn = scal[0], inv = scal[1];
  float cnt = (float)(indptr[i + 1] - indptr[i]);
  dinv[i] = rsqrtf(1.f + (sumem[i] - cnt * mn) * inv);
}

// ================= GCN layer (quarter-wave gather, 2x unroll) =================
template<int RELU, int OUTB>
__global__ void k_gcn(const unsigned short* __restrict__ xW, const int* __restrict__ indptr,
                      const int* __restrict__ csr_src, const float* __restrict__ em,
                      const float* __restrict__ scal, const float* __restrict__ dinv,
                      const float* __restrict__ bias, void* __restrict__ out, int ostride){
  int lane = threadIdx.x & 63, wid = threadIdx.x >> 6;
  int node = blockIdx.x * 4 + wid;
  if(node >= N_NODES) return;
  int q = lane >> 4, c = lane & 15;
  float mn = scal[0], inv = scal[1];
  float di = dinv[node];
  float a0 = 0.f, a1 = 0.f, a2 = 0.f, a3 = 0.f;
  int beg = indptr[node], end = indptr[node + 1];
  int j = beg + q;
  for(; j + 4 < end; j += 8){
    int s0 = csr_src[j], s1 = csr_src[j + 4];
    float w0 = (em[j] - mn) * inv * dinv[s0];
    float w1 = (em[j + 4] - mn) * inv * dinv[s1];
    uint2 u0 = *(const uint2*)(xW + (size_t)s0 * 64 + c * 4);
    uint2 u1 = *(const uint2*)(xW + (size_t)s1 * 64 + c * 4);
    a0 += w0 * b2f_lo(u0.x) + w1 * b2f_lo(u1.x);
    a1 += w0 * b2f_hi(u0.x) + w1 * b2f_hi(u1.x);
    a2 += w0 * b2f_lo(u0.y) + w1 * b2f_lo(u1.y);
    a3 += w0 * b2f_hi(u0.y) + w1 * b2f_hi(u1.y);
  }
  if(j < end){
    int s = csr_src[j];
    float wv = (em[j] - mn) * inv * dinv[s];
    uint2 u = *(const uint2*)(xW + (size_t)s * 64 + c * 4);
    a0 += wv * b2f_lo(u.x); a1 += wv * b2f_hi(u.x);
    a2 += wv * b2f_lo(u.y); a3 += wv * b2f_hi(u.y);
  }
  a0 += __shfl_xor(a0, 16, 64); a1 += __shfl_xor(a1, 16, 64);
  a2 += __shfl_xor(a2, 16, 64); a3 += __shfl_xor(a3, 16, 64);
  a0 += __shfl_xor(a0, 32, 64); a1 += __shfl_xor(a1, 32, 64);
  a2 += __shfl_xor(a2, 32, 64); a3 += __shfl_xor(a3, 32, 64);
  if(q == 0){
    uint2 su = *(const uint2*)(xW + (size_t)node * 64 + c * 4);
    float4 bv = *(const float4*)&bias[c * 4];
    float dd = di * di;
    float r0 = a0 * di + b2f_lo(su.x) * dd + bv.x;
    float r1 = a1 * di + b2f_hi(su.x) * dd + bv.y;
    float r2 = a2 * di + b2f_lo(su.y) * dd + bv.z;
    float r3 = a3 * di + b2f_hi(su.y) * dd + bv.w;
    if(RELU){ r0 = fmaxf(r0, 0.f); r1 = fmaxf(r1, 0.f); r2 = fmaxf(r2, 0.f); r3 = fmaxf(r3, 0.f); }
    if(OUTB){
      ushort4 o; o.x = f2b(r0); o.y = f2b(r1); o.z = f2b(r2); o.w = f2b(r3);
      *(ushort4*)((unsigned short*)out + (size_t)node * ostride + c * 4) = o;
    } else {
      *(float4*)((float*)out + (size_t)node * ostride + c * 4) = float4{r0, r1, r2, r3};
    }
  }
}

// ================= logits + log_softmax =================
__global__ void k_logits(const float* __restrict__ xt, const float* __restrict__ lin_W,
                         const float* __restrict__ lin_b, float* __restrict__ out){
  int lane = threadIdx.x & 63, wid = threadIdx.x >> 6;
  int node = blockIdx.x * 4 + wid;
  if(node >= N_NODES) return;
  float a0 = 0.f, a1 = 0.f;
  #pragma unroll
  for(int q = 0; q < 3; q++){
    int k = q * 64 + lane;
    float v = xt[(size_t)node * 192 + k];
    a0 += v * lin_W[k * 2 + 0];
    a1 += v * lin_W[k * 2 + 1];
  }
  a0 = wave_red(a0);
  a1 = wave_red(a1);
  if(lane == 0){
    float l0 = fminf(fmaxf(a0 + lin_b[0], -1e10f), 1e10f);
    float l1 = fminf(fmaxf(a1 + lin_b[1], -1e10f), 1e10f);
    float m = fmaxf(l0, l1);
    float d = expf(l0 - m) + expf(l1 - m);
    float ls = m + logf(d);
    out[(size_t)node * 2 + 0] = l0 - ls;
    out[(size_t)node * 2 + 1] = l1 - ls;
  }
}

// =====================================================================
extern "C" void kernel_launch(void* const* d_in, const int* in_sizes, int n_in,
                              void* d_out, int out_size, void* d_ws, size_t ws_size,
                              hipStream_t stream){
  (void)in_sizes; (void)n_in; (void)out_size;
  const int N = N_NODES, E = NEDGE;

  const float* x        = (const float*)d_in[0];
  const int*  edge_main = (const int*)d_in[1];
  const int*  edge_tree = (const int*)d_in[2];
  const float* sage_Wl0 = (const float*)d_in[3];
  const float* sage_Wr0 = (const float*)d_in[4];
  const float* sage_b0  = (const float*)d_in[5];
  const float* sage_Wl1 = (const float*)d_in[6];
  const float* sage_Wr1 = (const float*)d_in[7];
  const float* sage_b1  = (const float*)d_in[8];
  const float* tree_Wl  = (const float*)d_in[9];
  const float* tree_Wr  = (const float*)d_in[10];
  const float* tree_b   = (const float*)d_in[11];
  const float* gate_W   = (const float*)d_in[12];
  const float* gate_b   = (const float*)d_in[13];
  const float* node_emb = (const float*)d_in[14];
  const float* edge_emb = (const float*)d_in[15];
  const float* fm_W     = (const float*)d_in[16];
  const float* fm_b     = (const float*)d_in[17];
  const float* ea_W1    = (const float*)d_in[18];
  const float* ea_b1    = (const float*)d_in[19];
  const float* ea_W2    = (const float*)d_in[20];
  const float* ea_b2    = (const float*)d_in[21];
  const float* gcn_W0   = (const float*)d_in[22];
  const float* gcn_b0   = (const float*)d_in[23];
  const float* gcn_W1   = (const float*)d_in[24];
  const float* gcn_b1   = (const float*)d_in[25];
  const float* lin_W    = (const float*)d_in[26];
  const float* lin_b    = (const float*)d_in[27];

  float* out_lsm   = (float*)d_out;
  float* out_xtemp = (float*)d_out + (size_t)N * NCLS;

  // ---- workspace (~93.4 MB, phase-overlaid) ----
  char* ws = (char*)d_ws;
  unsigned short* TB3  = (unsigned short*)(ws + 0);          // bf16 [3][N][64] (steps 1-2)
  unsigned short* TBs  = (unsigned short*)(ws + 0);          // bf16 [N,64] (steps 3-4)
  float*          Y    = (float*)(ws + 0);                   // f32 [N,64] (steps 5-6)
  unsigned short* xW0b = (unsigned short*)(ws + 0);          // gcn phase
  unsigned short* z0b  = (unsigned short*)(ws + 6400000);
  unsigned short* xW1b = (unsigned short*)(ws + 12800000);
  unsigned short* AG3  = (unsigned short*)(ws + 19200000);   // bf16 [3][N][64] (step 2)
  float*          AG   = (float*)(ws + 19200000);            // f32 [N,64] (steps 4-5)
  unsigned short* LOb  = (unsigned short*)(ws + 25600000);   // bf16 [N,64] (steps 6-11)
  unsigned short* AB   = (unsigned short*)(ws + 0);          // bf16 [N,256] (steps 8-9)
  unsigned short* y0b  = (unsigned short*)(ws + 38400000);   // bf16 [N,64]
  unsigned short* T0b  = (unsigned short*)(ws + 44800000);
  unsigned short* T1b  = (unsigned short*)(ws + 51200000);
  unsigned short* MXb  = (unsigned short*)(ws + 38400000);   // bf16 [N,128] (steps 11-13)
  unsigned short* xb   = (unsigned short*)(ws + 57600000);   // bf16 [N,128] persistent
  int*   bucketed = (int*)(ws + 0);                          // [9][BKT][CAP] CSR phase only
  unsigned short* Wpk = (unsigned short*)(ws + 70400000);    // packed weights (~0.6MB)
  int*   csr9     = (int*)(ws + 71000064);                   // 18MB
  int*   indptr9  = (int*)(ws + 89000064);                   // 1.8MB
  float* em       = (float*)(ws + 90800128);                 // 2MB
  float* sumem    = (float*)(ws + 92800128);                 // 200KB
  float* dinv     = (float*)(ws + 93000128);                 // 200KB
  int*   cursor   = (int*)(ws + 93200128);
  int*   bktbase  = (int*)(ws + 93214208);
  float* cvecE    = (float*)(ws + 93228288);
  float* cvecF    = (float*)(ws + 93228800);
  float* scal     = (float*)(ws + 93229312);
  float* pmn      = (float*)(ws + 93229568);                 // 50KB (12500 blocks)
  float* pmx      = (float*)(ws + 93279568);                 // 50KB
  if(ws_size < 93330000) return;

  const int GN4 = (N + 3) / 4;
  const int GN  = (N + 255) / 256;
  const int GGM = (N + 63) / 64;
  const int NCH = (E + CHUNK - 1) / CHUNK;

  // ---- weight pack jobs ----
  PackJobs PJ[2]; PJ[0].n = 0; PJ[1].n = 0;
  int npj = 0, dstElem = 0;
  const unsigned short* WlpA[NREL]; const unsigned short* WlpB[NREL]; const unsigned short* WlpC[NREL];
  const unsigned short* Wr0j[NREL]; const unsigned short* WrT0[NREL]; const unsigned short* WrT1[NREL];
  const unsigned short* Wl1j[NREL]; const unsigned short* Wr1j[NREL];
  const unsigned short* Fm0j[NREL]; const unsigned short* Fm1j[NREL];
  const unsigned short* G0j[NREL];  const unsigned short* G1j[NREL];
  const unsigned short *EaA0, *EaA1, *EaB0, *EaB1;
  auto addjob = [&](const float* src, int wst, int K) -> const unsigned short* {
    int slot = npj < 20 ? 0 : 1;
    int k = npj - slot * 20;
    PJ[slot].src[k] = src; PJ[slot].wst[k] = wst; PJ[slot].K[k] = K; PJ[slot].dst[k] = dstElem;
    PJ[slot].n = k + 1;
    const unsigned short* ret = Wpk + dstElem;
    dstElem += K * 64; npj++;
    return ret;
  };
  for(int r = 0; r < NREL; r++){
    WlpA[r] = addjob(sage_Wl0 + (size_t)r * 8192, 64, 128);
    WlpB[r] = addjob(tree_Wl + (size_t)(r * NTREE + 0) * 8192, 64, 128);
    WlpC[r] = addjob(tree_Wl + (size_t)(r * NTREE + 1) * 8192, 64, 128);
    Wr0j[r] = addjob(sage_Wr0 + (size_t)r * 8192, 64, 128);
    WrT0[r] = addjob(tree_Wr + (size_t)(r * NTREE + 0) * 8192, 64, 128);
    WrT1[r] = addjob(tree_Wr + (size_t)(r * NTREE + 1) * 8192, 64, 128);
    Wl1j[r] = addjob(sage_Wl1 + (size_t)r * 4096, 64, 64);
    Wr1j[r] = addjob(sage_Wr1 + (size_t)r * 4096, 64, 64);
    Fm0j[r] = addjob(fm_W + (size_t)r * 32768, 128, 192);
    Fm1j[r] = addjob(fm_W + (size_t)r * 32768 + 64, 128, 192);
    G0j[r]  = addjob(gcn_W0 + (size_t)r * 8192, 64, 128);
    G1j[r]  = addjob(gcn_W1 + (size_t)r * 4096, 64, 64);
  }
  EaA0 = addjob(ea_W1, 128, 64);
  EaA1 = addjob(ea_W1 + 64, 128, 64);
  EaB0 = addjob(ea_W1 + 64 * 128, 128, 64);
  EaB1 = addjob(ea_W1 + 64 * 128 + 64, 128, 64);

  // ---- CSR build for all 9 edge sets ----
  EdgePtrs ep;
  for(int r = 0; r < NREL; r++){
    ep.s[r * 3 + 0] = edge_main + (size_t)r * 2 * E;
    ep.d[r * 3 + 0] = ep.s[r * 3 + 0] + E;
    for(int t = 0; t < NTREE; t++){
      ep.s[r * 3 + 1 + t] = edge_tree + ((size_t)(r * NTREE + t) * 2) * E;
      ep.d[r * 3 + 1 + t] = ep.s[r * 3 + 1 + t] + E;
    }
  }
  hipMemsetAsync(cursor, 0, 9 * BKT * 4, stream);
  k_passA<<<dim3(NCH, 9), 256, 0, stream>>>(ep, cursor, bucketed);
  k_scanB<<<9, 512, 0, stream>>>(cursor, bktbase, indptr9);
  k_passB<<<dim3(BKT, 9), 256, 0, stream>>>(bucketed, cursor, bktbase, indptr9, csr9);

  // ---- one-time conversions ----
  k_wpack<<<PJ[0].n, 256, 0, stream>>>(PJ[0], Wpk);
  k_wpack<<<PJ[1].n, 256, 0, stream>>>(PJ[1], Wpk);
  k_tobf16<<<(N * 128 / 4 + 255) / 256, 256, 0, stream>>>(x, xb, N * 128 / 4);

  for(int r = 0; r < NREL; r++){
    const int* ipM = indptr9 + (size_t)(r * 3) * (N + 1);
    const int* csM = csr9 + (size_t)(r * 3) * E;

    // 1. Wl-pack: TB3[br] = bf16( x @ Wl[br] )
    { MG p{}; p.ost = 64;
      p.Wt[0] = WlpA[r]; p.Wt[1] = WlpB[r]; p.Wt[2] = WlpC[r];
      p.out[0] = TB3; p.out[1] = TB3 + (size_t)N * 64; p.out[2] = TB3 + (size_t)2 * N * 64;
      k_mgemm<128, 0, 3, 0, 0, 0, 0, 1><<<GGM, 256, 0, stream>>>(xb, 128, nullptr, 0, p); }

    // 2a. batched aggs for 3 branches -> AG3 (bf16)
    k_aggq<1><<<dim3(GN4, 3), 256, 0, stream>>>(TB3, N * 64, ipM, csM, AG3);
    // 2b. one NGRP=3 mgemm: y0/T0/T1 = relu(x@Wr + AG3 + b)
    { MG p{}; p.ast = 64; p.ost = 64;
      p.Wt[0] = Wr0j[r]; p.bias[0] = sage_b0 + r * 64; p.add[0] = AG3;                         p.out[0] = y0b;
      p.Wt[1] = WrT0[r]; p.bias[1] = tree_b + (size_t)(r * NTREE + 0) * 64; p.add[1] = AG3 + (size_t)N * 64;   p.out[1] = T0b;
      p.Wt[2] = WrT1[r]; p.bias[2] = tree_b + (size_t)(r * NTREE + 1) * 64; p.add[2] = AG3 + (size_t)2 * N * 64; p.out[2] = T1b;
      k_mgemm<128, 0, 3, 1, 1, 1, 0, 1><<<GGM, 256, 0, stream>>>(xb, 128, nullptr, 0, p); }

    // 3. TBs = bf16(y0 @ Wl1)
    { MG p{}; p.ost = 64; p.Wt[0] = Wl1j[r]; p.out[0] = TBs;
      k_mgemm<64, 0, 1, 0, 0, 0, 0, 1><<<GGM, 256, 0, stream>>>(y0b, 64, nullptr, 0, p); }
    // 4. AG = agg(TBs, main), f32
    k_aggq<0><<<dim3(GN4, 1), 256, 0, stream>>>(TBs, N * 64, ipM, csM, AG);
    // 5. Y = y0 @ Wr1 + AG + b1 (f32)
    { MG p{}; p.ast = 64; p.ost = 64;
      p.Wt[0] = Wr1j[r]; p.bias[0] = sage_b1 + r * 64; p.add[0] = AG; p.out[0] = Y;
      k_mgemm<64, 0, 1, 0, 1, 0, 0, 0><<<GGM, 256, 0, stream>>>(y0b, 64, nullptr, 0, p); }

    // 6+7. gating -> lo, plus cvecE/cvecF in 2 extra blocks
    k_gates_cvec<<<GN4 + 2, 256, 0, stream>>>(T0b, T1b, Y, gate_W + (size_t)r * 128,
                                              gate_b + r * 2, LOb,
                                              edge_emb + r * 64, node_emb + r * 64,
                                              ea_W1, ea_b1, fm_W + (size_t)r * 32768,
                                              fm_b + r * 128, cvecE, cvecF, GN4);

    // 8+11. fused: AB = bf16(lo@Ea*), MXb = bf16(x * ([lo|x]@fmW + cvecF))
    { ABMX p{};
      p.Wea[0] = EaA0; p.Wea[1] = EaA1; p.Wea[2] = EaB0; p.Wea[3] = EaB1;
      p.Wfm[0] = Fm0j[r]; p.Wfm[1] = Fm1j[r];
      p.cF = cvecF; p.xf32 = x; p.ab = AB; p.mx = MXb;
      k_abmx<<<GGM, 256, 0, stream>>>(LOb, xb, p); }

    // 9. em (fused sumem + block min/max partials)
    k_em2<<<GN4, 256, 0, stream>>>(AB, ipM, csM, cvecE, ea_W2, ea_b2, em, sumem, pmn, pmx);

    // 9b. final min/max over partials
    k_minmax_final<<<1, 256, 0, stream>>>(pmn, pmx, GN4, scal);

    // 10. dinv (O(N))
    k_dinv<<<GN, 256, 0, stream>>>(ipM, sumem, scal, dinv);

    // 13-16. GCN stack
    { MG p{}; p.ost = 64; p.Wt[0] = G0j[r]; p.out[0] = xW0b;
      k_mgemm<128, 0, 1, 0, 0, 0, 0, 1><<<GGM, 256, 0, stream>>>(MXb, 128, nullptr, 0, p); }
    k_gcn<1, 1><<<GN4, 256, 0, stream>>>(xW0b, ipM, csM, em, scal, dinv, gcn_b0 + r * 64, z0b, 64);
    { MG p{}; p.ost = 64; p.Wt[0] = G1j[r]; p.out[0] = xW1b;
      k_mgemm<64, 0, 1, 0, 0, 0, 0, 1><<<GGM, 256, 0, stream>>>(z0b, 64, nullptr, 0, p); }
    k_gcn<0, 0><<<GN4, 256, 0, stream>>>(xW1b, ipM, csM, em, scal, dinv, gcn_b1 + r * 64,
                                         out_xtemp + r * 64, 192);
  }

  k_logits<<<GN4, 256, 0, stream>>>(out_xtemp, lin_W, lin_b, out_lsm);
}

// Round 9
// 892.455 us; speedup vs baseline: 4.7928x; 1.0238x over previous
//
#include <hip/hip_runtime.h>
#include <cstdint>

#define N_NODES 50000
#define FEAT    128
#define HID     64
#define NREL    3
#define NTREE   2
#define NEDGE   500000
#define NCLS    2

#define BKT   391
#define CAP   1600
#define CHUNK 4096

typedef __attribute__((ext_vector_type(8))) short bfrag;   // 8 bf16 (4 VGPR)
typedef __attribute__((ext_vector_type(4))) float ffrag;   // 4 f32 acc

__device__ __forceinline__ float wave_red(float v){
  #pragma unroll
  for(int off = 32; off > 0; off >>= 1) v += __shfl_xor(v, off, 64);
  return v;
}

__device__ __forceinline__ unsigned short f2b(float f){
  unsigned int u = __float_as_uint(f);
  unsigned int r = (u + 0x7FFFu + ((u >> 16) & 1u)) >> 16;
  return (unsigned short)r;
}
__device__ __forceinline__ float b2f_lo(unsigned int u){ return __uint_as_float(u << 16); }
__device__ __forceinline__ float b2f_hi(unsigned int u){ return __uint_as_float(u & 0xFFFF0000u); }
__device__ __forceinline__ float b2f(unsigned short s){ return __uint_as_float(((unsigned int)s) << 16); }
__device__ __forceinline__ unsigned int pk2(float lo, float hi){
  return ((unsigned int)f2b(hi) << 16) | f2b(lo);
}

struct EdgePtrs { const int* s[9]; const int* d[9]; };

// ================= CSR build pass A: LDS-staged bucket sort =================
__global__ __launch_bounds__(256)
void k_passA(EdgePtrs ep, int* __restrict__ cursor, int* __restrict__ bucketed){
  int set = blockIdx.y;
  const int* src = ep.s[set];
  const int* dst = ep.d[set];
  __shared__ int stage[CHUNK];
  __shared__ int hist[BKT], gbase[BKT], lbase[BKT], cur[BKT];
  int tid = threadIdx.x;
  for(int b = tid; b < BKT; b += 256) hist[b] = 0;
  __syncthreads();
  int e0 = blockIdx.x * CHUNK;
  int nE = NEDGE - e0; if(nE > CHUNK) nE = CHUNK;
  for(int i = tid; i < nE; i += 256) atomicAdd(&hist[dst[e0 + i] >> 7], 1);
  __syncthreads();
  for(int b = tid; b < BKT; b += 256){
    int c = hist[b];
    gbase[b] = c ? atomicAdd(&cursor[set * BKT + b], c) : 0;
  }
  if(tid < 64){
    int running = 0;
    for(int base = 0; base < BKT; base += 64){
      int idx = base + tid;
      int v = (idx < BKT) ? hist[idx] : 0;
      int orig = v;
      #pragma unroll
      for(int off = 1; off < 64; off <<= 1){
        int t = __shfl_up(v, off, 64);
        if(tid >= off) v += t;
      }
      if(idx < BKT){ lbase[idx] = running + v - orig; cur[idx] = running + v - orig; }
      running += __shfl(v, 63, 64);
    }
  }
  __syncthreads();
  for(int i = tid; i < nE; i += 256){
    int e = e0 + i;
    int d = dst[e];
    int r = atomicAdd(&cur[d >> 7], 1);
    stage[r] = (d << 16) | src[e];
  }
  __syncthreads();
  int* bk = bucketed + (size_t)set * BKT * CAP;
  for(int i = tid; i < nE; i += 256){
    int p = stage[i];
    int b = ((unsigned int)p) >> 23;
    int pos = gbase[b] + (i - lbase[b]);
    if(pos < CAP) bk[b * CAP + pos] = p;
  }
}

__global__ void k_scanB(const int* __restrict__ cursor, int* __restrict__ bktbase,
                        int* __restrict__ indptr9){
  int set = blockIdx.x;
  __shared__ int sm[512];
  int tid = threadIdx.x;
  int v = (tid < BKT) ? cursor[set * BKT + tid] : 0;
  sm[tid] = v; __syncthreads();
  for(int off = 1; off < 512; off <<= 1){
    int t = (tid >= off) ? sm[tid - off] : 0;
    __syncthreads();
    sm[tid] += t;
    __syncthreads();
  }
  if(tid < BKT) bktbase[set * BKT + tid] = sm[tid] - v;
  if(tid == 0) indptr9[(size_t)set * (N_NODES + 1) + N_NODES] = NEDGE;
}

__global__ __launch_bounds__(256)
void k_passB(const int* __restrict__ bucketed, const int* __restrict__ cursor,
             const int* __restrict__ bktbase, int* __restrict__ indptr9,
             int* __restrict__ csr9){
  int set = blockIdx.y, b = blockIdx.x;
  int cnt = cursor[set * BKT + b]; if(cnt > CAP) cnt = CAP;
  int ebase = bktbase[set * BKT + b];
  const int* bk = bucketed + (size_t)set * BKT * CAP + b * CAP;
  __shared__ int pk[CAP];
  __shared__ int stage[CAP];
  __shared__ int h[128], sc[128], cur[128];
  int tid = threadIdx.x;
  for(int i = tid; i < cnt; i += 256) pk[i] = bk[i];
  if(tid < 128) h[tid] = 0;
  __syncthreads();
  for(int i = tid; i < cnt; i += 256) atomicAdd(&h[(pk[i] >> 16) & 127], 1);
  __syncthreads();
  if(tid < 128) sc[tid] = h[tid];
  __syncthreads();
  for(int off = 1; off < 128; off <<= 1){
    int t = 0;
    if(tid < 128 && tid >= off) t = sc[tid - off];
    __syncthreads();
    if(tid < 128) sc[tid] += t;
    __syncthreads();
  }
  if(tid < 128){
    int excl = sc[tid] - h[tid];
    cur[tid] = excl;
    int node = b * 128 + tid;
    if(node < N_NODES) indptr9[(size_t)set * (N_NODES + 1) + node] = ebase + excl;
  }
  __syncthreads();
  for(int i = tid; i < cnt; i += 256){
    int p = pk[i];
    int r = atomicAdd(&cur[(p >> 16) & 127], 1);
    stage[r] = p & 0xFFFF;
  }
  __syncthreads();
  int* out = csr9 + (size_t)set * NEDGE + ebase;
  for(int i = tid; i < cnt; i += 256) out[i] = stage[i];
}

// ================= f32 -> bf16 bulk convert =================
__global__ void k_tobf16(const float* __restrict__ in, unsigned short* __restrict__ o, int n4){
  int i = blockIdx.x * 256 + threadIdx.x;
  if(i < n4){
    float4 v = ((const float4*)in)[i];
    ushort4 u; u.x = f2b(v.x); u.y = f2b(v.y); u.z = f2b(v.z); u.w = f2b(v.w);
    ((ushort4*)o)[i] = u;
  }
}

// ================= weight pack =================
struct PackJobs { const float* src[20]; int wst[20]; int K[20]; int dst[20]; int n; };

__global__ void k_wpack(PackJobs J, unsigned short* __restrict__ out){
  int j = blockIdx.x;
  if(j >= J.n) return;
  const float* s = J.src[j];
  int wst = J.wst[j], K = J.K[j];
  unsigned short* o = out + J.dst[j];
  for(int i = threadIdx.x; i < K * 64; i += 256){
    int k = i >> 6, c = i & 63;
    o[((((k >> 3) * 64) + c) << 3) + (k & 7)] = f2b(s[(size_t)k * wst + c]);
  }
}

// ================= MFMA node GEMM =================
struct MG {
  const unsigned short* Wt[4];
  const float* bias[4];
  const void* add[4];
  const float* mul[4];
  void* out[4];
  int ast, mst, ost;
};

template<int K1, int K2, int NGRP, int RELU, int HAS_ADD, int ADDB, int HAS_MUL, int OUT_BF16>
__global__ __launch_bounds__(256)
void k_mgemm(const unsigned short* __restrict__ X1, int xs1,
             const unsigned short* __restrict__ X2, int xs2, MG P){
  constexpr int K = K1 + K2;
  constexpr int KS = K / 32;
  int tid = threadIdx.x;
  int lane = tid & 63;
  int w = tid >> 6;
  int row0 = blockIdx.x * 64 + w * 16;
  int l15 = lane & 15, kg = lane >> 4;
  int arow = row0 + l15; if(arow > N_NODES - 1) arow = N_NODES - 1;
  bfrag a[KS];
  #pragma unroll
  for(int ks = 0; ks < KS; ks++){
    int kk = ks * 32 + kg * 8;
    const unsigned short* p = (kk < K1) ? (X1 + (size_t)arow * xs1 + kk)
                                        : (X2 + (size_t)arow * xs2 + (kk - K1));
    a[ks] = *(const bfrag*)p;
  }
  int orow0 = row0 + kg * 4;
  #pragma unroll
  for(int g = 0; g < NGRP; g++){
    const unsigned short* Wg = P.Wt[g];
    #pragma unroll
    for(int ct = 0; ct < 4; ct++){
      int col = ct * 16 + l15;
      ffrag acc = {0.f, 0.f, 0.f, 0.f};
      #pragma unroll
      for(int ks = 0; ks < KS; ks++){
        bfrag bf = *(const bfrag*)(Wg + (((size_t)(ks * 4 + kg) * 64 + col) << 3));
        acc = __builtin_amdgcn_mfma_f32_16x16x32_bf16(a[ks], bf, acc, 0, 0, 0);
      }
      float bv = P.bias[g] ? P.bias[g][col] : 0.f;
      #pragma unroll
      for(int i = 0; i < 4; i++){
        int r = orow0 + i;
        if(r >= N_NODES) break;
        float v = acc[i] + bv;
        if(HAS_ADD){
          if(ADDB) v += b2f(((const unsigned short*)P.add[g])[(size_t)r * P.ast + col]);
          else     v += ((const float*)P.add[g])[(size_t)r * P.ast + col];
        }
        if(RELU) v = fmaxf(v, 0.f);
        if(HAS_MUL) v *= P.mul[g][(size_t)r * P.mst + col];
        if(OUT_BF16) ((unsigned short*)P.out[g])[(size_t)r * P.ost + col] = f2b(v);
        else         ((float*)P.out[g])[(size_t)r * P.ost + col] = v;
      }
    }
  }
}

// ================= fused AB + MX GEMM =================
struct ABMX {
  const unsigned short* Wea[4];
  const unsigned short* Wfm[2];
  const float* cF;
  const float* xf32;
  unsigned short* ab;
  unsigned short* mx;
};

__global__ __launch_bounds__(256)
void k_abmx(const unsigned short* __restrict__ LOb, const unsigned short* __restrict__ xb, ABMX P){
  int tid = threadIdx.x, lane = tid & 63, w = tid >> 6;
  int row0 = blockIdx.x * 64 + w * 16;
  int l15 = lane & 15, kg = lane >> 4;
  int arow = row0 + l15; if(arow > N_NODES - 1) arow = N_NODES - 1;
  bfrag a[6];
  a[0] = *(const bfrag*)(LOb + (size_t)arow * 64 + kg * 8);
  a[1] = *(const bfrag*)(LOb + (size_t)arow * 64 + 32 + kg * 8);
  #pragma unroll
  for(int ks = 0; ks < 4; ks++)
    a[2 + ks] = *(const bfrag*)(xb + (size_t)arow * 128 + ks * 32 + kg * 8);
  int orow0 = row0 + kg * 4;
  #pragma unroll
  for(int g = 0; g < 4; g++){
    const unsigned short* Wg = P.Wea[g];
    #pragma unroll
    for(int ct = 0; ct < 4; ct++){
      int col = ct * 16 + l15;
      ffrag acc = {0.f, 0.f, 0.f, 0.f};
      bfrag b0 = *(const bfrag*)(Wg + (((size_t)(0 * 4 + kg) * 64 + col) << 3));
      bfrag b1 = *(const bfrag*)(Wg + (((size_t)(1 * 4 + kg) * 64 + col) << 3));
      acc = __builtin_amdgcn_mfma_f32_16x16x32_bf16(a[0], b0, acc, 0, 0, 0);
      acc = __builtin_amdgcn_mfma_f32_16x16x32_bf16(a[1], b1, acc, 0, 0, 0);
      #pragma unroll
      for(int i = 0; i < 4; i++){
        int r = orow0 + i;
        if(r >= N_NODES) break;
        P.ab[(size_t)r * 256 + g * 64 + col] = f2b(acc[i]);
      }
    }
  }
  #pragma unroll
  for(int g = 0; g < 2; g++){
    const unsigned short* Wg = P.Wfm[g];
    #pragma unroll
    for(int ct = 0; ct < 4; ct++){
      int col = ct * 16 + l15;
      ffrag acc = {0.f, 0.f, 0.f, 0.f};
      #pragma unroll
      for(int ks = 0; ks < 6; ks++){
        bfrag bf = *(const bfrag*)(Wg + (((size_t)(ks * 4 + kg) * 64 + col) << 3));
        acc = __builtin_amdgcn_mfma_f32_16x16x32_bf16(a[ks], bf, acc, 0, 0, 0);
      }
      float bv = P.cF[g * 64 + col];
      #pragma unroll
      for(int i = 0; i < 4; i++){
        int r = orow0 + i;
        if(r >= N_NODES) break;
        float v = (acc[i] + bv) * P.xf32[(size_t)r * 128 + g * 64 + col];
        P.mx[(size_t)r * 128 + g * 64 + col] = f2b(v);
      }
    }
  }
}

// ================= mean aggregation (eighth-wave uint4: 8 edges in flight, 2x unroll) ==========
template<int OUTB>
__global__ void k_agg8(const unsigned short* __restrict__ TB, int tst,
                       const int* __restrict__ indptr, const int* __restrict__ csr,
                       void* __restrict__ out){
  int br = blockIdx.y;
  const unsigned short* T = TB + (size_t)br * tst;
  const int* ip = indptr + (size_t)br * (N_NODES + 1);
  const int* cs = csr + (size_t)br * NEDGE;
  int lane = threadIdx.x & 63, wid = threadIdx.x >> 6;
  int node = blockIdx.x * 4 + wid;
  if(node >= N_NODES) return;
  int q = lane >> 3, c = lane & 7;
  int beg = ip[node], end = ip[node + 1];
  int cnt = end - beg;
  float sc = 1.0f / (float)(cnt >= 1 ? cnt : 1);
  float a0=0.f,a1=0.f,a2=0.f,a3=0.f,a4=0.f,a5=0.f,a6=0.f,a7=0.f;
  int j = beg + q;
  for(; j + 8 < end; j += 16){
    int s0 = cs[j], s1 = cs[j + 8];
    uint4 u0 = *(const uint4*)(T + (size_t)s0 * 64 + c * 8);
    uint4 u1 = *(const uint4*)(T + (size_t)s1 * 64 + c * 8);
    a0 += b2f_lo(u0.x) + b2f_lo(u1.x); a1 += b2f_hi(u0.x) + b2f_hi(u1.x);
    a2 += b2f_lo(u0.y) + b2f_lo(u1.y); a3 += b2f_hi(u0.y) + b2f_hi(u1.y);
    a4 += b2f_lo(u0.z) + b2f_lo(u1.z); a5 += b2f_hi(u0.z) + b2f_hi(u1.z);
    a6 += b2f_lo(u0.w) + b2f_lo(u1.w); a7 += b2f_hi(u0.w) + b2f_hi(u1.w);
  }
  if(j < end){
    int s = cs[j];
    uint4 u = *(const uint4*)(T + (size_t)s * 64 + c * 8);
    a0 += b2f_lo(u.x); a1 += b2f_hi(u.x);
    a2 += b2f_lo(u.y); a3 += b2f_hi(u.y);
    a4 += b2f_lo(u.z); a5 += b2f_hi(u.z);
    a6 += b2f_lo(u.w); a7 += b2f_hi(u.w);
  }
  #pragma unroll
  for(int off = 8; off < 64; off <<= 1){
    a0 += __shfl_xor(a0, off, 64); a1 += __shfl_xor(a1, off, 64);
    a2 += __shfl_xor(a2, off, 64); a3 += __shfl_xor(a3, off, 64);
    a4 += __shfl_xor(a4, off, 64); a5 += __shfl_xor(a5, off, 64);
    a6 += __shfl_xor(a6, off, 64); a7 += __shfl_xor(a7, off, 64);
  }
  if(q == 0){
    if(OUTB){
      uint4 o;
      o.x = pk2(a0 * sc, a1 * sc); o.y = pk2(a2 * sc, a3 * sc);
      o.z = pk2(a4 * sc, a5 * sc); o.w = pk2(a6 * sc, a7 * sc);
      *(uint4*)((unsigned short*)out + (size_t)br * tst + (size_t)node * 64 + c * 8) = o;
    } else {
      float* o = (float*)out + (size_t)node * 64 + c * 8;
      *(float4*)o       = float4{a0 * sc, a1 * sc, a2 * sc, a3 * sc};
      *(float4*)(o + 4) = float4{a4 * sc, a5 * sc, a6 * sc, a7 * sc};
    }
  }
}

// ================= gating + lo (+ constant vectors in extra blocks) =================
__global__ void k_gates_cvec(const unsigned short* __restrict__ t0b, const unsigned short* __restrict__ t1b,
                             const float* __restrict__ y, const float* __restrict__ gate_W,
                             const float* __restrict__ gate_b, unsigned short* __restrict__ lo,
                             const float* __restrict__ ee, const float* __restrict__ ne,
                             const float* __restrict__ eaW1, const float* __restrict__ eab1,
                             const float* __restrict__ fmW, const float* __restrict__ fmb,
                             float* __restrict__ cE, float* __restrict__ cF, int gn4){
  if(blockIdx.x >= gn4){
    int which = blockIdx.x - gn4;
    int j = threadIdx.x;
    if(j < 128){
      if(which == 0){
        float s = eab1[j];
        for(int k = 0; k < 64; k++) s += ee[k] * eaW1[(128 + k) * 128 + j];
        cE[j] = s;
      } else {
        float s = fmb[j];
        for(int k = 0; k < 64; k++) s += ne[k] * fmW[(192 + k) * 128 + j];
        cF[j] = s;
      }
    }
    return;
  }
  int lane = threadIdx.x & 63, wid = threadIdx.x >> 6;
  int node = blockIdx.x * 4 + wid;
  if(node >= N_NODES) return;
  size_t idx = (size_t)node * 64 + lane;
  float t0v = b2f(t0b[idx]), t1v = b2f(t1b[idx]), yv = y[idx];
  float g0 = wave_red(t0v * gate_W[lane]) + gate_b[0];
  float g1 = wave_red(t1v * gate_W[64 + lane]) + gate_b[1];
  float m = fmaxf(g0, g1);
  float e0 = expf(g0 - m), e1 = expf(g1 - m);
  float a0 = e0 / (e0 + e1);
  lo[idx] = f2b(yv + a0 * t0v + (1.f - a0) * t1v);
}

// ========== per-edge MLP (quarter-wave uint4, 2x unroll, fused sumem + block minmax) ==========
__global__ void k_em2(const unsigned short* __restrict__ AB,
                      const int* __restrict__ indptr, const int* __restrict__ csr_src,
                      const float* __restrict__ cvec, const float* __restrict__ W2,
                      const float* __restrict__ b2, float* __restrict__ em,
                      float* __restrict__ sumem, float* __restrict__ pmn, float* __restrict__ pmx){
  int lane = threadIdx.x & 63, wid = threadIdx.x >> 6;
  int node = blockIdx.x * 4 + wid;
  float mn = 3.4e38f, mx = -3.4e38f;
  if(node < N_NODES){
    int q = lane >> 4, c = lane & 15;
    uint4 bu = *(const uint4*)(AB + (size_t)node * 256 + 128 + c * 8);
    float4 cva = *(const float4*)&cvec[c * 8];
    float4 cvb = *(const float4*)&cvec[c * 8 + 4];
    float4 wva = *(const float4*)&W2[c * 8];
    float4 wvb = *(const float4*)&W2[c * 8 + 4];
    float cc0 = b2f_lo(bu.x) + cva.x, cc1 = b2f_hi(bu.x) + cva.y;
    float cc2 = b2f_lo(bu.y) + cva.z, cc3 = b2f_hi(bu.y) + cva.w;
    float cc4 = b2f_lo(bu.z) + cvb.x, cc5 = b2f_hi(bu.z) + cvb.y;
    float cc6 = b2f_lo(bu.w) + cvb.z, cc7 = b2f_hi(bu.w) + cvb.w;
    float b2v = b2[0];
    int beg = indptr[node], end = indptr[node + 1];
    float ssum = 0.f;
    int j = beg + q;
    for(; j + 4 < end; j += 8){
      int s0 = csr_src[j], s1 = csr_src[j + 4];
      uint4 u0 = *(const uint4*)(AB + (size_t)s0 * 256 + c * 8);
      uint4 u1 = *(const uint4*)(AB + (size_t)s1 * 256 + c * 8);
      float v0 = fmaxf(b2f_lo(u0.x) + cc0, 0.f) * wva.x + fmaxf(b2f_hi(u0.x) + cc1, 0.f) * wva.y
               + fmaxf(b2f_lo(u0.y) + cc2, 0.f) * wva.z + fmaxf(b2f_hi(u0.y) + cc3, 0.f) * wva.w
               + fmaxf(b2f_lo(u0.z) + cc4, 0.f) * wvb.x + fmaxf(b2f_hi(u0.z) + cc5, 0.f) * wvb.y
               + fmaxf(b2f_lo(u0.w) + cc6, 0.f) * wvb.z + fmaxf(b2f_hi(u0.w) + cc7, 0.f) * wvb.w;
      float v1 = fmaxf(b2f_lo(u1.x) + cc0, 0.f) * wva.x + fmaxf(b2f_hi(u1.x) + cc1, 0.f) * wva.y
               + fmaxf(b2f_lo(u1.y) + cc2, 0.f) * wva.z + fmaxf(b2f_hi(u1.y) + cc3, 0.f) * wva.w
               + fmaxf(b2f_lo(u1.z) + cc4, 0.f) * wvb.x + fmaxf(b2f_hi(u1.z) + cc5, 0.f) * wvb.y
               + fmaxf(b2f_lo(u1.w) + cc6, 0.f) * wvb.z + fmaxf(b2f_hi(u1.w) + cc7, 0.f) * wvb.w;
      #pragma unroll
      for(int off = 1; off < 16; off <<= 1){
        v0 += __shfl_xor(v0, off, 64);
        v1 += __shfl_xor(v1, off, 64);
      }
      float r0 = v0 + b2v, r1 = v1 + b2v;
      if(c == 0){ em[j] = r0; em[j + 4] = r1; }
      ssum += r0 + r1;
      mn = fminf(mn, fminf(r0, r1)); mx = fmaxf(mx, fmaxf(r0, r1));
    }
    if(j < end){
      int s = csr_src[j];
      uint4 u = *(const uint4*)(AB + (size_t)s * 256 + c * 8);
      float v = fmaxf(b2f_lo(u.x) + cc0, 0.f) * wva.x + fmaxf(b2f_hi(u.x) + cc1, 0.f) * wva.y
              + fmaxf(b2f_lo(u.y) + cc2, 0.f) * wva.z + fmaxf(b2f_hi(u.y) + cc3, 0.f) * wva.w
              + fmaxf(b2f_lo(u.z) + cc4, 0.f) * wvb.x + fmaxf(b2f_hi(u.z) + cc5, 0.f) * wvb.y
              + fmaxf(b2f_lo(u.w) + cc6, 0.f) * wvb.z + fmaxf(b2f_hi(u.w) + cc7, 0.f) * wvb.w;
      #pragma unroll
      for(int off = 1; off < 16; off <<= 1) v += __shfl_xor(v, off, 64);
      float r = v + b2v;
      if(c == 0) em[j] = r;
      ssum += r;
      mn = fminf(mn, r); mx = fmaxf(mx, r);
    }
    // cross-group (q) reduction: values identical within each 16-lane group
    ssum += __shfl_xor(ssum, 16, 64); ssum += __shfl_xor(ssum, 32, 64);
    mn = fminf(mn, __shfl_xor(mn, 16, 64)); mn = fminf(mn, __shfl_xor(mn, 32, 64));
    mx = fmaxf(mx, __shfl_xor(mx, 16, 64)); mx = fmaxf(mx, __shfl_xor(mx, 32, 64));
    if(lane == 0) sumem[node] = ssum;
  }
  __shared__ float bmn[4], bmx[4];
  if(lane == 0){ bmn[wid] = mn; bmx[wid] = mx; }
  __syncthreads();
  if(threadIdx.x == 0){
    pmn[blockIdx.x] = fminf(fminf(bmn[0], bmn[1]), fminf(bmn[2], bmn[3]));
    pmx[blockIdx.x] = fmaxf(fmaxf(bmx[0], bmx[1]), fmaxf(bmx[2], bmx[3]));
  }
}

// ================= final min/max over block partials =================
__global__ void k_minmax_final(const float* __restrict__ pmn, const float* __restrict__ pmx,
                               int nb, float* __restrict__ scal){
  __shared__ float smn[256], smx[256];
  int tid = threadIdx.x;
  float mn = 3.4e38f, mx = -3.4e38f;
  for(int i = tid; i < nb; i += 256){
    mn = fminf(mn, pmn[i]); mx = fmaxf(mx, pmx[i]);
  }
  smn[tid] = mn; smx[tid] = mx; __syncthreads();
  for(int s = 128; s > 0; s >>= 1){
    if(tid < s){ smn[tid] = fminf(smn[tid], smn[tid + s]); smx[tid] = fmaxf(smx[tid], smx[tid + s]); }
    __syncthreads();
  }
  if(tid == 0){
    scal[0] = smn[0];
    scal[1] = 1.0f / fmaxf(smx[0] - smn[0], 1e-30f);
  }
}

// ================= scal + deg^-1/2 (O(N)) =================
__global__ void k_dinv(const int* __restrict__ indptr, const float* __restrict__ sumem,
                       const float* __restrict__ scal, float* __restrict__ dinv){
  int i = blockIdx.x * 256 + threadIdx.x;
  if(i >= N_NODES) return;
  float mn = scal[0], inv = scal[1];
  float cnt = (float)(indptr[i + 1] - indptr[i]);
  dinv[i] = rsqrtf(1.f + (sumem[i] - cnt * mn) * inv);
}

// ================= GCN layer (eighth-wave uint4, 2x unroll) =================
template<int RELU, int OUTB>
__global__ void k_gcn(const unsigned short* __restrict__ xW, const int* __restrict__ indptr,
                      const int* __restrict__ csr_src, const float* __restrict__ em,
                      const float* __restrict__ scal, const float* __restrict__ dinv,
                      const float* __restrict__ bias, void* __restrict__ out, int ostride){
  int lane = threadIdx.x & 63, wid = threadIdx.x >> 6;
  int node = blockIdx.x * 4 + wid;
  if(node >= N_NODES) return;
  int q = lane >> 3, c = lane & 7;
  float mn = scal[0], inv = scal[1];
  float di = dinv[node];
  float a0=0.f,a1=0.f,a2=0.f,a3=0.f,a4=0.f,a5=0.f,a6=0.f,a7=0.f;
  int beg = indptr[node], end = indptr[node + 1];
  int j = beg + q;
  for(; j + 8 < end; j += 16){
    int s0 = csr_src[j], s1 = csr_src[j + 8];
    float w0 = (em[j] - mn) * inv * dinv[s0];
    float w1 = (em[j + 8] - mn) * inv * dinv[s1];
    uint4 u0 = *(const uint4*)(xW + (size_t)s0 * 64 + c * 8);
    uint4 u1 = *(const uint4*)(xW + (size_t)s1 * 64 + c * 8);
    a0 += w0 * b2f_lo(u0.x) + w1 * b2f_lo(u1.x); a1 += w0 * b2f_hi(u0.x) + w1 * b2f_hi(u1.x);
    a2 += w0 * b2f_lo(u0.y) + w1 * b2f_lo(u1.y); a3 += w0 * b2f_hi(u0.y) + w1 * b2f_hi(u1.y);
    a4 += w0 * b2f_lo(u0.z) + w1 * b2f_lo(u1.z); a5 += w0 * b2f_hi(u0.z) + w1 * b2f_hi(u1.z);
    a6 += w0 * b2f_lo(u0.w) + w1 * b2f_lo(u1.w); a7 += w0 * b2f_hi(u0.w) + w1 * b2f_hi(u1.w);
  }
  if(j < end){
    int s = csr_src[j];
    float wv = (em[j] - mn) * inv * dinv[s];
    uint4 u = *(const uint4*)(xW + (size_t)s * 64 + c * 8);
    a0 += wv * b2f_lo(u.x); a1 += wv * b2f_hi(u.x);
    a2 += wv * b2f_lo(u.y); a3 += wv * b2f_hi(u.y);
    a4 += wv * b2f_lo(u.z); a5 += wv * b2f_hi(u.z);
    a6 += wv * b2f_lo(u.w); a7 += wv * b2f_hi(u.w);
  }
  #pragma unroll
  for(int off = 8; off < 64; off <<= 1){
    a0 += __shfl_xor(a0, off, 64); a1 += __shfl_xor(a1, off, 64);
    a2 += __shfl_xor(a2, off, 64); a3 += __shfl_xor(a3, off, 64);
    a4 += __shfl_xor(a4, off, 64); a5 += __shfl_xor(a5, off, 64);
    a6 += __shfl_xor(a6, off, 64); a7 += __shfl_xor(a7, off, 64);
  }
  if(q == 0){
    uint4 su = *(const uint4*)(xW + (size_t)node * 64 + c * 8);
    float4 bva = *(const float4*)&bias[c * 8];
    float4 bvb = *(const float4*)&bias[c * 8 + 4];
    float dd = di * di;
    float r0 = a0 * di + b2f_lo(su.x) * dd + bva.x;
    float r1 = a1 * di + b2f_hi(su.x) * dd + bva.y;
    float r2 = a2 * di + b2f_lo(su.y) * dd + bva.z;
    float r3 = a3 * di + b2f_hi(su.y) * dd + bva.w;
    float r4 = a4 * di + b2f_lo(su.z) * dd + bvb.x;
    float r5 = a5 * di + b2f_hi(su.z) * dd + bvb.y;
    float r6 = a6 * di + b2f_lo(su.w) * dd + bvb.z;
    float r7 = a7 * di + b2f_hi(su.w) * dd + bvb.w;
    if(RELU){
      r0 = fmaxf(r0, 0.f); r1 = fmaxf(r1, 0.f); r2 = fmaxf(r2, 0.f); r3 = fmaxf(r3, 0.f);
      r4 = fmaxf(r4, 0.f); r5 = fmaxf(r5, 0.f); r6 = fmaxf(r6, 0.f); r7 = fmaxf(r7, 0.f);
    }
    if(OUTB){
      uint4 o;
      o.x = pk2(r0, r1); o.y = pk2(r2, r3); o.z = pk2(r4, r5); o.w = pk2(r6, r7);
      *(uint4*)((unsigned short*)out + (size_t)node * ostride + c * 8) = o;
    } else {
      float* o = (float*)out + (size_t)node * ostride + c * 8;
      *(float4*)o       = float4{r0, r1, r2, r3};
      *(float4*)(o + 4) = float4{r4, r5, r6, r7};
    }
  }
}

// ================= logits + log_softmax =================
__global__ void k_logits(const float* __restrict__ xt, const float* __restrict__ lin_W,
                         const float* __restrict__ lin_b, float* __restrict__ out){
  int lane = threadIdx.x & 63, wid = threadIdx.x >> 6;
  int node = blockIdx.x * 4 + wid;
  if(node >= N_NODES) return;
  float a0 = 0.f, a1 = 0.f;
  #pragma unroll
  for(int q = 0; q < 3; q++){
    int k = q * 64 + lane;
    float v = xt[(size_t)node * 192 + k];
    a0 += v * lin_W[k * 2 + 0];
    a1 += v * lin_W[k * 2 + 1];
  }
  a0 = wave_red(a0);
  a1 = wave_red(a1);
  if(lane == 0){
    float l0 = fminf(fmaxf(a0 + lin_b[0], -1e10f), 1e10f);
    float l1 = fminf(fmaxf(a1 + lin_b[1], -1e10f), 1e10f);
    float m = fmaxf(l0, l1);
    float d = expf(l0 - m) + expf(l1 - m);
    float ls = m + logf(d);
    out[(size_t)node * 2 + 0] = l0 - ls;
    out[(size_t)node * 2 + 1] = l1 - ls;
  }
}

// =====================================================================
extern "C" void kernel_launch(void* const* d_in, const int* in_sizes, int n_in,
                              void* d_out, int out_size, void* d_ws, size_t ws_size,
                              hipStream_t stream){
  (void)in_sizes; (void)n_in; (void)out_size;
  const int N = N_NODES, E = NEDGE;

  const float* x        = (const float*)d_in[0];
  const int*  edge_main = (const int*)d_in[1];
  const int*  edge_tree = (const int*)d_in[2];
  const float* sage_Wl0 = (const float*)d_in[3];
  const float* sage_Wr0 = (const float*)d_in[4];
  const float* sage_b0  = (const float*)d_in[5];
  const float* sage_Wl1 = (const float*)d_in[6];
  const float* sage_Wr1 = (const float*)d_in[7];
  const float* sage_b1  = (const float*)d_in[8];
  const float* tree_Wl  = (const float*)d_in[9];
  const float* tree_Wr  = (const float*)d_in[10];
  const float* tree_b   = (const float*)d_in[11];
  const float* gate_W   = (const float*)d_in[12];
  const float* gate_b   = (const float*)d_in[13];
  const float* node_emb = (const float*)d_in[14];
  const float* edge_emb = (const float*)d_in[15];
  const float* fm_W     = (const float*)d_in[16];
  const float* fm_b     = (const float*)d_in[17];
  const float* ea_W1    = (const float*)d_in[18];
  const float* ea_b1    = (const float*)d_in[19];
  const float* ea_W2    = (const float*)d_in[20];
  const float* ea_b2    = (const float*)d_in[21];
  const float* gcn_W0   = (const float*)d_in[22];
  const float* gcn_b0   = (const float*)d_in[23];
  const float* gcn_W1   = (const float*)d_in[24];
  const float* gcn_b1   = (const float*)d_in[25];
  const float* lin_W    = (const float*)d_in[26];
  const float* lin_b    = (const float*)d_in[27];

  float* out_lsm   = (float*)d_out;
  float* out_xtemp = (float*)d_out + (size_t)N * NCLS;

  // ---- workspace (~93.4 MB, phase-overlaid) ----
  char* ws = (char*)d_ws;
  unsigned short* TB3  = (unsigned short*)(ws + 0);
  unsigned short* TBs  = (unsigned short*)(ws + 0);
  float*          Y    = (float*)(ws + 0);
  unsigned short* xW0b = (unsigned short*)(ws + 0);
  unsigned short* z0b  = (unsigned short*)(ws + 6400000);
  unsigned short* xW1b = (unsigned short*)(ws + 12800000);
  unsigned short* AG3  = (unsigned short*)(ws + 19200000);
  float*          AG   = (float*)(ws + 19200000);
  unsigned short* LOb  = (unsigned short*)(ws + 25600000);
  unsigned short* AB   = (unsigned short*)(ws + 0);
  unsigned short* y0b  = (unsigned short*)(ws + 38400000);
  unsigned short* T0b  = (unsigned short*)(ws + 44800000);
  unsigned short* T1b  = (unsigned short*)(ws + 51200000);
  unsigned short* MXb  = (unsigned short*)(ws + 38400000);
  unsigned short* xb   = (unsigned short*)(ws + 57600000);
  int*   bucketed = (int*)(ws + 0);
  unsigned short* Wpk = (unsigned short*)(ws + 70400000);
  int*   csr9     = (int*)(ws + 71000064);
  int*   indptr9  = (int*)(ws + 89000064);
  float* em       = (float*)(ws + 90800128);
  float* sumem    = (float*)(ws + 92800128);
  float* dinv     = (float*)(ws + 93000128);
  int*   cursor   = (int*)(ws + 93200128);
  int*   bktbase  = (int*)(ws + 93214208);
  float* cvecE    = (float*)(ws + 93228288);
  float* cvecF    = (float*)(ws + 93228800);
  float* scal     = (float*)(ws + 93229312);
  float* pmn      = (float*)(ws + 93229568);
  float* pmx      = (float*)(ws + 93279568);
  if(ws_size < 93330000) return;

  const int GN4 = (N + 3) / 4;
  const int GN  = (N + 255) / 256;
  const int GGM = (N + 63) / 64;
  const int NCH = (E + CHUNK - 1) / CHUNK;

  // ---- weight pack jobs ----
  PackJobs PJ[2]; PJ[0].n = 0; PJ[1].n = 0;
  int npj = 0, dstElem = 0;
  const unsigned short* WlpA[NREL]; const unsigned short* WlpB[NREL]; const unsigned short* WlpC[NREL];
  const unsigned short* Wr0j[NREL]; const unsigned short* WrT0[NREL]; const unsigned short* WrT1[NREL];
  const unsigned short* Wl1j[NREL]; const unsigned short* Wr1j[NREL];
  const unsigned short* Fm0j[NREL]; const unsigned short* Fm1j[NREL];
  const unsigned short* G0j[NREL];  const unsigned short* G1j[NREL];
  const unsigned short *EaA0, *EaA1, *EaB0, *EaB1;
  auto addjob = [&](const float* src, int wst, int K) -> const unsigned short* {
    int slot = npj < 20 ? 0 : 1;
    int k = npj - slot * 20;
    PJ[slot].src[k] = src; PJ[slot].wst[k] = wst; PJ[slot].K[k] = K; PJ[slot].dst[k] = dstElem;
    PJ[slot].n = k + 1;
    const unsigned short* ret = Wpk + dstElem;
    dstElem += K * 64; npj++;
    return ret;
  };
  for(int r = 0; r < NREL; r++){
    WlpA[r] = addjob(sage_Wl0 + (size_t)r * 8192, 64, 128);
    WlpB[r] = addjob(tree_Wl + (size_t)(r * NTREE + 0) * 8192, 64, 128);
    WlpC[r] = addjob(tree_Wl + (size_t)(r * NTREE + 1) * 8192, 64, 128);
    Wr0j[r] = addjob(sage_Wr0 + (size_t)r * 8192, 64, 128);
    WrT0[r] = addjob(tree_Wr + (size_t)(r * NTREE + 0) * 8192, 64, 128);
    WrT1[r] = addjob(tree_Wr + (size_t)(r * NTREE + 1) * 8192, 64, 128);
    Wl1j[r] = addjob(sage_Wl1 + (size_t)r * 4096, 64, 64);
    Wr1j[r] = addjob(sage_Wr1 + (size_t)r * 4096, 64, 64);
    Fm0j[r] = addjob(fm_W + (size_t)r * 32768, 128, 192);
    Fm1j[r] = addjob(fm_W + (size_t)r * 32768 + 64, 128, 192);
    G0j[r]  = addjob(gcn_W0 + (size_t)r * 8192, 64, 128);
    G1j[r]  = addjob(gcn_W1 + (size_t)r * 4096, 64, 64);
  }
  EaA0 = addjob(ea_W1, 128, 64);
  EaA1 = addjob(ea_W1 + 64, 128, 64);
  EaB0 = addjob(ea_W1 + 64 * 128, 128, 64);
  EaB1 = addjob(ea_W1 + 64 * 128 + 64, 128, 64);

  // ---- CSR build for all 9 edge sets ----
  EdgePtrs ep;
  for(int r = 0; r < NREL; r++){
    ep.s[r * 3 + 0] = edge_main + (size_t)r * 2 * E;
    ep.d[r * 3 + 0] = ep.s[r * 3 + 0] + E;
    for(int t = 0; t < NTREE; t++){
      ep.s[r * 3 + 1 + t] = edge_tree + ((size_t)(r * NTREE + t) * 2) * E;
      ep.d[r * 3 + 1 + t] = ep.s[r * 3 + 1 + t] + E;
    }
  }
  hipMemsetAsync(cursor, 0, 9 * BKT * 4, stream);
  k_passA<<<dim3(NCH, 9), 256, 0, stream>>>(ep, cursor, bucketed);
  k_scanB<<<9, 512, 0, stream>>>(cursor, bktbase, indptr9);
  k_passB<<<dim3(BKT, 9), 256, 0, stream>>>(bucketed, cursor, bktbase, indptr9, csr9);

  // ---- one-time conversions ----
  k_wpack<<<PJ[0].n, 256, 0, stream>>>(PJ[0], Wpk);
  k_wpack<<<PJ[1].n, 256, 0, stream>>>(PJ[1], Wpk);
  k_tobf16<<<(N * 128 / 4 + 255) / 256, 256, 0, stream>>>(x, xb, N * 128 / 4);

  for(int r = 0; r < NREL; r++){
    const int* ipM = indptr9 + (size_t)(r * 3) * (N + 1);
    const int* csM = csr9 + (size_t)(r * 3) * E;

    // 1. Wl-pack: TB3[br] = bf16( x @ Wl[br] )
    { MG p{}; p.ost = 64;
      p.Wt[0] = WlpA[r]; p.Wt[1] = WlpB[r]; p.Wt[2] = WlpC[r];
      p.out[0] = TB3; p.out[1] = TB3 + (size_t)N * 64; p.out[2] = TB3 + (size_t)2 * N * 64;
      k_mgemm<128, 0, 3, 0, 0, 0, 0, 1><<<GGM, 256, 0, stream>>>(xb, 128, nullptr, 0, p); }

    // 2a. batched aggs for 3 branches -> AG3 (bf16)
    k_agg8<1><<<dim3(GN4, 3), 256, 0, stream>>>(TB3, N * 64, ipM, csM, AG3);
    // 2b. one NGRP=3 mgemm: y0/T0/T1 = relu(x@Wr + AG3 + b)
    { MG p{}; p.ast = 64; p.ost = 64;
      p.Wt[0] = Wr0j[r]; p.bias[0] = sage_b0 + r * 64; p.add[0] = AG3;                         p.out[0] = y0b;
      p.Wt[1] = WrT0[r]; p.bias[1] = tree_b + (size_t)(r * NTREE + 0) * 64; p.add[1] = AG3 + (size_t)N * 64;   p.out[1] = T0b;
      p.Wt[2] = WrT1[r]; p.bias[2] = tree_b + (size_t)(r * NTREE + 1) * 64; p.add[2] = AG3 + (size_t)2 * N * 64; p.out[2] = T1b;
      k_mgemm<128, 0, 3, 1, 1, 1, 0, 1><<<GGM, 256, 0, stream>>>(xb, 128, nullptr, 0, p); }

    // 3. TBs = bf16(y0 @ Wl1)
    { MG p{}; p.ost = 64; p.Wt[0] = Wl1j[r]; p.out[0] = TBs;
      k_mgemm<64, 0, 1, 0, 0, 0, 0, 1><<<GGM, 256, 0, stream>>>(y0b, 64, nullptr, 0, p); }
    // 4. AG = agg(TBs, main), f32
    k_agg8<0><<<dim3(GN4, 1), 256, 0, stream>>>(TBs, N * 64, ipM, csM, AG);
    // 5. Y = y0 @ Wr1 + AG + b1 (f32)
    { MG p{}; p.ast = 64; p.ost = 64;
      p.Wt[0] = Wr1j[r]; p.bias[0] = sage_b1 + r * 64; p.add[0] = AG; p.out[0] = Y;
      k_mgemm<64, 0, 1, 0, 1, 0, 0, 0><<<GGM, 256, 0, stream>>>(y0b, 64, nullptr, 0, p); }

    // 6+7. gating -> lo, plus cvecE/cvecF in 2 extra blocks
    k_gates_cvec<<<GN4 + 2, 256, 0, stream>>>(T0b, T1b, Y, gate_W + (size_t)r * 128,
                                              gate_b + r * 2, LOb,
                                              edge_emb + r * 64, node_emb + r * 64,
                                              ea_W1, ea_b1, fm_W + (size_t)r * 32768,
                                              fm_b + r * 128, cvecE, cvecF, GN4);

    // 8+11. fused: AB = bf16(lo@Ea*), MXb = bf16(x * ([lo|x]@fmW + cvecF))
    { ABMX p{};
      p.Wea[0] = EaA0; p.Wea[1] = EaA1; p.Wea[2] = EaB0; p.Wea[3] = EaB1;
      p.Wfm[0] = Fm0j[r]; p.Wfm[1] = Fm1j[r];
      p.cF = cvecF; p.xf32 = x; p.ab = AB; p.mx = MXb;
      k_abmx<<<GGM, 256, 0, stream>>>(LOb, xb, p); }

    // 9. em (fused sumem + block min/max partials)
    k_em2<<<GN4, 256, 0, stream>>>(AB, ipM, csM, cvecE, ea_W2, ea_b2, em, sumem, pmn, pmx);

    // 9b. final min/max over partials
    k_minmax_final<<<1, 256, 0, stream>>>(pmn, pmx, GN4, scal);

    // 10. dinv (O(N))
    k_dinv<<<GN, 256, 0, stream>>>(ipM, sumem, scal, dinv);

    // 13-16. GCN stack
    { MG p{}; p.ost = 64; p.Wt[0] = G0j[r]; p.out[0] = xW0b;
      k_mgemm<128, 0, 1, 0, 0, 0, 0, 1><<<GGM, 256, 0, stream>>>(MXb, 128, nullptr, 0, p); }
    k_gcn<1, 1><<<GN4, 256, 0, stream>>>(xW0b, ipM, csM, em, scal, dinv, gcn_b0 + r * 64, z0b, 64);
    { MG p{}; p.ost = 64; p.Wt[0] = G1j[r]; p.out[0] = xW1b;
      k_mgemm<64, 0, 1, 0, 0, 0, 0, 1><<<GGM, 256, 0, stream>>>(z0b, 64, nullptr, 0, p); }
    k_gcn<0, 0><<<GN4, 256, 0, stream>>>(xW1b, ipM, csM, em, scal, dinv, gcn_b1 + r * 64,
                                         out_xtemp + r * 64, 192);
  }

  k_logits<<<GN4, 256, 0, stream>>>(out_xtemp, lin_W, lin_b, out_lsm);
}

// Round 10
// 799.024 us; speedup vs baseline: 5.3532x; 1.1169x over previous
//
#include <hip/hip_runtime.h>
#include <cstdint>

#define N_NODES 50000
#define FEAT    128
#define HID     64
#define NREL    3
#define NTREE   2
#define NEDGE   500000
#define NCLS    2

#define BKT   391
#define CAP   1600
#define CHUNK 4096

typedef __attribute__((ext_vector_type(8))) short bfrag;   // 8 bf16 (4 VGPR)
typedef __attribute__((ext_vector_type(4))) float ffrag;   // 4 f32 acc

__device__ __forceinline__ float wave_red(float v){
  #pragma unroll
  for(int off = 32; off > 0; off >>= 1) v += __shfl_xor(v, off, 64);
  return v;
}

__device__ __forceinline__ unsigned short f2b(float f){
  unsigned int u = __float_as_uint(f);
  unsigned int r = (u + 0x7FFFu + ((u >> 16) & 1u)) >> 16;
  return (unsigned short)r;
}
__device__ __forceinline__ float b2f_lo(unsigned int u){ return __uint_as_float(u << 16); }
__device__ __forceinline__ float b2f_hi(unsigned int u){ return __uint_as_float(u & 0xFFFF0000u); }
__device__ __forceinline__ float b2f(unsigned short s){ return __uint_as_float(((unsigned int)s) << 16); }
__device__ __forceinline__ unsigned int pk2(float lo, float hi){
  return ((unsigned int)f2b(hi) << 16) | f2b(lo);
}

struct EdgePtrs { const int* s[9]; const int* d[9]; };

// ================= CSR build pass A: LDS-staged bucket sort =================
__global__ __launch_bounds__(256)
void k_passA(EdgePtrs ep, int* __restrict__ cursor, int* __restrict__ bucketed){
  int set = blockIdx.y;
  const int* src = ep.s[set];
  const int* dst = ep.d[set];
  __shared__ int stage[CHUNK];
  __shared__ int hist[BKT], gbase[BKT], lbase[BKT], cur[BKT];
  int tid = threadIdx.x;
  for(int b = tid; b < BKT; b += 256) hist[b] = 0;
  __syncthreads();
  int e0 = blockIdx.x * CHUNK;
  int nE = NEDGE - e0; if(nE > CHUNK) nE = CHUNK;
  for(int i = tid; i < nE; i += 256) atomicAdd(&hist[dst[e0 + i] >> 7], 1);
  __syncthreads();
  for(int b = tid; b < BKT; b += 256){
    int c = hist[b];
    gbase[b] = c ? atomicAdd(&cursor[set * BKT + b], c) : 0;
  }
  if(tid < 64){
    int running = 0;
    for(int base = 0; base < BKT; base += 64){
      int idx = base + tid;
      int v = (idx < BKT) ? hist[idx] : 0;
      int orig = v;
      #pragma unroll
      for(int off = 1; off < 64; off <<= 1){
        int t = __shfl_up(v, off, 64);
        if(tid >= off) v += t;
      }
      if(idx < BKT){ lbase[idx] = running + v - orig; cur[idx] = running + v - orig; }
      running += __shfl(v, 63, 64);
    }
  }
  __syncthreads();
  for(int i = tid; i < nE; i += 256){
    int e = e0 + i;
    int d = dst[e];
    int r = atomicAdd(&cur[d >> 7], 1);
    stage[r] = (d << 16) | src[e];
  }
  __syncthreads();
  int* bk = bucketed + (size_t)set * BKT * CAP;
  for(int i = tid; i < nE; i += 256){
    int p = stage[i];
    int b = ((unsigned int)p) >> 23;
    int pos = gbase[b] + (i - lbase[b]);
    if(pos < CAP) bk[b * CAP + pos] = p;
  }
}

__global__ void k_scanB(const int* __restrict__ cursor, int* __restrict__ bktbase,
                        int* __restrict__ indptr9){
  int set = blockIdx.x;
  __shared__ int sm[512];
  int tid = threadIdx.x;
  int v = (tid < BKT) ? cursor[set * BKT + tid] : 0;
  sm[tid] = v; __syncthreads();
  for(int off = 1; off < 512; off <<= 1){
    int t = (tid >= off) ? sm[tid - off] : 0;
    __syncthreads();
    sm[tid] += t;
    __syncthreads();
  }
  if(tid < BKT) bktbase[set * BKT + tid] = sm[tid] - v;
  if(tid == 0) indptr9[(size_t)set * (N_NODES + 1) + N_NODES] = NEDGE;
}

__global__ __launch_bounds__(256)
void k_passB(const int* __restrict__ bucketed, const int* __restrict__ cursor,
             const int* __restrict__ bktbase, int* __restrict__ indptr9,
             int* __restrict__ csr9){
  int set = blockIdx.y, b = blockIdx.x;
  int cnt = cursor[set * BKT + b]; if(cnt > CAP) cnt = CAP;
  int ebase = bktbase[set * BKT + b];
  const int* bk = bucketed + (size_t)set * BKT * CAP + b * CAP;
  __shared__ int pk[CAP];
  __shared__ int stage[CAP];
  __shared__ int h[128], sc[128], cur[128];
  int tid = threadIdx.x;
  for(int i = tid; i < cnt; i += 256) pk[i] = bk[i];
  if(tid < 128) h[tid] = 0;
  __syncthreads();
  for(int i = tid; i < cnt; i += 256) atomicAdd(&h[(pk[i] >> 16) & 127], 1);
  __syncthreads();
  if(tid < 128) sc[tid] = h[tid];
  __syncthreads();
  for(int off = 1; off < 128; off <<= 1){
    int t = 0;
    if(tid < 128 && tid >= off) t = sc[tid - off];
    __syncthreads();
    if(tid < 128) sc[tid] += t;
    __syncthreads();
  }
  if(tid < 128){
    int excl = sc[tid] - h[tid];
    cur[tid] = excl;
    int node = b * 128 + tid;
    if(node < N_NODES) indptr9[(size_t)set * (N_NODES + 1) + node] = ebase + excl;
  }
  __syncthreads();
  for(int i = tid; i < cnt; i += 256){
    int p = pk[i];
    int r = atomicAdd(&cur[(p >> 16) & 127], 1);
    stage[r] = p & 0xFFFF;
  }
  __syncthreads();
  int* out = csr9 + (size_t)set * NEDGE + ebase;
  for(int i = tid; i < cnt; i += 256) out[i] = stage[i];
}

// ================= f32 -> bf16 bulk convert =================
__global__ void k_tobf16(const float* __restrict__ in, unsigned short* __restrict__ o, int n4){
  int i = blockIdx.x * 256 + threadIdx.x;
  if(i < n4){
    float4 v = ((const float4*)in)[i];
    ushort4 u; u.x = f2b(v.x); u.y = f2b(v.y); u.z = f2b(v.z); u.w = f2b(v.w);
    ((ushort4*)o)[i] = u;
  }
}

// ================= weight pack =================
struct PackJobs { const float* src[20]; int wst[20]; int K[20]; int dst[20]; int n; };

__global__ void k_wpack(PackJobs J, unsigned short* __restrict__ out){
  int j = blockIdx.x;
  if(j >= J.n) return;
  const float* s = J.src[j];
  int wst = J.wst[j], K = J.K[j];
  unsigned short* o = out + J.dst[j];
  for(int i = threadIdx.x; i < K * 64; i += 256){
    int k = i >> 6, c = i & 63;
    o[((((k >> 3) * 64) + c) << 3) + (k & 7)] = f2b(s[(size_t)k * wst + c]);
  }
}

// ================= generic MFMA node GEMM (steps 1 & 15) =================
struct MG {
  const unsigned short* Wt[4];
  const float* bias[4];
  const void* add[4];
  const float* mul[4];
  void* out[4];
  int ast, mst, ost;
};

template<int K1, int NGRP, int OUT_BF16>
__global__ __launch_bounds__(256)
void k_mgemm(const unsigned short* __restrict__ X1, int xs1, MG P){
  constexpr int KS = K1 / 32;
  int tid = threadIdx.x;
  int lane = tid & 63;
  int w = tid >> 6;
  int row0 = blockIdx.x * 64 + w * 16;
  int l15 = lane & 15, kg = lane >> 4;
  int arow = row0 + l15; if(arow > N_NODES - 1) arow = N_NODES - 1;
  bfrag a[KS];
  #pragma unroll
  for(int ks = 0; ks < KS; ks++)
    a[ks] = *(const bfrag*)(X1 + (size_t)arow * xs1 + ks * 32 + kg * 8);
  int orow0 = row0 + kg * 4;
  #pragma unroll
  for(int g = 0; g < NGRP; g++){
    const unsigned short* Wg = P.Wt[g];
    #pragma unroll
    for(int ct = 0; ct < 4; ct++){
      int col = ct * 16 + l15;
      ffrag acc = {0.f, 0.f, 0.f, 0.f};
      #pragma unroll
      for(int ks = 0; ks < KS; ks++){
        bfrag bf = *(const bfrag*)(Wg + (((size_t)(ks * 4 + kg) * 64 + col) << 3));
        acc = __builtin_amdgcn_mfma_f32_16x16x32_bf16(a[ks], bf, acc, 0, 0, 0);
      }
      #pragma unroll
      for(int i = 0; i < 4; i++){
        int r = orow0 + i;
        if(r >= N_NODES) break;
        float v = acc[i];
        if(OUT_BF16) ((unsigned short*)P.out[g])[(size_t)r * P.ost + col] = f2b(v);
        else         ((float*)P.out[g])[(size_t)r * P.ost + col] = v;
      }
    }
  }
}

// ========== step 2b + 3 fused: y0/T0/T1 = relu(x@Wr + AG3 + b); TBs = y0@Wl1 ==========
struct S23 {
  const unsigned short* Wr[3];
  const float* bias[3];
  const unsigned short* ag3;   // bf16 [3][N][64]
  const unsigned short* Wl1;
  unsigned short *y0, *t0, *t1, *tbs;
};

__global__ __launch_bounds__(256)
void k_s23(const unsigned short* __restrict__ xb, S23 P){
  __shared__ unsigned short ytile[64][72];
  int tid = threadIdx.x, lane = tid & 63, w = tid >> 6;
  int row0 = blockIdx.x * 64 + w * 16;
  int l15 = lane & 15, kg = lane >> 4;
  int arow = row0 + l15; if(arow > N_NODES - 1) arow = N_NODES - 1;
  bfrag a[4];
  #pragma unroll
  for(int ks = 0; ks < 4; ks++)
    a[ks] = *(const bfrag*)(xb + (size_t)arow * 128 + ks * 32 + kg * 8);
  int orow0 = row0 + kg * 4;
  #pragma unroll
  for(int g = 0; g < 3; g++){
    const unsigned short* Wg = P.Wr[g];
    unsigned short* og = (g == 0) ? P.y0 : (g == 1) ? P.t0 : P.t1;
    #pragma unroll
    for(int ct = 0; ct < 4; ct++){
      int col = ct * 16 + l15;
      ffrag acc = {0.f, 0.f, 0.f, 0.f};
      #pragma unroll
      for(int ks = 0; ks < 4; ks++){
        bfrag bf = *(const bfrag*)(Wg + (((size_t)(ks * 4 + kg) * 64 + col) << 3));
        acc = __builtin_amdgcn_mfma_f32_16x16x32_bf16(a[ks], bf, acc, 0, 0, 0);
      }
      float bv = P.bias[g][col];
      #pragma unroll
      for(int i = 0; i < 4; i++){
        int r = orow0 + i;
        int rr = (r < N_NODES) ? r : N_NODES - 1;
        float v = acc[i] + bv + b2f(P.ag3[(size_t)g * N_NODES * 64 + (size_t)rr * 64 + col]);
        v = fmaxf(v, 0.f);
        unsigned short hh = f2b(v);
        if(g == 0) ytile[w * 16 + kg * 4 + i][col] = hh;
        if(r < N_NODES) og[(size_t)r * 64 + col] = hh;
      }
    }
  }
  __syncthreads();
  // TBs = y0 @ Wl1 (A-frags from LDS)
  bfrag a2[2];
  a2[0] = *(const bfrag*)&ytile[w * 16 + l15][kg * 8];
  a2[1] = *(const bfrag*)&ytile[w * 16 + l15][32 + kg * 8];
  #pragma unroll
  for(int ct = 0; ct < 4; ct++){
    int col = ct * 16 + l15;
    ffrag acc = {0.f, 0.f, 0.f, 0.f};
    bfrag b0 = *(const bfrag*)(P.Wl1 + (((size_t)(0 * 4 + kg) * 64 + col) << 3));
    bfrag b1 = *(const bfrag*)(P.Wl1 + (((size_t)(1 * 4 + kg) * 64 + col) << 3));
    acc = __builtin_amdgcn_mfma_f32_16x16x32_bf16(a2[0], b0, acc, 0, 0, 0);
    acc = __builtin_amdgcn_mfma_f32_16x16x32_bf16(a2[1], b1, acc, 0, 0, 0);
    #pragma unroll
    for(int i = 0; i < 4; i++){
      int r = orow0 + i;
      if(r >= N_NODES) break;
      P.tbs[(size_t)r * 64 + col] = f2b(acc[i]);
    }
  }
}

// ========== step 5 + 6 + 7 fused: Y = y0@Wr1 + AG + b1; gating -> lo; cvec tails ==========
struct YG {
  const unsigned short* Wr1;
  const float* b1;
  const float* AG;
  const unsigned short *t0b, *t1b;
  const float *gate_W, *gate_b;
  unsigned short* lo;
  const float *ee, *ne, *eaW1, *eab1, *fmW, *fmb;
  float *cE, *cF;
  int ggm;
};

__global__ __launch_bounds__(256)
void k_ygates(const unsigned short* __restrict__ y0b, YG P){
  if(blockIdx.x >= P.ggm){
    int which = blockIdx.x - P.ggm;
    int j = threadIdx.x;
    if(j < 128){
      if(which == 0){
        float s = P.eab1[j];
        for(int k = 0; k < 64; k++) s += P.ee[k] * P.eaW1[(128 + k) * 128 + j];
        P.cE[j] = s;
      } else {
        float s = P.fmb[j];
        for(int k = 0; k < 64; k++) s += P.ne[k] * P.fmW[(192 + k) * 128 + j];
        P.cF[j] = s;
      }
    }
    return;
  }
  int tid = threadIdx.x, lane = tid & 63, w = tid >> 6;
  int row0 = blockIdx.x * 64 + w * 16;
  int l15 = lane & 15, kg = lane >> 4;
  int arow = row0 + l15; if(arow > N_NODES - 1) arow = N_NODES - 1;
  bfrag a0f = *(const bfrag*)(y0b + (size_t)arow * 64 + kg * 8);
  bfrag a1f = *(const bfrag*)(y0b + (size_t)arow * 64 + 32 + kg * 8);
  int orow0 = row0 + kg * 4;
  float vv[4][4], t0v[4][4], t1v[4][4];
  float gw0[4], gw1[4];
  #pragma unroll
  for(int ct = 0; ct < 4; ct++){
    int col = ct * 16 + l15;
    gw0[ct] = P.gate_W[col];
    gw1[ct] = P.gate_W[64 + col];
  }
  #pragma unroll
  for(int ct = 0; ct < 4; ct++){
    int col = ct * 16 + l15;
    ffrag acc = {0.f, 0.f, 0.f, 0.f};
    bfrag b0 = *(const bfrag*)(P.Wr1 + (((size_t)(0 * 4 + kg) * 64 + col) << 3));
    bfrag b1 = *(const bfrag*)(P.Wr1 + (((size_t)(1 * 4 + kg) * 64 + col) << 3));
    acc = __builtin_amdgcn_mfma_f32_16x16x32_bf16(a0f, b0, acc, 0, 0, 0);
    acc = __builtin_amdgcn_mfma_f32_16x16x32_bf16(a1f, b1, acc, 0, 0, 0);
    float bv = P.b1[col];
    #pragma unroll
    for(int i = 0; i < 4; i++){
      int r = orow0 + i;
      int rr = (r < N_NODES) ? r : N_NODES - 1;
      vv[i][ct] = acc[i] + bv + P.AG[(size_t)rr * 64 + col];
      t0v[i][ct] = b2f(P.t0b[(size_t)rr * 64 + col]);
      t1v[i][ct] = b2f(P.t1b[(size_t)rr * 64 + col]);
    }
  }
  float pg0[4] = {0.f, 0.f, 0.f, 0.f}, pg1[4] = {0.f, 0.f, 0.f, 0.f};
  #pragma unroll
  for(int i = 0; i < 4; i++)
    #pragma unroll
    for(int ct = 0; ct < 4; ct++){
      pg0[i] += t0v[i][ct] * gw0[ct];
      pg1[i] += t1v[i][ct] * gw1[ct];
    }
  #pragma unroll
  for(int off = 1; off < 16; off <<= 1){
    #pragma unroll
    for(int i = 0; i < 4; i++){
      pg0[i] += __shfl_xor(pg0[i], off, 64);
      pg1[i] += __shfl_xor(pg1[i], off, 64);
    }
  }
  float gb0 = P.gate_b[0], gb1 = P.gate_b[1];
  #pragma unroll
  for(int i = 0; i < 4; i++){
    int r = orow0 + i;
    if(r >= N_NODES) break;
    float g0 = pg0[i] + gb0, g1 = pg1[i] + gb1;
    float m = fmaxf(g0, g1);
    float e0 = expf(g0 - m), e1 = expf(g1 - m);
    float av = e0 / (e0 + e1);
    #pragma unroll
    for(int ct = 0; ct < 4; ct++){
      int col = ct * 16 + l15;
      P.lo[(size_t)r * 64 + col] = f2b(vv[i][ct] + av * t0v[i][ct] + (1.f - av) * t1v[i][ct]);
    }
  }
}

// ========== step 8 + 11 + 13 fused: AB = lo@Ea*; MX = x*([lo|x]@fmW+cF) (LDS); xW0 = MX@G0 ==========
struct ABMX2 {
  const unsigned short* Wea[4];
  const unsigned short* Wfm[2];
  const unsigned short* G0;
  const float* cF;
  const float* xf32;
  unsigned short* ab;
  unsigned short* xw0;
};

__global__ __launch_bounds__(256)
void k_abmx2(const unsigned short* __restrict__ LOb, const unsigned short* __restrict__ xb, ABMX2 P){
  __shared__ unsigned short mxtile[64][136];
  int tid = threadIdx.x, lane = tid & 63, w = tid >> 6;
  int row0 = blockIdx.x * 64 + w * 16;
  int l15 = lane & 15, kg = lane >> 4;
  int arow = row0 + l15; if(arow > N_NODES - 1) arow = N_NODES - 1;
  bfrag a[6];
  a[0] = *(const bfrag*)(LOb + (size_t)arow * 64 + kg * 8);
  a[1] = *(const bfrag*)(LOb + (size_t)arow * 64 + 32 + kg * 8);
  #pragma unroll
  for(int ks = 0; ks < 4; ks++)
    a[2 + ks] = *(const bfrag*)(xb + (size_t)arow * 128 + ks * 32 + kg * 8);
  int orow0 = row0 + kg * 4;
  #pragma unroll
  for(int g = 0; g < 4; g++){
    const unsigned short* Wg = P.Wea[g];
    #pragma unroll
    for(int ct = 0; ct < 4; ct++){
      int col = ct * 16 + l15;
      ffrag acc = {0.f, 0.f, 0.f, 0.f};
      bfrag b0 = *(const bfrag*)(Wg + (((size_t)(0 * 4 + kg) * 64 + col) << 3));
      bfrag b1 = *(const bfrag*)(Wg + (((size_t)(1 * 4 + kg) * 64 + col) << 3));
      acc = __builtin_amdgcn_mfma_f32_16x16x32_bf16(a[0], b0, acc, 0, 0, 0);
      acc = __builtin_amdgcn_mfma_f32_16x16x32_bf16(a[1], b1, acc, 0, 0, 0);
      #pragma unroll
      for(int i = 0; i < 4; i++){
        int r = orow0 + i;
        if(r >= N_NODES) break;
        P.ab[(size_t)r * 256 + g * 64 + col] = f2b(acc[i]);
      }
    }
  }
  #pragma unroll
  for(int g = 0; g < 2; g++){
    const unsigned short* Wg = P.Wfm[g];
    #pragma unroll
    for(int ct = 0; ct < 4; ct++){
      int col = ct * 16 + l15;
      ffrag acc = {0.f, 0.f, 0.f, 0.f};
      #pragma unroll
      for(int ks = 0; ks < 6; ks++){
        bfrag bf = *(const bfrag*)(Wg + (((size_t)(ks * 4 + kg) * 64 + col) << 3));
        acc = __builtin_amdgcn_mfma_f32_16x16x32_bf16(a[ks], bf, acc, 0, 0, 0);
      }
      float bv = P.cF[g * 64 + col];
      #pragma unroll
      for(int i = 0; i < 4; i++){
        int r = orow0 + i;
        int rr = (r < N_NODES) ? r : N_NODES - 1;
        float v = (acc[i] + bv) * P.xf32[(size_t)rr * 128 + g * 64 + col];
        mxtile[w * 16 + kg * 4 + i][g * 64 + col] = f2b(v);
      }
    }
  }
  __syncthreads();
  // xW0 = MX @ G0 (A-frags from LDS)
  bfrag a3[4];
  #pragma unroll
  for(int ks = 0; ks < 4; ks++)
    a3[ks] = *(const bfrag*)&mxtile[w * 16 + l15][ks * 32 + kg * 8];
  #pragma unroll
  for(int ct = 0; ct < 4; ct++){
    int col = ct * 16 + l15;
    ffrag acc = {0.f, 0.f, 0.f, 0.f};
    #pragma unroll
    for(int ks = 0; ks < 4; ks++){
      bfrag bf = *(const bfrag*)(P.G0 + (((size_t)(ks * 4 + kg) * 64 + col) << 3));
      acc = __builtin_amdgcn_mfma_f32_16x16x32_bf16(a3[ks], bf, acc, 0, 0, 0);
    }
    #pragma unroll
    for(int i = 0; i < 4; i++){
      int r = orow0 + i;
      if(r >= N_NODES) break;
      P.xw0[(size_t)r * 64 + col] = f2b(acc[i]);
    }
  }
}

// ================= mean aggregation (quarter-wave uint2, 2x unroll) =================
template<int OUTB>
__global__ void k_aggq(const unsigned short* __restrict__ TB, int tst,
                       const int* __restrict__ indptr, const int* __restrict__ csr,
                       void* __restrict__ out){
  int br = blockIdx.y;
  const unsigned short* T = TB + (size_t)br * tst;
  const int* ip = indptr + (size_t)br * (N_NODES + 1);
  const int* cs = csr + (size_t)br * NEDGE;
  int lane = threadIdx.x & 63, wid = threadIdx.x >> 6;
  int node = blockIdx.x * 4 + wid;
  if(node >= N_NODES) return;
  int q = lane >> 4, c = lane & 15;
  int beg = ip[node], end = ip[node + 1];
  int cnt = end - beg;
  float sc = 1.0f / (float)(cnt >= 1 ? cnt : 1);
  float a0 = 0.f, a1 = 0.f, a2 = 0.f, a3 = 0.f;
  int j = beg + q;
  for(; j + 4 < end; j += 8){
    int s0 = cs[j], s1 = cs[j + 4];
    uint2 u0 = *(const uint2*)(T + (size_t)s0 * 64 + c * 4);
    uint2 u1 = *(const uint2*)(T + (size_t)s1 * 64 + c * 4);
    a0 += b2f_lo(u0.x) + b2f_lo(u1.x); a1 += b2f_hi(u0.x) + b2f_hi(u1.x);
    a2 += b2f_lo(u0.y) + b2f_lo(u1.y); a3 += b2f_hi(u0.y) + b2f_hi(u1.y);
  }
  if(j < end){
    int s = cs[j];
    uint2 u = *(const uint2*)(T + (size_t)s * 64 + c * 4);
    a0 += b2f_lo(u.x); a1 += b2f_hi(u.x);
    a2 += b2f_lo(u.y); a3 += b2f_hi(u.y);
  }
  a0 += __shfl_xor(a0, 16, 64); a1 += __shfl_xor(a1, 16, 64);
  a2 += __shfl_xor(a2, 16, 64); a3 += __shfl_xor(a3, 16, 64);
  a0 += __shfl_xor(a0, 32, 64); a1 += __shfl_xor(a1, 32, 64);
  a2 += __shfl_xor(a2, 32, 64); a3 += __shfl_xor(a3, 32, 64);
  if(q == 0){
    if(OUTB){
      ushort4 o; o.x = f2b(a0 * sc); o.y = f2b(a1 * sc); o.z = f2b(a2 * sc); o.w = f2b(a3 * sc);
      *(ushort4*)((unsigned short*)out + (size_t)br * tst + (size_t)node * 64 + c * 4) = o;
    } else {
      *(float4*)((float*)out + (size_t)node * 64 + c * 4) = float4{a0 * sc, a1 * sc, a2 * sc, a3 * sc};
    }
  }
}

// ========== per-edge MLP (quarter-wave uint4, 2x unroll, fused sumem + block minmax) ==========
__global__ void k_em2(const unsigned short* __restrict__ AB,
                      const int* __restrict__ indptr, const int* __restrict__ csr_src,
                      const float* __restrict__ cvec, const float* __restrict__ W2,
                      const float* __restrict__ b2, float* __restrict__ em,
                      float* __restrict__ sumem, float* __restrict__ pmn, float* __restrict__ pmx){
  int lane = threadIdx.x & 63, wid = threadIdx.x >> 6;
  int node = blockIdx.x * 4 + wid;
  float mn = 3.4e38f, mx = -3.4e38f;
  if(node < N_NODES){
    int q = lane >> 4, c = lane & 15;
    uint4 bu = *(const uint4*)(AB + (size_t)node * 256 + 128 + c * 8);
    float4 cva = *(const float4*)&cvec[c * 8];
    float4 cvb = *(const float4*)&cvec[c * 8 + 4];
    float4 wva = *(const float4*)&W2[c * 8];
    float4 wvb = *(const float4*)&W2[c * 8 + 4];
    float cc0 = b2f_lo(bu.x) + cva.x, cc1 = b2f_hi(bu.x) + cva.y;
    float cc2 = b2f_lo(bu.y) + cva.z, cc3 = b2f_hi(bu.y) + cva.w;
    float cc4 = b2f_lo(bu.z) + cvb.x, cc5 = b2f_hi(bu.z) + cvb.y;
    float cc6 = b2f_lo(bu.w) + cvb.z, cc7 = b2f_hi(bu.w) + cvb.w;
    float b2v = b2[0];
    int beg = indptr[node], end = indptr[node + 1];
    float ssum = 0.f;
    int j = beg + q;
    for(; j + 4 < end; j += 8){
      int s0 = csr_src[j], s1 = csr_src[j + 4];
      uint4 u0 = *(const uint4*)(AB + (size_t)s0 * 256 + c * 8);
      uint4 u1 = *(const uint4*)(AB + (size_t)s1 * 256 + c * 8);
      float v0 = fmaxf(b2f_lo(u0.x) + cc0, 0.f) * wva.x + fmaxf(b2f_hi(u0.x) + cc1, 0.f) * wva.y
               + fmaxf(b2f_lo(u0.y) + cc2, 0.f) * wva.z + fmaxf(b2f_hi(u0.y) + cc3, 0.f) * wva.w
               + fmaxf(b2f_lo(u0.z) + cc4, 0.f) * wvb.x + fmaxf(b2f_hi(u0.z) + cc5, 0.f) * wvb.y
               + fmaxf(b2f_lo(u0.w) + cc6, 0.f) * wvb.z + fmaxf(b2f_hi(u0.w) + cc7, 0.f) * wvb.w;
      float v1 = fmaxf(b2f_lo(u1.x) + cc0, 0.f) * wva.x + fmaxf(b2f_hi(u1.x) + cc1, 0.f) * wva.y
               + fmaxf(b2f_lo(u1.y) + cc2, 0.f) * wva.z + fmaxf(b2f_hi(u1.y) + cc3, 0.f) * wva.w
               + fmaxf(b2f_lo(u1.z) + cc4, 0.f) * wvb.x + fmaxf(b2f_hi(u1.z) + cc5, 0.f) * wvb.y
               + fmaxf(b2f_lo(u1.w) + cc6, 0.f) * wvb.z + fmaxf(b2f_hi(u1.w) + cc7, 0.f) * wvb.w;
      #pragma unroll
      for(int off = 1; off < 16; off <<= 1){
        v0 += __shfl_xor(v0, off, 64);
        v1 += __shfl_xor(v1, off, 64);
      }
      float r0 = v0 + b2v, r1 = v1 + b2v;
      if(c == 0){ em[j] = r0; em[j + 4] = r1; }
      ssum += r0 + r1;
      mn = fminf(mn, fminf(r0, r1)); mx = fmaxf(mx, fmaxf(r0, r1));
    }
    if(j < end){
      int s = csr_src[j];
      uint4 u = *(const uint4*)(AB + (size_t)s * 256 + c * 8);
      float v = fmaxf(b2f_lo(u.x) + cc0, 0.f) * wva.x + fmaxf(b2f_hi(u.x) + cc1, 0.f) * wva.y
              + fmaxf(b2f_lo(u.y) + cc2, 0.f) * wva.z + fmaxf(b2f_hi(u.y) + cc3, 0.f) * wva.w
              + fmaxf(b2f_lo(u.z) + cc4, 0.f) * wvb.x + fmaxf(b2f_hi(u.z) + cc5, 0.f) * wvb.y
              + fmaxf(b2f_lo(u.w) + cc6, 0.f) * wvb.z + fmaxf(b2f_hi(u.w) + cc7, 0.f) * wvb.w;
      #pragma unroll
      for(int off = 1; off < 16; off <<= 1) v += __shfl_xor(v, off, 64);
      float r = v + b2v;
      if(c == 0) em[j] = r;
      ssum += r;
      mn = fminf(mn, r); mx = fmaxf(mx, r);
    }
    ssum += __shfl_xor(ssum, 16, 64); ssum += __shfl_xor(ssum, 32, 64);
    mn = fminf(mn, __shfl_xor(mn, 16, 64)); mn = fminf(mn, __shfl_xor(mn, 32, 64));
    mx = fmaxf(mx, __shfl_xor(mx, 16, 64)); mx = fmaxf(mx, __shfl_xor(mx, 32, 64));
    if(lane == 0) sumem[node] = ssum;
  }
  __shared__ float bmn[4], bmx[4];
  if(lane == 0){ bmn[wid] = mn; bmx[wid] = mx; }
  __syncthreads();
  if(threadIdx.x == 0){
    pmn[blockIdx.x] = fminf(fminf(bmn[0], bmn[1]), fminf(bmn[2], bmn[3]));
    pmx[blockIdx.x] = fmaxf(fmaxf(bmx[0], bmx[1]), fmaxf(bmx[2], bmx[3]));
  }
}

// ================= dinv + absorbed min/max final =================
__global__ void k_dinv2(const int* __restrict__ indptr, const float* __restrict__ sumem,
                        const float* __restrict__ pmn, const float* __restrict__ pmx, int nb,
                        float* __restrict__ scal, float* __restrict__ dinv){
  __shared__ float smn[256], smx[256];
  int tid = threadIdx.x;
  float mn = 3.4e38f, mx = -3.4e38f;
  for(int i = tid; i < nb; i += 256){
    mn = fminf(mn, pmn[i]); mx = fmaxf(mx, pmx[i]);
  }
  smn[tid] = mn; smx[tid] = mx; __syncthreads();
  for(int s = 128; s > 0; s >>= 1){
    if(tid < s){ smn[tid] = fminf(smn[tid], smn[tid + s]); smx[tid] = fmaxf(smx[tid], smx[tid + s]); }
    __syncthreads();
  }
  float mn0 = smn[0];
  float inv = 1.0f / fmaxf(smx[0] - mn0, 1e-30f);
  if(blockIdx.x == 0 && tid == 0){ scal[0] = mn0; scal[1] = inv; }
  int i = blockIdx.x * 256 + tid;
  if(i >= N_NODES) return;
  float cnt = (float)(indptr[i + 1] - indptr[i]);
  dinv[i] = rsqrtf(1.f + (sumem[i] - cnt * mn0) * inv);
}

// ================= GCN layer (eighth-wave uint4, 2x unroll) =================
template<int RELU, int OUTB>
__global__ void k_gcn(const unsigned short* __restrict__ xW, const int* __restrict__ indptr,
                      const int* __restrict__ csr_src, const float* __restrict__ em,
                      const float* __restrict__ scal, const float* __restrict__ dinv,
                      const float* __restrict__ bias, void* __restrict__ out, int ostride){
  int lane = threadIdx.x & 63, wid = threadIdx.x >> 6;
  int node = blockIdx.x * 4 + wid;
  if(node >= N_NODES) return;
  int q = lane >> 3, c = lane & 7;
  float mn = scal[0], inv = scal[1];
  float di = dinv[node];
  float a0=0.f,a1=0.f,a2=0.f,a3=0.f,a4=0.f,a5=0.f,a6=0.f,a7=0.f;
  int beg = indptr[node], end = indptr[node + 1];
  int j = beg + q;
  for(; j + 8 < end; j += 16){
    int s0 = csr_src[j], s1 = csr_src[j + 8];
    float w0 = (em[j] - mn) * inv * dinv[s0];
    float w1 = (em[j + 8] - mn) * inv * dinv[s1];
    uint4 u0 = *(const uint4*)(xW + (size_t)s0 * 64 + c * 8);
    uint4 u1 = *(const uint4*)(xW + (size_t)s1 * 64 + c * 8);
    a0 += w0 * b2f_lo(u0.x) + w1 * b2f_lo(u1.x); a1 += w0 * b2f_hi(u0.x) + w1 * b2f_hi(u1.x);
    a2 += w0 * b2f_lo(u0.y) + w1 * b2f_lo(u1.y); a3 += w0 * b2f_hi(u0.y) + w1 * b2f_hi(u1.y);
    a4 += w0 * b2f_lo(u0.z) + w1 * b2f_lo(u1.z); a5 += w0 * b2f_hi(u0.z) + w1 * b2f_hi(u1.z);
    a6 += w0 * b2f_lo(u0.w) + w1 * b2f_lo(u1.w); a7 += w0 * b2f_hi(u0.w) + w1 * b2f_hi(u1.w);
  }
  if(j < end){
    int s = csr_src[j];
    float wv = (em[j] - mn) * inv * dinv[s];
    uint4 u = *(const uint4*)(xW + (size_t)s * 64 + c * 8);
    a0 += wv * b2f_lo(u.x); a1 += wv * b2f_hi(u.x);
    a2 += wv * b2f_lo(u.y); a3 += wv * b2f_hi(u.y);
    a4 += wv * b2f_lo(u.z); a5 += wv * b2f_hi(u.z);
    a6 += wv * b2f_lo(u.w); a7 += wv * b2f_hi(u.w);
  }
  #pragma unroll
  for(int off = 8; off < 64; off <<= 1){
    a0 += __shfl_xor(a0, off, 64); a1 += __shfl_xor(a1, off, 64);
    a2 += __shfl_xor(a2, off, 64); a3 += __shfl_xor(a3, off, 64);
    a4 += __shfl_xor(a4, off, 64); a5 += __shfl_xor(a5, off, 64);
    a6 += __shfl_xor(a6, off, 64); a7 += __shfl_xor(a7, off, 64);
  }
  if(q == 0){
    uint4 su = *(const uint4*)(xW + (size_t)node * 64 + c * 8);
    float4 bva = *(const float4*)&bias[c * 8];
    float4 bvb = *(const float4*)&bias[c * 8 + 4];
    float dd = di * di;
    float r0 = a0 * di + b2f_lo(su.x) * dd + bva.x;
    float r1 = a1 * di + b2f_hi(su.x) * dd + bva.y;
    float r2 = a2 * di + b2f_lo(su.y) * dd + bva.z;
    float r3 = a3 * di + b2f_hi(su.y) * dd + bva.w;
    float r4 = a4 * di + b2f_lo(su.z) * dd + bvb.x;
    float r5 = a5 * di + b2f_hi(su.z) * dd + bvb.y;
    float r6 = a6 * di + b2f_lo(su.w) * dd + bvb.z;
    float r7 = a7 * di + b2f_hi(su.w) * dd + bvb.w;
    if(RELU){
      r0 = fmaxf(r0, 0.f); r1 = fmaxf(r1, 0.f); r2 = fmaxf(r2, 0.f); r3 = fmaxf(r3, 0.f);
      r4 = fmaxf(r4, 0.f); r5 = fmaxf(r5, 0.f); r6 = fmaxf(r6, 0.f); r7 = fmaxf(r7, 0.f);
    }
    if(OUTB){
      uint4 o;
      o.x = pk2(r0, r1); o.y = pk2(r2, r3); o.z = pk2(r4, r5); o.w = pk2(r6, r7);
      *(uint4*)((unsigned short*)out + (size_t)node * ostride + c * 8) = o;
    } else {
      float* o = (float*)out + (size_t)node * ostride + c * 8;
      *(float4*)o       = float4{r0, r1, r2, r3};
      *(float4*)(o + 4) = float4{r4, r5, r6, r7};
    }
  }
}

// ================= logits + log_softmax =================
__global__ void k_logits(const float* __restrict__ xt, const float* __restrict__ lin_W,
                         const float* __restrict__ lin_b, float* __restrict__ out){
  int lane = threadIdx.x & 63, wid = threadIdx.x >> 6;
  int node = blockIdx.x * 4 + wid;
  if(node >= N_NODES) return;
  float a0 = 0.f, a1 = 0.f;
  #pragma unroll
  for(int q = 0; q < 3; q++){
    int k = q * 64 + lane;
    float v = xt[(size_t)node * 192 + k];
    a0 += v * lin_W[k * 2 + 0];
    a1 += v * lin_W[k * 2 + 1];
  }
  a0 = wave_red(a0);
  a1 = wave_red(a1);
  if(lane == 0){
    float l0 = fminf(fmaxf(a0 + lin_b[0], -1e10f), 1e10f);
    float l1 = fminf(fmaxf(a1 + lin_b[1], -1e10f), 1e10f);
    float m = fmaxf(l0, l1);
    float d = expf(l0 - m) + expf(l1 - m);
    float ls = m + logf(d);
    out[(size_t)node * 2 + 0] = l0 - ls;
    out[(size_t)node * 2 + 1] = l1 - ls;
  }
}

// =====================================================================
extern "C" void kernel_launch(void* const* d_in, const int* in_sizes, int n_in,
                              void* d_out, int out_size, void* d_ws, size_t ws_size,
                              hipStream_t stream){
  (void)in_sizes; (void)n_in; (void)out_size;
  const int N = N_NODES, E = NEDGE;

  const float* x        = (const float*)d_in[0];
  const int*  edge_main = (const int*)d_in[1];
  const int*  edge_tree = (const int*)d_in[2];
  const float* sage_Wl0 = (const float*)d_in[3];
  const float* sage_Wr0 = (const float*)d_in[4];
  const float* sage_b0  = (const float*)d_in[5];
  const float* sage_Wl1 = (const float*)d_in[6];
  const float* sage_Wr1 = (const float*)d_in[7];
  const float* sage_b1  = (const float*)d_in[8];
  const float* tree_Wl  = (const float*)d_in[9];
  const float* tree_Wr  = (const float*)d_in[10];
  const float* tree_b   = (const float*)d_in[11];
  const float* gate_W   = (const float*)d_in[12];
  const float* gate_b   = (const float*)d_in[13];
  const float* node_emb = (const float*)d_in[14];
  const float* edge_emb = (const float*)d_in[15];
  const float* fm_W     = (const float*)d_in[16];
  const float* fm_b     = (const float*)d_in[17];
  const float* ea_W1    = (const float*)d_in[18];
  const float* ea_b1    = (const float*)d_in[19];
  const float* ea_W2    = (const float*)d_in[20];
  const float* ea_b2    = (const float*)d_in[21];
  const float* gcn_W0   = (const float*)d_in[22];
  const float* gcn_b0   = (const float*)d_in[23];
  const float* gcn_W1   = (const float*)d_in[24];
  const float* gcn_b1   = (const float*)d_in[25];
  const float* lin_W    = (const float*)d_in[26];
  const float* lin_b    = (const float*)d_in[27];

  float* out_lsm   = (float*)d_out;
  float* out_xtemp = (float*)d_out + (size_t)N * NCLS;

  // ---- workspace (~93.4 MB, phase-overlaid) ----
  char* ws = (char*)d_ws;
  unsigned short* TB3  = (unsigned short*)(ws + 0);          // bf16 [3][N][64] (steps 1-2)
  unsigned short* TBs  = (unsigned short*)(ws + 0);          // bf16 [N,64] (steps 3-4)
  unsigned short* AB   = (unsigned short*)(ws + 0);          // bf16 [N,256] (steps 6-7)
  unsigned short* AG3  = (unsigned short*)(ws + 19200000);   // bf16 [3][N][64] (step 2)
  float*          AG   = (float*)(ws + 19200000);            // f32 [N,64] (steps 4-5)
  unsigned short* LOb  = (unsigned short*)(ws + 32000000);   // bf16 [N,64] (steps 5-6)
  unsigned short* y0b  = (unsigned short*)(ws + 38400000);   // bf16 [N,64] (steps 3-5)
  unsigned short* xW0b = (unsigned short*)(ws + 38400000);   // bf16 [N,64] (steps 6-9, after y0b dead)
  unsigned short* T0b  = (unsigned short*)(ws + 44800000);   // (steps 3-5)
  unsigned short* z0b  = (unsigned short*)(ws + 44800000);   // (steps 9-10)
  unsigned short* T1b  = (unsigned short*)(ws + 51200000);   // (steps 3-5)
  unsigned short* xW1b = (unsigned short*)(ws + 51200000);   // (steps 10-11)
  unsigned short* xb   = (unsigned short*)(ws + 57600000);   // bf16 [N,128] persistent
  int*   bucketed = (int*)(ws + 0);                          // CSR phase only
  unsigned short* Wpk = (unsigned short*)(ws + 70400000);
  int*   csr9     = (int*)(ws + 71000064);
  int*   indptr9  = (int*)(ws + 89000064);
  float* em       = (float*)(ws + 90800128);
  float* sumem    = (float*)(ws + 92800128);
  float* dinv     = (float*)(ws + 93000128);
  int*   cursor   = (int*)(ws + 93200128);
  int*   bktbase  = (int*)(ws + 93214208);
  float* cvecE    = (float*)(ws + 93228288);
  float* cvecF    = (float*)(ws + 93228800);
  float* scal     = (float*)(ws + 93229312);
  float* pmn      = (float*)(ws + 93229568);
  float* pmx      = (float*)(ws + 93279568);
  if(ws_size < 93330000) return;

  const int GN4 = (N + 3) / 4;
  const int GN  = (N + 255) / 256;
  const int GGM = (N + 63) / 64;
  const int NCH = (E + CHUNK - 1) / CHUNK;

  // ---- weight pack jobs ----
  PackJobs PJ[2]; PJ[0].n = 0; PJ[1].n = 0;
  int npj = 0, dstElem = 0;
  const unsigned short* WlpA[NREL]; const unsigned short* WlpB[NREL]; const unsigned short* WlpC[NREL];
  const unsigned short* Wr0j[NREL]; const unsigned short* WrT0[NREL]; const unsigned short* WrT1[NREL];
  const unsigned short* Wl1j[NREL]; const unsigned short* Wr1j[NREL];
  const unsigned short* Fm0j[NREL]; const unsigned short* Fm1j[NREL];
  const unsigned short* G0j[NREL];  const unsigned short* G1j[NREL];
  const unsigned short *EaA0, *EaA1, *EaB0, *EaB1;
  auto addjob = [&](const float* src, int wst, int K) -> const unsigned short* {
    int slot = npj < 20 ? 0 : 1;
    int k = npj - slot * 20;
    PJ[slot].src[k] = src; PJ[slot].wst[k] = wst; PJ[slot].K[k] = K; PJ[slot].dst[k] = dstElem;
    PJ[slot].n = k + 1;
    const unsigned short* ret = Wpk + dstElem;
    dstElem += K * 64; npj++;
    return ret;
  };
  for(int r = 0; r < NREL; r++){
    WlpA[r] = addjob(sage_Wl0 + (size_t)r * 8192, 64, 128);
    WlpB[r] = addjob(tree_Wl + (size_t)(r * NTREE + 0) * 8192, 64, 128);
    WlpC[r] = addjob(tree_Wl + (size_t)(r * NTREE + 1) * 8192, 64, 128);
    Wr0j[r] = addjob(sage_Wr0 + (size_t)r * 8192, 64, 128);
    WrT0[r] = addjob(tree_Wr + (size_t)(r * NTREE + 0) * 8192, 64, 128);
    WrT1[r] = addjob(tree_Wr + (size_t)(r * NTREE + 1) * 8192, 64, 128);
    Wl1j[r] = addjob(sage_Wl1 + (size_t)r * 4096, 64, 64);
    Wr1j[r] = addjob(sage_Wr1 + (size_t)r * 4096, 64, 64);
    Fm0j[r] = addjob(fm_W + (size_t)r * 32768, 128, 192);
    Fm1j[r] = addjob(fm_W + (size_t)r * 32768 + 64, 128, 192);
    G0j[r]  = addjob(gcn_W0 + (size_t)r * 8192, 64, 128);
    G1j[r]  = addjob(gcn_W1 + (size_t)r * 4096, 64, 64);
  }
  EaA0 = addjob(ea_W1, 128, 64);
  EaA1 = addjob(ea_W1 + 64, 128, 64);
  EaB0 = addjob(ea_W1 + 64 * 128, 128, 64);
  EaB1 = addjob(ea_W1 + 64 * 128 + 64, 128, 64);

  // ---- CSR build for all 9 edge sets ----
  EdgePtrs ep;
  for(int r = 0; r < NREL; r++){
    ep.s[r * 3 + 0] = edge_main + (size_t)r * 2 * E;
    ep.d[r * 3 + 0] = ep.s[r * 3 + 0] + E;
    for(int t = 0; t < NTREE; t++){
      ep.s[r * 3 + 1 + t] = edge_tree + ((size_t)(r * NTREE + t) * 2) * E;
      ep.d[r * 3 + 1 + t] = ep.s[r * 3 + 1 + t] + E;
    }
  }
  hipMemsetAsync(cursor, 0, 9 * BKT * 4, stream);
  k_passA<<<dim3(NCH, 9), 256, 0, stream>>>(ep, cursor, bucketed);
  k_scanB<<<9, 512, 0, stream>>>(cursor, bktbase, indptr9);
  k_passB<<<dim3(BKT, 9), 256, 0, stream>>>(bucketed, cursor, bktbase, indptr9, csr9);

  // ---- one-time conversions ----
  k_wpack<<<PJ[0].n, 256, 0, stream>>>(PJ[0], Wpk);
  k_wpack<<<PJ[1].n, 256, 0, stream>>>(PJ[1], Wpk);
  k_tobf16<<<(N * 128 / 4 + 255) / 256, 256, 0, stream>>>(x, xb, N * 128 / 4);

  for(int r = 0; r < NREL; r++){
    const int* ipM = indptr9 + (size_t)(r * 3) * (N + 1);
    const int* csM = csr9 + (size_t)(r * 3) * E;

    // 1. Wl-pack: TB3[br] = bf16( x @ Wl[br] )
    { MG p{}; p.ost = 64;
      p.Wt[0] = WlpA[r]; p.Wt[1] = WlpB[r]; p.Wt[2] = WlpC[r];
      p.out[0] = TB3; p.out[1] = TB3 + (size_t)N * 64; p.out[2] = TB3 + (size_t)2 * N * 64;
      k_mgemm<128, 3, 1><<<GGM, 256, 0, stream>>>(xb, 128, p); }

    // 2. batched aggs for 3 branches -> AG3 (bf16)
    k_aggq<1><<<dim3(GN4, 3), 256, 0, stream>>>(TB3, N * 64, ipM, csM, AG3);

    // 3. fused: y0/T0/T1 = relu(x@Wr + AG3 + b); TBs = y0@Wl1
    { S23 p{};
      p.Wr[0] = Wr0j[r]; p.bias[0] = sage_b0 + r * 64;
      p.Wr[1] = WrT0[r]; p.bias[1] = tree_b + (size_t)(r * NTREE + 0) * 64;
      p.Wr[2] = WrT1[r]; p.bias[2] = tree_b + (size_t)(r * NTREE + 1) * 64;
      p.ag3 = AG3; p.Wl1 = Wl1j[r];
      p.y0 = y0b; p.t0 = T0b; p.t1 = T1b; p.tbs = TBs;
      k_s23<<<GGM, 256, 0, stream>>>(xb, p); }

    // 4. AG = agg(TBs, main), f32
    k_aggq<0><<<dim3(GN4, 1), 256, 0, stream>>>(TBs, N * 64, ipM, csM, AG);

    // 5. fused: Y = y0@Wr1 + AG + b1; gating -> lo; cvecE/cvecF in 2 tail blocks
    { YG p{};
      p.Wr1 = Wr1j[r]; p.b1 = sage_b1 + r * 64; p.AG = AG;
      p.t0b = T0b; p.t1b = T1b;
      p.gate_W = gate_W + (size_t)r * 128; p.gate_b = gate_b + r * 2;
      p.lo = LOb;
      p.ee = edge_emb + r * 64; p.ne = node_emb + r * 64;
      p.eaW1 = ea_W1; p.eab1 = ea_b1;
      p.fmW = fm_W + (size_t)r * 32768; p.fmb = fm_b + r * 128;
      p.cE = cvecE; p.cF = cvecF; p.ggm = GGM;
      k_ygates<<<GGM + 2, 256, 0, stream>>>(y0b, p); }

    // 6. fused: AB = lo@Ea*; MX in LDS; xW0 = MX@G0
    { ABMX2 p{};
      p.Wea[0] = EaA0; p.Wea[1] = EaA1; p.Wea[2] = EaB0; p.Wea[3] = EaB1;
      p.Wfm[0] = Fm0j[r]; p.Wfm[1] = Fm1j[r];
      p.G0 = G0j[r]; p.cF = cvecF; p.xf32 = x;
      p.ab = AB; p.xw0 = xW0b;
      k_abmx2<<<GGM, 256, 0, stream>>>(LOb, xb, p); }

    // 7. em (fused sumem + block min/max partials)
    k_em2<<<GN4, 256, 0, stream>>>(AB, ipM, csM, cvecE, ea_W2, ea_b2, em, sumem, pmn, pmx);

    // 8. dinv (+ absorbed min/max final)
    k_dinv2<<<GN, 256, 0, stream>>>(ipM, sumem, pmn, pmx, GN4, scal, dinv);

    // 9-11. GCN stack
    k_gcn<1, 1><<<GN4, 256, 0, stream>>>(xW0b, ipM, csM, em, scal, dinv, gcn_b0 + r * 64, z0b, 64);
    { MG p{}; p.ost = 64; p.Wt[0] = G1j[r]; p.out[0] = xW1b;
      k_mgemm<64, 1, 1><<<GGM, 256, 0, stream>>>(z0b, 64, p); }
    k_gcn<0, 0><<<GN4, 256, 0, stream>>>(xW1b, ipM, csM, em, scal, dinv, gcn_b1 + r * 64,
                                         out_xtemp + r * 64, 192);
  }

  k_logits<<<GN4, 256, 0, stream>>>(out_xtemp, lin_W, lin_b, out_lsm);
}